// Round 8
// baseline (322.609 us; speedup 1.0000x reference)
//
#include <hip/hip_runtime.h>

#define NN 6000
#define NE 150000
#define TBM 2048
#define TROWS (TBM + 1)

typedef unsigned int uint;
typedef unsigned short ushort;
typedef __attribute__((ext_vector_type(8))) short short8v;
typedef __attribute__((ext_vector_type(4))) float float4v;

__device__ __forceinline__ float siluf(float x) { return x / (1.f + __expf(-x)); }
__device__ __forceinline__ float sigmf(float x) { return 1.f / (1.f + __expf(-x)); }
__device__ __forceinline__ uint pack2bf(float lo, float hi) {
    uint ul = __float_as_uint(lo);
    ul = (ul + 0x7fffu + ((ul >> 16) & 1u)) >> 16;
    uint uh = __float_as_uint(hi);
    uh = ((uh + 0x7fffu + ((uh >> 16) & 1u)) >> 16) << 16;
    return ul | uh;
}
__device__ __forceinline__ ushort f2bf(float f) {
    uint u = __float_as_uint(f);
    return (ushort)((u + 0x7fffu + ((u >> 16) & 1u)) >> 16);
}
__device__ __forceinline__ float2 up2(uint u) {
    return make_float2(__uint_as_float(u << 16), __uint_as_float(u & 0xffff0000u));
}

// ---------------- fold W2 through per-layer weights ----------------
__global__ __launch_bounds__(256)
void k_w2a(const float* __restrict__ W2, const float* __restrict__ b2,
           const float* __restrict__ Wa1, const float* __restrict__ Wg,
           float* __restrict__ W2A, float* __restrict__ W2G,
           float* __restrict__ bA, float* __restrict__ bG)
{
    const int l = blockIdx.y;
    const float* Wa1e = Wa1 + (size_t)l * 384 * 128 + 256 * 128;
    const float* Wgl  = Wg  + (size_t)l * 128 * 8;
    const int tid = threadIdx.x;

    if (blockIdx.x < 16) {
        __shared__ float w2_s[8][132];
        const int i0 = blockIdx.x * 8;
        for (int q = tid; q < 8 * 32; q += 256) {
            int ni = q >> 5, j4 = (q & 31) * 4;
            *reinterpret_cast<float4*>(&w2_s[ni][j4]) =
                *reinterpret_cast<const float4*>(&W2[(size_t)(i0 + ni) * 128 + j4]);
        }
        __syncthreads();
        const int j = tid & 127, ng = tid >> 7;
        float a[4] = {0.f, 0.f, 0.f, 0.f};
        #pragma unroll 4
        for (int k4 = 0; k4 < 128; k4 += 4) {
            float w0 = Wa1e[(k4 + 0) * 128 + j];
            float w1 = Wa1e[(k4 + 1) * 128 + j];
            float w2v = Wa1e[(k4 + 2) * 128 + j];
            float w3 = Wa1e[(k4 + 3) * 128 + j];
            #pragma unroll
            for (int r = 0; r < 4; ++r) {
                const float4 xv = *reinterpret_cast<const float4*>(&w2_s[ng * 4 + r][k4]);
                a[r] += xv.x * w0 + xv.y * w1 + xv.z * w2v + xv.w * w3;
            }
        }
        #pragma unroll
        for (int r = 0; r < 4; ++r)
            W2A[(size_t)l * 16384 + (size_t)(i0 + ng * 4 + r) * 128 + j] = a[r];
    } else if (blockIdx.x == 16) {
        const int i = tid & 127, hq = tid >> 7;
        float a[4] = {0.f, 0.f, 0.f, 0.f};
        for (int k = 0; k < 128; ++k) {
            float w = W2[(size_t)i * 128 + k];
            const float4 g4 = *reinterpret_cast<const float4*>(&Wgl[k * 8 + hq * 4]);
            a[0] += w * g4.x; a[1] += w * g4.y; a[2] += w * g4.z; a[3] += w * g4.w;
        }
        #pragma unroll
        for (int q = 0; q < 4; ++q)
            W2G[(size_t)l * 1024 + (size_t)i * 8 + hq * 4 + q] = a[q];
    } else {
        if (tid < 128) {
            float s = 0.f;
            for (int k = 0; k < 128; ++k) s += b2[k] * Wa1e[k * 128 + tid];
            bA[l * 128 + tid] = s;
        } else if (tid < 136) {
            int h = tid - 128;
            float s = 0.f;
            for (int k = 0; k < 128; ++k) s += b2[k] * Wgl[k * 8 + h];
            bG[l * 8 + h] = s;
        }
    }
}

// ---------------- bond-combo tables ----------------
__global__ __launch_bounds__(128)
void k_bondtabs(const float* __restrict__ bemb, const float* __restrict__ Wa1,
                const float* __restrict__ Wg,
                uint* __restrict__ BAcb, float* __restrict__ BGc)
{
    const int l = blockIdx.y, cb = blockIdx.x, c = threadIdx.x;
    const float* Wa1e = Wa1 + (size_t)l * 384 * 128 + 256 * 128;
    const float* Wgl  = Wg  + (size_t)l * 128 * 8;
    const int b[3] = {cb >> 6, (cb >> 3) & 7, cb & 7};

    float s = 0.f;
    #pragma unroll
    for (int f = 0; f < 3; ++f) {
        const float* er = &bemb[(size_t)(f * 8 + b[f]) * 128];
        for (int k = 0; k < 128; ++k)
            s += er[k] * Wa1e[k * 128 + c];
    }
    float hi = __shfl_down(s, 1, 64);
    if ((c & 1) == 0)
        BAcb[(size_t)l * 512 * 64 + (size_t)cb * 64 + (c >> 1)] = pack2bf(s, hi);

    if (c < 8) {
        float g = 0.f;
        #pragma unroll
        for (int f = 0; f < 3; ++f) {
            const float* er = &bemb[(size_t)(f * 8 + b[f]) * 128];
            for (int k = 0; k < 128; ++k)
                g += er[k] * Wgl[k * 8 + c];
        }
        BGc[(size_t)l * 512 * 8 + (size_t)cb * 8 + c] = g;
    }
}

// ---------------- fused t1 + TA + TG table build ----------------
__global__ __launch_bounds__(256)
void k_t1ta(const float* __restrict__ W1, const float* __restrict__ b1,
            const float* __restrict__ W2A, const float* __restrict__ W2G,
            const float* __restrict__ bA, const float* __restrict__ bG,
            uint* __restrict__ TAb, float* __restrict__ TG)
{
    __shared__ float rbf_s[8][32];
    __shared__ int   bs_s[8];
    __shared__ float t1_s[8][132];
    const int l = blockIdx.y, tid = threadIdx.x;
    const int r0 = blockIdx.x * 8;

    {
        int ri = tid >> 5, j = tid & 31;
        int row = min(r0 + ri, TBM);
        float d = (float)row * (5.0f / TBM);
        const float step = 5.0f / 511.0f;
        const float invw = 512.0f / 5.0f;
        int b0 = (int)(d * (511.0f / 5.0f) + 0.5f);
        int bs = min(max(b0 - 16, 0), 512 - 32);
        if (j == 0) bs_s[ri] = bs;
        float z = (d - (float)(bs + j) * step) * invw;
        rbf_s[ri][j] = __expf(-z * z);
    }
    __syncthreads();

    #pragma unroll
    for (int pass = 0; pass < 4; ++pass) {
        int idx = pass * 256 + tid;
        int ri = idx >> 7, c = idx & 127;
        int bs = bs_s[ri];
        float t = b1[c];
        #pragma unroll
        for (int j = 0; j < 32; ++j)
            t += rbf_s[ri][j] * W1[(bs + j) * 128 + c];
        t1_s[ri][c] = siluf(t);
    }
    __syncthreads();

    const float* W2Al = W2A + (size_t)l * 16384;
    const int c = tid & 127, ng = tid >> 7;
    float a[4];
    #pragma unroll
    for (int r = 0; r < 4; ++r) a[r] = bA[l * 128 + c];
    #pragma unroll 4
    for (int k4 = 0; k4 < 128; k4 += 4) {
        float w0 = W2Al[(k4 + 0) * 128 + c];
        float w1 = W2Al[(k4 + 1) * 128 + c];
        float w2v = W2Al[(k4 + 2) * 128 + c];
        float w3 = W2Al[(k4 + 3) * 128 + c];
        #pragma unroll
        for (int r = 0; r < 4; ++r) {
            const float4 xv = *reinterpret_cast<const float4*>(&t1_s[ng * 4 + r][k4]);
            a[r] += xv.x * w0 + xv.y * w1 + xv.z * w2v + xv.w * w3;
        }
    }
    #pragma unroll
    for (int r = 0; r < 4; ++r) {
        float hi = __shfl_down(a[r], 1, 64);
        int row = r0 + ng * 4 + r;
        if (((c & 1) == 0) && row <= TBM)
            TAb[(size_t)l * TROWS * 64 + (size_t)row * 64 + (c >> 1)] = pack2bf(a[r], hi);
    }

    if (tid < 64) {
        int ri = tid >> 3, h = tid & 7;
        int row = r0 + ri;
        if (row <= TBM) {
            const float* W2Gl = W2G + (size_t)l * 1024;
            float s = bG[l * 8 + h];
            #pragma unroll 8
            for (int k = 0; k < 128; ++k)
                s += t1_s[ri][k] * W2Gl[k * 8 + h];
            TG[(size_t)l * TROWS * 8 + (size_t)row * 8 + h] = s;
        }
    }
}

// ---------------- pack weights into MFMA B-fragment order (bf16) ----------------
__global__ __launch_bounds__(64)
void k_packw(const float* __restrict__ Wf1, const float* __restrict__ Wf2,
             const float* __restrict__ Wv, const float* __restrict__ Wa1,
             ushort* __restrict__ Wf1x, ushort* __restrict__ Wf2x,
             ushort* __restrict__ Wvx, ushort* __restrict__ Wa1sx,
             ushort* __restrict__ Wa1dx)
{
    const int l = blockIdx.y, bx = blockIdx.x, lane = threadIdx.x;
    if (bx < 128) {
        const int nt = bx >> 2, kt = bx & 3;
        const float* src = Wf1 + (size_t)l * 65536;
        ushort* dst = Wf1x + (size_t)l * 65536 + ((size_t)bx * 64 + lane) * 8;
        #pragma unroll
        for (int j = 0; j < 8; ++j)
            dst[j] = f2bf(src[(size_t)(kt * 32 + (lane >> 4) * 8 + j) * 512 + nt * 16 + (lane & 15)]);
    } else if (bx < 256) {
        const int b2x = bx - 128;
        const int nt = b2x >> 4, kt = b2x & 15;
        const float* src = Wf2 + (size_t)l * 65536;
        ushort* dst = Wf2x + (size_t)l * 65536 + ((size_t)b2x * 64 + lane) * 8;
        #pragma unroll
        for (int j = 0; j < 8; ++j)
            dst[j] = f2bf(src[(size_t)(kt * 32 + (lane >> 4) * 8 + j) * 128 + nt * 16 + (lane & 15)]);
    } else {
        const int b3 = bx - 256;
        const int mat = b3 >> 5, blk = b3 & 31;
        const int nt = blk >> 2, kt = blk & 3;
        const float* src;
        ushort* dst;
        if (mat == 0)      { src = Wv  + (size_t)l * 16384;             dst = Wvx   + (size_t)l * 16384; }
        else if (mat == 1) { src = Wa1 + (size_t)l * 384 * 128;         dst = Wa1sx + (size_t)l * 16384; }
        else               { src = Wa1 + (size_t)l * 384 * 128 + 16384; dst = Wa1dx + (size_t)l * 16384; }
        dst += ((size_t)blk * 64 + lane) * 8;
        #pragma unroll
        for (int j = 0; j < 8; ++j)
            dst[j] = f2bf(src[(size_t)(kt * 32 + (lane >> 4) * 8 + j) * 128 + nt * 16 + (lane & 15)]);
    }
}

// ---------------- shared device helper: 3 node GEMMs from a_s ----------------
__device__ __forceinline__
void node_gemm3(const ushort a_s[16][136], int tid, int n0,
                const ushort* __restrict__ Wvx, const ushort* __restrict__ Wa1sx,
                const ushort* __restrict__ Wa1dx,
                uint* __restrict__ Vb, uint* __restrict__ Psb, uint* __restrict__ Pdb)
{
    const int l = tid & 63, wq = tid >> 6;
    const int lr = l & 15, lk = l >> 4;
    #pragma unroll
    for (int jb = 0; jb < 6; ++jb) {
        int job = wq * 6 + jb;
        int mat = job >> 3, nt = job & 7;
        const ushort* W = (mat == 0) ? Wvx : (mat == 1 ? Wa1sx : Wa1dx);
        uint* O = (mat == 0) ? Vb : (mat == 1 ? Psb : Pdb);
        float4v acc = (float4v){0.f, 0.f, 0.f, 0.f};
        #pragma unroll
        for (int ks = 0; ks < 4; ++ks) {
            short8v af = *reinterpret_cast<const short8v*>(&a_s[lr][lk * 8 + ks * 32]);
            short8v bf = *reinterpret_cast<const short8v*>(&W[((size_t)(nt * 4 + ks) * 64 + l) * 8]);
            acc = __builtin_amdgcn_mfma_f32_16x16x32_bf16(af, bf, acc, 0, 0, 0);
        }
        #pragma unroll
        for (int r = 0; r < 4; ++r) {
            float v = acc[r];
            float vn = __shfl_xor(v, 1, 64);
            if ((l & 1) == 0) {
                int row = lk * 4 + r, col = nt * 16 + lr;
                O[(size_t)(n0 + row) * 64 + (col >> 1)] = pack2bf(v, vn);
            }
        }
    }
}

// ---------------- fused atom-embed + rms + 3 node GEMMs (16 nodes/block) ----------------
__global__ __launch_bounds__(256)
void k_embedgemm(const int* __restrict__ af, const float* __restrict__ aemb,
                 float* __restrict__ x, int* __restrict__ deg,
                 const ushort* __restrict__ Wvx, const ushort* __restrict__ Wa1sx,
                 const ushort* __restrict__ Wa1dx,
                 uint* __restrict__ Vb, uint* __restrict__ Psb, uint* __restrict__ Pdb)
{
    __shared__ ushort a_s[16][136];
    const int tid = threadIdx.x, n0 = blockIdx.x * 16;
    if (tid < 16) deg[n0 + tid] = 0;

    {
        int ni = tid >> 4, c8 = (tid & 15) * 8;
        int n = n0 + ni;
        float v[8];
        #pragma unroll
        for (int q = 0; q < 8; ++q) v[q] = 0.f;
        #pragma unroll
        for (int f = 0; f < 4; ++f) {
            int idx = af[n * 4 + f];
            const float* er = &aemb[(size_t)(f * 10 + idx) * 128 + c8];
            float4 e0 = *reinterpret_cast<const float4*>(er);
            float4 e1 = *reinterpret_cast<const float4*>(er + 4);
            v[0] += e0.x; v[1] += e0.y; v[2] += e0.z; v[3] += e0.w;
            v[4] += e1.x; v[5] += e1.y; v[6] += e1.z; v[7] += e1.w;
        }
        float* xr = &x[(size_t)n * 128 + c8];
        *reinterpret_cast<float4*>(xr)     = make_float4(v[0], v[1], v[2], v[3]);
        *reinterpret_cast<float4*>(xr + 4) = make_float4(v[4], v[5], v[6], v[7]);
        float ss = 0.f;
        #pragma unroll
        for (int q = 0; q < 8; ++q) ss += v[q] * v[q];
        #pragma unroll
        for (int m = 1; m < 16; m <<= 1) ss += __shfl_xor(ss, m, 16);
        float r = rsqrtf(ss * (1.0f / 1152.0f) + 1e-6f);
        uint4 pk;
        pk.x = pack2bf(v[0] * r, v[1] * r);
        pk.y = pack2bf(v[2] * r, v[3] * r);
        pk.z = pack2bf(v[4] * r, v[5] * r);
        pk.w = pack2bf(v[6] * r, v[7] * r);
        *reinterpret_cast<uint4*>(&a_s[ni][c8]) = pk;
    }
    __syncthreads();
    node_gemm3(a_s, tid, n0, Wvx, Wa1sx, Wa1dx, Vb, Psb, Pdb);
}

// ---------------- CSR build ----------------
__global__ __launch_bounds__(256)
void k_hist(const int* __restrict__ eidx, int* __restrict__ deg)
{
    int e = blockIdx.x * 256 + threadIdx.x;
    if (e < NE) atomicAdd(&deg[eidx[NE + e]], 1);
}

__global__ __launch_bounds__(1024)
void k_scan(const int* __restrict__ deg, int* __restrict__ off, int* __restrict__ cursor)
{
    __shared__ int part[1024];
    const int t = threadIdx.x;
    const int base = t * 6;
    int loc[6]; int s = 0;
    #pragma unroll
    for (int i = 0; i < 6; ++i) {
        int d = (base + i < NN) ? deg[base + i] : 0;
        loc[i] = s; s += d;
    }
    part[t] = s;
    __syncthreads();
    for (int o = 1; o < 1024; o <<= 1) {
        int v = (t >= o) ? part[t - o] : 0;
        __syncthreads();
        part[t] += v;
        __syncthreads();
    }
    int pre = (t > 0) ? part[t - 1] : 0;
    #pragma unroll
    for (int i = 0; i < 6; ++i) {
        if (base + i < NN) {
            int v = pre + loc[i];
            off[base + i] = v;
            cursor[base + i] = v;
        }
    }
    if (t == 1023) off[NN] = part[1023];
}

__global__ __launch_bounds__(256)
void k_fill(const int* __restrict__ eidx, const int* __restrict__ bondf,
            const float* __restrict__ dist, int* __restrict__ cursor,
            int* __restrict__ srcp, int* __restrict__ dstp,
            float* __restrict__ distp, int* __restrict__ cbp)
{
    int e = blockIdx.x * 256 + threadIdx.x;
    if (e < NE) {
        int d = eidx[NE + e];
        int p = atomicAdd(&cursor[d], 1);
        srcp[p] = eidx[e];
        dstp[p] = d;
        distp[p] = dist[e];
        cbp[p] = bondf[e * 3 + 0] * 64 + bondf[e * 3 + 1] * 8 + bondf[e * 3 + 2];
    }
}

// ---------------- attention: register-resident, no LDS, no sync ----------------
__global__ __launch_bounds__(256)
void k_attn(const int* __restrict__ srcp, const int* __restrict__ dstp,
            const float* __restrict__ distp, const int* __restrict__ cbp,
            const uint* __restrict__ Psb, const uint* __restrict__ Pdb,
            const uint* __restrict__ TAbl, const float* __restrict__ TGl,
            const uint* __restrict__ BAcbl, const float* __restrict__ BGcl,
            const float* __restrict__ Wa2l,
            float* __restrict__ num, float* __restrict__ exs)
{
    const int tid = threadIdx.x;
    const int p0 = blockIdx.x * 32;
    const int ei = tid >> 3, g = tid & 7;
    const int p = min(p0 + ei, NE - 1);
    const int sn = srcp[p], dn = dstp[p];
    const float d = distp[p];
    const int cb = cbp[p];
    float u = d * ((float)TBM / 5.0f);
    int i = min((int)u, TBM - 1);
    float f = u - (float)i, f1 = 1.f - f;

    uint ps[8], pd[8], t0[8], t1v[8], ba[8];
    {
        const uint4* pp = reinterpret_cast<const uint4*>(&Psb[(size_t)sn * 64 + g * 8]);
        uint4 a = pp[0], b = pp[1];
        ps[0]=a.x; ps[1]=a.y; ps[2]=a.z; ps[3]=a.w; ps[4]=b.x; ps[5]=b.y; ps[6]=b.z; ps[7]=b.w;
        pp = reinterpret_cast<const uint4*>(&Pdb[(size_t)dn * 64 + g * 8]);
        a = pp[0]; b = pp[1];
        pd[0]=a.x; pd[1]=a.y; pd[2]=a.z; pd[3]=a.w; pd[4]=b.x; pd[5]=b.y; pd[6]=b.z; pd[7]=b.w;
        pp = reinterpret_cast<const uint4*>(&TAbl[(size_t)i * 64 + g * 8]);
        a = pp[0]; b = pp[1];
        t0[0]=a.x; t0[1]=a.y; t0[2]=a.z; t0[3]=a.w; t0[4]=b.x; t0[5]=b.y; t0[6]=b.z; t0[7]=b.w;
        pp = reinterpret_cast<const uint4*>(&TAbl[(size_t)(i + 1) * 64 + g * 8]);
        a = pp[0]; b = pp[1];
        t1v[0]=a.x; t1v[1]=a.y; t1v[2]=a.z; t1v[3]=a.w; t1v[4]=b.x; t1v[5]=b.y; t1v[6]=b.z; t1v[7]=b.w;
        pp = reinterpret_cast<const uint4*>(&BAcbl[(size_t)cb * 64 + g * 8]);
        a = pp[0]; b = pp[1];
        ba[0]=a.x; ba[1]=a.y; ba[2]=a.z; ba[3]=a.w; ba[4]=b.x; ba[5]=b.y; ba[6]=b.z; ba[7]=b.w;
    }

    // partial logits for all 8 heads over this thread's 16 channels
    float acc[8];
    #pragma unroll
    for (int h = 0; h < 8; ++h) acc[h] = 0.f;
    #pragma unroll
    for (int q = 0; q < 8; ++q) {
        float2 vs = up2(ps[q]), vd = up2(pd[q]), v0 = up2(t0[q]), v1 = up2(t1v[q]), vb = up2(ba[q]);
        float s0 = siluf(vs.x + vd.x + f1 * v0.x + f * v1.x + vb.x);
        float s1 = siluf(vs.y + vd.y + f1 * v0.y + f * v1.y + vb.y);
        int c0 = g * 16 + 2 * q;
        const float4* w0 = reinterpret_cast<const float4*>(&Wa2l[(size_t)c0 * 8]);
        float4 wa = w0[0], wb = w0[1], wc = w0[2], wd = w0[3];   // rows c0, c0+1
        acc[0] += s0 * wa.x + s1 * wc.x;
        acc[1] += s0 * wa.y + s1 * wc.y;
        acc[2] += s0 * wa.z + s1 * wc.z;
        acc[3] += s0 * wa.w + s1 * wc.w;
        acc[4] += s0 * wb.x + s1 * wd.x;
        acc[5] += s0 * wb.y + s1 * wd.y;
        acc[6] += s0 * wb.z + s1 * wd.z;
        acc[7] += s0 * wb.w + s1 * wd.w;
    }
    // butterfly all-reduce across the 8 threads of this edge (lanes differ in bits 0..2)
    #pragma unroll
    for (int m = 1; m < 8; m <<= 1) {
        #pragma unroll
        for (int h = 0; h < 8; ++h)
            acc[h] += __shfl_xor(acc[h], m, 64);
    }
    // thread g owns head g (static-index extraction)
    float lg = 0.f;
    #pragma unroll
    for (int h = 0; h < 8; ++h) lg += (h == g) ? acc[h] : 0.f;

    if (p0 + ei < NE) {
        float ex = __expf(lg);
        float gp = f1 * TGl[(size_t)i * 8 + g] + f * TGl[(size_t)(i + 1) * 8 + g]
                 + BGcl[(size_t)cb * 8 + g];
        num[(size_t)p * 8 + g] = ex * sigmf(gp);
        exs[(size_t)p * 8 + g] = ex;
    }
}

// ---------------- fused aggregate (+denominator) + out_proj ----------------
__global__ __launch_bounds__(128)
void k_aggo(const int* __restrict__ off, const int* __restrict__ srcp,
            const float* __restrict__ num, const float* __restrict__ exs,
            const uint* __restrict__ Vb, const float* __restrict__ Wol,
            float* __restrict__ x)
{
    __shared__ float a_s[128];
    const int n = blockIdx.x, c = threadIdx.x;
    const int s = off[n], t = off[n + 1];
    const int h = c >> 4, cd = c >> 1, sel = c & 1;
    float acc = 0.f, es = 0.f;
    int p = s;
    for (; p + 4 <= t; p += 4) {
        int sn0 = srcp[p + 0], sn1 = srcp[p + 1], sn2 = srcp[p + 2], sn3 = srcp[p + 3];
        float cf0 = num[(size_t)(p + 0) * 8 + h];
        float cf1 = num[(size_t)(p + 1) * 8 + h];
        float cf2 = num[(size_t)(p + 2) * 8 + h];
        float cf3 = num[(size_t)(p + 3) * 8 + h];
        es += exs[(size_t)(p + 0) * 8 + h] + exs[(size_t)(p + 1) * 8 + h]
            + exs[(size_t)(p + 2) * 8 + h] + exs[(size_t)(p + 3) * 8 + h];
        uint u0 = Vb[(size_t)sn0 * 64 + cd];
        uint u1 = Vb[(size_t)sn1 * 64 + cd];
        uint u2 = Vb[(size_t)sn2 * 64 + cd];
        uint u3 = Vb[(size_t)sn3 * 64 + cd];
        float v0 = sel ? __uint_as_float(u0 & 0xffff0000u) : __uint_as_float(u0 << 16);
        float v1 = sel ? __uint_as_float(u1 & 0xffff0000u) : __uint_as_float(u1 << 16);
        float v2 = sel ? __uint_as_float(u2 & 0xffff0000u) : __uint_as_float(u2 << 16);
        float v3 = sel ? __uint_as_float(u3 & 0xffff0000u) : __uint_as_float(u3 << 16);
        acc += cf0 * v0 + cf1 * v1 + cf2 * v2 + cf3 * v3;
    }
    for (; p < t; ++p) {
        int sn = srcp[p];
        float cf = num[(size_t)p * 8 + h];
        es += exs[(size_t)p * 8 + h];
        uint u = Vb[(size_t)sn * 64 + cd];
        float v = sel ? __uint_as_float(u & 0xffff0000u) : __uint_as_float(u << 16);
        acc += cf * v;
    }
    a_s[c] = acc / (es + 1e-9f);
    __syncthreads();
    float o = 0.f;
    #pragma unroll 4
    for (int j4 = 0; j4 < 128; j4 += 4) {
        const float4 a4 = *reinterpret_cast<const float4*>(&a_s[j4]);
        o += a4.x * Wol[(j4 + 0) * 128 + c] + a4.y * Wol[(j4 + 1) * 128 + c]
           + a4.z * Wol[(j4 + 2) * 128 + c] + a4.w * Wol[(j4 + 3) * 128 + c];
    }
    x[n * 128 + c] += o;
}

// ---------------- fused rms + FFN (+ next-layer GEMMs, or finalize) ----------------
template<int LAST>
__global__ __launch_bounds__(256)
void k_ffn_fused(float* __restrict__ x, const ushort* __restrict__ Wf1xl,
                 const ushort* __restrict__ Wf2xl, float* __restrict__ out,
                 const ushort* __restrict__ WvxN, const ushort* __restrict__ Wa1sxN,
                 const ushort* __restrict__ Wa1dxN,
                 uint* __restrict__ Vb, uint* __restrict__ Psb, uint* __restrict__ Pdb)
{
    __shared__ ushort a_s[16][136];
    __shared__ ushort h_s[16][520];
    __shared__ float xf_s[16][132];
    const int tid = threadIdx.x;
    const int n0 = blockIdx.x * 16;

    {   // rms prologue + stash x_old
        int ni = tid >> 4, c8 = (tid & 15) * 8;
        const float* xr = &x[(size_t)(n0 + ni) * 128 + c8];
        float4 v0 = *reinterpret_cast<const float4*>(xr);
        float4 v1 = *reinterpret_cast<const float4*>(xr + 4);
        *reinterpret_cast<float4*>(&xf_s[ni][c8]) = v0;
        *reinterpret_cast<float4*>(&xf_s[ni][c8 + 4]) = v1;
        float ss = v0.x * v0.x + v0.y * v0.y + v0.z * v0.z + v0.w * v0.w
                 + v1.x * v1.x + v1.y * v1.y + v1.z * v1.z + v1.w * v1.w;
        #pragma unroll
        for (int m = 1; m < 16; m <<= 1) ss += __shfl_xor(ss, m, 16);
        float r = rsqrtf(ss * (1.0f / 1152.0f) + 1e-6f);
        uint4 pk;
        pk.x = pack2bf(v0.x * r, v0.y * r);
        pk.y = pack2bf(v0.z * r, v0.w * r);
        pk.z = pack2bf(v1.x * r, v1.y * r);
        pk.w = pack2bf(v1.z * r, v1.w * r);
        *reinterpret_cast<uint4*>(&a_s[ni][c8]) = pk;
    }
    __syncthreads();

    const int l  = tid & 63;
    const int wq = tid >> 6;
    const int lr = l & 15, lk = l >> 4;

    float4v acc[8];
    #pragma unroll
    for (int nf = 0; nf < 8; ++nf) acc[nf] = (float4v){0.f, 0.f, 0.f, 0.f};
    #pragma unroll
    for (int ks = 0; ks < 4; ++ks) {
        short8v af = *reinterpret_cast<const short8v*>(&a_s[lr][lk * 8 + ks * 32]);
        #pragma unroll
        for (int nf = 0; nf < 8; ++nf) {
            int nt = wq * 8 + nf;
            short8v bf = *reinterpret_cast<const short8v*>(&Wf1xl[((size_t)(nt * 4 + ks) * 64 + l) * 8]);
            acc[nf] = __builtin_amdgcn_mfma_f32_16x16x32_bf16(af, bf, acc[nf], 0, 0, 0);
        }
    }
    #pragma unroll
    for (int nf = 0; nf < 8; ++nf) {
        #pragma unroll
        for (int r = 0; r < 4; ++r) {
            float v = siluf(acc[nf][r]);
            float vn = __shfl_xor(v, 1, 64);
            if ((l & 1) == 0) {
                int row = lk * 4 + r;
                int col = wq * 128 + nf * 16 + lr;
                *reinterpret_cast<uint*>(&h_s[row][col]) = pack2bf(v, vn);
            }
        }
    }
    __syncthreads();

    float4v acc2[2];
    acc2[0] = (float4v){0.f, 0.f, 0.f, 0.f};
    acc2[1] = (float4v){0.f, 0.f, 0.f, 0.f};
    #pragma unroll 4
    for (int ks = 0; ks < 16; ++ks) {
        short8v af = *reinterpret_cast<const short8v*>(&h_s[lr][lk * 8 + ks * 32]);
        #pragma unroll
        for (int nf = 0; nf < 2; ++nf) {
            int nt = wq * 2 + nf;
            short8v bf = *reinterpret_cast<const short8v*>(&Wf2xl[((size_t)(nt * 16 + ks) * 64 + l) * 8]);
            acc2[nf] = __builtin_amdgcn_mfma_f32_16x16x32_bf16(af, bf, acc2[nf], 0, 0, 0);
        }
    }
    // delta -> xf_s (unique (row,col) per thread)
    #pragma unroll
    for (int nf = 0; nf < 2; ++nf) {
        #pragma unroll
        for (int r = 0; r < 4; ++r) {
            int row = lk * 4 + r;
            int col = wq * 32 + nf * 16 + lr;
            xf_s[row][col] += acc2[nf][r];
        }
    }
    __syncthreads();

    int ni = tid >> 4, c8 = (tid & 15) * 8;
    float4 v0 = *reinterpret_cast<const float4*>(&xf_s[ni][c8]);
    float4 v1 = *reinterpret_cast<const float4*>(&xf_s[ni][c8 + 4]);
    float ss = v0.x * v0.x + v0.y * v0.y + v0.z * v0.z + v0.w * v0.w
             + v1.x * v1.x + v1.y * v1.y + v1.z * v1.z + v1.w * v1.w;
    #pragma unroll
    for (int m = 1; m < 16; m <<= 1) ss += __shfl_xor(ss, m, 16);
    float r = rsqrtf(ss * (1.0f / 1152.0f) + 1e-6f);

    if (!LAST) {
        // write new x (residual state) + rms-packed a_s for next-layer GEMMs
        float* xr = &x[(size_t)(n0 + ni) * 128 + c8];
        *reinterpret_cast<float4*>(xr)     = v0;
        *reinterpret_cast<float4*>(xr + 4) = v1;
        uint4 pk;
        pk.x = pack2bf(v0.x * r, v0.y * r);
        pk.y = pack2bf(v0.z * r, v0.w * r);
        pk.z = pack2bf(v1.x * r, v1.y * r);
        pk.w = pack2bf(v1.z * r, v1.w * r);
        __syncthreads();   // all xf_s reads done before a_s overwrite (a_s/xf_s distinct, but keep phases clean)
        *reinterpret_cast<uint4*>(&a_s[ni][c8]) = pk;
        __syncthreads();
        node_gemm3(a_s, tid, n0, WvxN, Wa1sxN, Wa1dxN, Vb, Psb, Pdb);
    } else {
        size_t base = (size_t)(n0 + ni) * 1152 + c8;
        *reinterpret_cast<float4*>(&out[base])     = make_float4(v0.x * r, v0.y * r, v0.z * r, v0.w * r);
        *reinterpret_cast<float4*>(&out[base + 4]) = make_float4(v1.x * r, v1.y * r, v1.z * r, v1.w * r);
        const float4 z4 = make_float4(0.f, 0.f, 0.f, 0.f);
        #pragma unroll
        for (int k = 1; k < 9; ++k) {
            *reinterpret_cast<float4*>(&out[base + (size_t)k * 128]) = z4;
            *reinterpret_cast<float4*>(&out[base + (size_t)k * 128 + 4]) = z4;
        }
    }
}

extern "C" void kernel_launch(void* const* d_in, const int* in_sizes, int n_in,
                              void* d_out, int out_size, void* d_ws, size_t ws_size,
                              hipStream_t stream)
{
    const int*   atom_feats = (const int*)d_in[0];
    const int*   bond_feats = (const int*)d_in[1];
    const int*   edge_index = (const int*)d_in[2];
    const float* edge_dist  = (const float*)d_in[3];
    const float* atom_emb   = (const float*)d_in[4];
    const float* bond_emb   = (const float*)d_in[5];
    const float* W_rbf1     = (const float*)d_in[6];
    const float* b_rbf1     = (const float*)d_in[7];
    const float* W_rbf2     = (const float*)d_in[8];
    const float* b_rbf2     = (const float*)d_in[9];
    const float* Wa1        = (const float*)d_in[10];
    const float* Wa2        = (const float*)d_in[11];
    const float* Wv         = (const float*)d_in[12];
    const float* Wg         = (const float*)d_in[13];
    const float* Wo         = (const float*)d_in[14];
    const float* Wf1        = (const float*)d_in[15];
    const float* Wf2        = (const float*)d_in[16];
    float* out = (float*)d_out;

    float* ws   = (float*)d_ws;
    float* x    = ws;                           // NN*128
    float* num  = x    + NN * 128;              // NE*8 (CSR order)
    float* exs  = num  + (size_t)NE * 8;        // NE*8
    float* W2A  = exs  + (size_t)NE * 8;        // 2*16384
    float* W2G  = W2A  + 2 * 16384;             // 2*1024
    float* bA   = W2G  + 2 * 1024;              // 2*128
    float* bG   = bA   + 2 * 128;               // 16
    float* TG   = bG   + 16;                    // 2*TROWS*8
    float* BGc  = TG   + 2 * (size_t)TROWS * 8; // 2*512*8
    float* distp = BGc + 2 * 512 * 8;           // NE
    uint* Vb    = (uint*)(distp + NE);          // NN*64
    uint* Psb   = Vb  + NN * 64;
    uint* Pdb   = Psb + NN * 64;
    uint* TAb   = Pdb + NN * 64;                // 2*TROWS*64
    uint* BAcb  = TAb + 2 * (size_t)TROWS * 64; // 2*512*64
    ushort* Wf1x  = (ushort*)(BAcb + 2 * 512 * 64);  // 2*65536
    ushort* Wf2x  = Wf1x  + 2 * 65536;
    ushort* Wvx   = Wf2x  + 2 * 65536;
    ushort* Wa1sx = Wvx   + 2 * 16384;
    ushort* Wa1dx = Wa1sx + 2 * 16384;
    int* deg    = (int*)(Wa1dx + 2 * 16384);
    int* off    = deg + NN;
    int* cursor = off + NN + 1;
    int* srcp   = cursor + NN;                  // NE
    int* dstp   = srcp + NE;                    // NE
    int* cbp    = dstp + NE;                    // NE

    // tables + packed weights (once per call)
    k_w2a<<<dim3(18, 2), 256, 0, stream>>>(W_rbf2, b_rbf2, Wa1, Wg, W2A, W2G, bA, bG);
    k_bondtabs<<<dim3(512, 2), 128, 0, stream>>>(bond_emb, Wa1, Wg, BAcb, BGc);
    k_packw<<<dim3(352, 2), 64, 0, stream>>>(Wf1, Wf2, Wv, Wa1, Wf1x, Wf2x, Wvx, Wa1sx, Wa1dx);
    k_t1ta<<<dim3((TBM + 8) / 8, 2), 256, 0, stream>>>(W_rbf1, b_rbf1, W2A, W2G, bA, bG, TAb, TG);

    // embed + layer-0 rms/GEMMs (also zeroes deg)
    k_embedgemm<<<NN / 16, 256, 0, stream>>>(atom_feats, atom_emb, x, deg,
                                             Wvx, Wa1sx, Wa1dx, Vb, Psb, Pdb);

    // CSR (dst is layer-invariant)
    k_hist<<<(NE + 255) / 256, 256, 0, stream>>>(edge_index, deg);
    k_scan<<<1, 1024, 0, stream>>>(deg, off, cursor);
    k_fill<<<(NE + 255) / 256, 256, 0, stream>>>(edge_index, bond_feats, edge_dist,
                                                 cursor, srcp, dstp, distp, cbp);

    for (int l = 0; l < 2; ++l) {
        k_attn<<<(NE + 31) / 32, 256, 0, stream>>>(srcp, dstp, distp, cbp,
            Psb, Pdb,
            TAb + (size_t)l * TROWS * 64, TG + (size_t)l * TROWS * 8,
            BAcb + (size_t)l * 512 * 64, BGc + (size_t)l * 512 * 8,
            Wa2 + (size_t)l * 128 * 8, num, exs);
        k_aggo<<<NN, 128, 0, stream>>>(off, srcp, num, exs, Vb,
                                       Wo + (size_t)l * 128 * 128, x);
        if (l == 0)
            k_ffn_fused<0><<<NN / 16, 256, 0, stream>>>(x,
                Wf1x, Wf2x, out,
                Wvx + 16384, Wa1sx + 16384, Wa1dx + 16384, Vb, Psb, Pdb);
        else
            k_ffn_fused<1><<<NN / 16, 256, 0, stream>>>(x,
                Wf1x + 65536, Wf2x + 65536, out,
                Wvx, Wa1sx, Wa1dx, Vb, Psb, Pdb);
    }
}

// Round 9
// 235.359 us; speedup vs baseline: 1.3707x; 1.3707x over previous
//
#include <hip/hip_runtime.h>

#define NN 6000
#define NE 150000
#define TBM 2048
#define TROWS (TBM + 1)

typedef unsigned int uint;
typedef unsigned short ushort;
typedef __attribute__((ext_vector_type(8))) short short8v;
typedef __attribute__((ext_vector_type(4))) float float4v;

__device__ __forceinline__ float siluf(float x) { return x / (1.f + __expf(-x)); }
__device__ __forceinline__ float sigmf(float x) { return 1.f / (1.f + __expf(-x)); }
__device__ __forceinline__ uint pack2bf(float lo, float hi) {
    uint ul = __float_as_uint(lo);
    ul = (ul + 0x7fffu + ((ul >> 16) & 1u)) >> 16;
    uint uh = __float_as_uint(hi);
    uh = ((uh + 0x7fffu + ((uh >> 16) & 1u)) >> 16) << 16;
    return ul | uh;
}
__device__ __forceinline__ ushort f2bf(float f) {
    uint u = __float_as_uint(f);
    return (ushort)((u + 0x7fffu + ((u >> 16) & 1u)) >> 16);
}
__device__ __forceinline__ float2 up2(uint u) {
    return make_float2(__uint_as_float(u << 16), __uint_as_float(u & 0xffff0000u));
}

// ---------------- fold W2 through per-layer weights ----------------
__global__ __launch_bounds__(256)
void k_w2a(const float* __restrict__ W2, const float* __restrict__ b2,
           const float* __restrict__ Wa1, const float* __restrict__ Wg,
           float* __restrict__ W2A, float* __restrict__ W2G,
           float* __restrict__ bA, float* __restrict__ bG)
{
    const int l = blockIdx.y;
    const float* Wa1e = Wa1 + (size_t)l * 384 * 128 + 256 * 128;
    const float* Wgl  = Wg  + (size_t)l * 128 * 8;
    const int tid = threadIdx.x;

    if (blockIdx.x < 16) {
        __shared__ float w2_s[8][132];
        const int i0 = blockIdx.x * 8;
        for (int q = tid; q < 8 * 32; q += 256) {
            int ni = q >> 5, j4 = (q & 31) * 4;
            *reinterpret_cast<float4*>(&w2_s[ni][j4]) =
                *reinterpret_cast<const float4*>(&W2[(size_t)(i0 + ni) * 128 + j4]);
        }
        __syncthreads();
        const int j = tid & 127, ng = tid >> 7;
        float a[4] = {0.f, 0.f, 0.f, 0.f};
        #pragma unroll 4
        for (int k4 = 0; k4 < 128; k4 += 4) {
            float w0 = Wa1e[(k4 + 0) * 128 + j];
            float w1 = Wa1e[(k4 + 1) * 128 + j];
            float w2v = Wa1e[(k4 + 2) * 128 + j];
            float w3 = Wa1e[(k4 + 3) * 128 + j];
            #pragma unroll
            for (int r = 0; r < 4; ++r) {
                const float4 xv = *reinterpret_cast<const float4*>(&w2_s[ng * 4 + r][k4]);
                a[r] += xv.x * w0 + xv.y * w1 + xv.z * w2v + xv.w * w3;
            }
        }
        #pragma unroll
        for (int r = 0; r < 4; ++r)
            W2A[(size_t)l * 16384 + (size_t)(i0 + ng * 4 + r) * 128 + j] = a[r];
    } else if (blockIdx.x == 16) {
        const int i = tid & 127, hq = tid >> 7;
        float a[4] = {0.f, 0.f, 0.f, 0.f};
        for (int k = 0; k < 128; ++k) {
            float w = W2[(size_t)i * 128 + k];
            const float4 g4 = *reinterpret_cast<const float4*>(&Wgl[k * 8 + hq * 4]);
            a[0] += w * g4.x; a[1] += w * g4.y; a[2] += w * g4.z; a[3] += w * g4.w;
        }
        #pragma unroll
        for (int q = 0; q < 4; ++q)
            W2G[(size_t)l * 1024 + (size_t)i * 8 + hq * 4 + q] = a[q];
    } else {
        if (tid < 128) {
            float s = 0.f;
            for (int k = 0; k < 128; ++k) s += b2[k] * Wa1e[k * 128 + tid];
            bA[l * 128 + tid] = s;
        } else if (tid < 136) {
            int h = tid - 128;
            float s = 0.f;
            for (int k = 0; k < 128; ++k) s += b2[k] * Wgl[k * 8 + h];
            bG[l * 8 + h] = s;
        }
    }
}

// ---------------- bond-combo tables ----------------
__global__ __launch_bounds__(128)
void k_bondtabs(const float* __restrict__ bemb, const float* __restrict__ Wa1,
                const float* __restrict__ Wg,
                uint* __restrict__ BAcb, float* __restrict__ BGc)
{
    const int l = blockIdx.y, cb = blockIdx.x, c = threadIdx.x;
    const float* Wa1e = Wa1 + (size_t)l * 384 * 128 + 256 * 128;
    const float* Wgl  = Wg  + (size_t)l * 128 * 8;
    const int b[3] = {cb >> 6, (cb >> 3) & 7, cb & 7};

    float s = 0.f;
    #pragma unroll
    for (int f = 0; f < 3; ++f) {
        const float* er = &bemb[(size_t)(f * 8 + b[f]) * 128];
        for (int k = 0; k < 128; ++k)
            s += er[k] * Wa1e[k * 128 + c];
    }
    float hi = __shfl_down(s, 1, 64);
    if ((c & 1) == 0)
        BAcb[(size_t)l * 512 * 64 + (size_t)cb * 64 + (c >> 1)] = pack2bf(s, hi);

    if (c < 8) {
        float g = 0.f;
        #pragma unroll
        for (int f = 0; f < 3; ++f) {
            const float* er = &bemb[(size_t)(f * 8 + b[f]) * 128];
            for (int k = 0; k < 128; ++k)
                g += er[k] * Wgl[k * 8 + c];
        }
        BGc[(size_t)l * 512 * 8 + (size_t)cb * 8 + c] = g;
    }
}

// ---------------- fused t1 + TA + TG table build ----------------
__global__ __launch_bounds__(256)
void k_t1ta(const float* __restrict__ W1, const float* __restrict__ b1,
            const float* __restrict__ W2A, const float* __restrict__ W2G,
            const float* __restrict__ bA, const float* __restrict__ bG,
            uint* __restrict__ TAb, float* __restrict__ TG)
{
    __shared__ float rbf_s[8][32];
    __shared__ int   bs_s[8];
    __shared__ float t1_s[8][132];
    const int l = blockIdx.y, tid = threadIdx.x;
    const int r0 = blockIdx.x * 8;

    {
        int ri = tid >> 5, j = tid & 31;
        int row = min(r0 + ri, TBM);
        float d = (float)row * (5.0f / TBM);
        const float step = 5.0f / 511.0f;
        const float invw = 512.0f / 5.0f;
        int b0 = (int)(d * (511.0f / 5.0f) + 0.5f);
        int bs = min(max(b0 - 16, 0), 512 - 32);
        if (j == 0) bs_s[ri] = bs;
        float z = (d - (float)(bs + j) * step) * invw;
        rbf_s[ri][j] = __expf(-z * z);
    }
    __syncthreads();

    #pragma unroll
    for (int pass = 0; pass < 4; ++pass) {
        int idx = pass * 256 + tid;
        int ri = idx >> 7, c = idx & 127;
        int bs = bs_s[ri];
        float t = b1[c];
        #pragma unroll
        for (int j = 0; j < 32; ++j)
            t += rbf_s[ri][j] * W1[(bs + j) * 128 + c];
        t1_s[ri][c] = siluf(t);
    }
    __syncthreads();

    const float* W2Al = W2A + (size_t)l * 16384;
    const int c = tid & 127, ng = tid >> 7;
    float a[4];
    #pragma unroll
    for (int r = 0; r < 4; ++r) a[r] = bA[l * 128 + c];
    #pragma unroll 4
    for (int k4 = 0; k4 < 128; k4 += 4) {
        float w0 = W2Al[(k4 + 0) * 128 + c];
        float w1 = W2Al[(k4 + 1) * 128 + c];
        float w2v = W2Al[(k4 + 2) * 128 + c];
        float w3 = W2Al[(k4 + 3) * 128 + c];
        #pragma unroll
        for (int r = 0; r < 4; ++r) {
            const float4 xv = *reinterpret_cast<const float4*>(&t1_s[ng * 4 + r][k4]);
            a[r] += xv.x * w0 + xv.y * w1 + xv.z * w2v + xv.w * w3;
        }
    }
    #pragma unroll
    for (int r = 0; r < 4; ++r) {
        float hi = __shfl_down(a[r], 1, 64);
        int row = r0 + ng * 4 + r;
        if (((c & 1) == 0) && row <= TBM)
            TAb[(size_t)l * TROWS * 64 + (size_t)row * 64 + (c >> 1)] = pack2bf(a[r], hi);
    }

    if (tid < 64) {
        int ri = tid >> 3, h = tid & 7;
        int row = r0 + ri;
        if (row <= TBM) {
            const float* W2Gl = W2G + (size_t)l * 1024;
            float s = bG[l * 8 + h];
            #pragma unroll 8
            for (int k = 0; k < 128; ++k)
                s += t1_s[ri][k] * W2Gl[k * 8 + h];
            TG[(size_t)l * TROWS * 8 + (size_t)row * 8 + h] = s;
        }
    }
}

// ---------------- pack weights into MFMA B-fragment order (bf16) ----------------
__global__ __launch_bounds__(64)
void k_packw(const float* __restrict__ Wf1, const float* __restrict__ Wf2,
             const float* __restrict__ Wv, const float* __restrict__ Wa1,
             ushort* __restrict__ Wf1x, ushort* __restrict__ Wf2x,
             ushort* __restrict__ Wvx, ushort* __restrict__ Wa1sx,
             ushort* __restrict__ Wa1dx)
{
    const int l = blockIdx.y, bx = blockIdx.x, lane = threadIdx.x;
    if (bx < 128) {
        const int nt = bx >> 2, kt = bx & 3;
        const float* src = Wf1 + (size_t)l * 65536;
        ushort* dst = Wf1x + (size_t)l * 65536 + ((size_t)bx * 64 + lane) * 8;
        #pragma unroll
        for (int j = 0; j < 8; ++j)
            dst[j] = f2bf(src[(size_t)(kt * 32 + (lane >> 4) * 8 + j) * 512 + nt * 16 + (lane & 15)]);
    } else if (bx < 256) {
        const int b2x = bx - 128;
        const int nt = b2x >> 4, kt = b2x & 15;
        const float* src = Wf2 + (size_t)l * 65536;
        ushort* dst = Wf2x + (size_t)l * 65536 + ((size_t)b2x * 64 + lane) * 8;
        #pragma unroll
        for (int j = 0; j < 8; ++j)
            dst[j] = f2bf(src[(size_t)(kt * 32 + (lane >> 4) * 8 + j) * 128 + nt * 16 + (lane & 15)]);
    } else {
        const int b3 = bx - 256;
        const int mat = b3 >> 5, blk = b3 & 31;
        const int nt = blk >> 2, kt = blk & 3;
        const float* src;
        ushort* dst;
        if (mat == 0)      { src = Wv  + (size_t)l * 16384;             dst = Wvx   + (size_t)l * 16384; }
        else if (mat == 1) { src = Wa1 + (size_t)l * 384 * 128;         dst = Wa1sx + (size_t)l * 16384; }
        else               { src = Wa1 + (size_t)l * 384 * 128 + 16384; dst = Wa1dx + (size_t)l * 16384; }
        dst += ((size_t)blk * 64 + lane) * 8;
        #pragma unroll
        for (int j = 0; j < 8; ++j)
            dst[j] = f2bf(src[(size_t)(kt * 32 + (lane >> 4) * 8 + j) * 128 + nt * 16 + (lane & 15)]);
    }
}

// ---------------- shared device helper: 3 node GEMMs from a_s ----------------
__device__ __forceinline__
void node_gemm3(const ushort a_s[16][136], int tid, int n0,
                const ushort* __restrict__ Wvx, const ushort* __restrict__ Wa1sx,
                const ushort* __restrict__ Wa1dx,
                uint* __restrict__ Vb, uint* __restrict__ Psb, uint* __restrict__ Pdb)
{
    const int l = tid & 63, wq = tid >> 6;
    const int lr = l & 15, lk = l >> 4;
    #pragma unroll
    for (int jb = 0; jb < 6; ++jb) {
        int job = wq * 6 + jb;
        int mat = job >> 3, nt = job & 7;
        const ushort* W = (mat == 0) ? Wvx : (mat == 1 ? Wa1sx : Wa1dx);
        uint* O = (mat == 0) ? Vb : (mat == 1 ? Psb : Pdb);
        float4v acc = (float4v){0.f, 0.f, 0.f, 0.f};
        #pragma unroll
        for (int ks = 0; ks < 4; ++ks) {
            short8v af = *reinterpret_cast<const short8v*>(&a_s[lr][lk * 8 + ks * 32]);
            short8v bf = *reinterpret_cast<const short8v*>(&W[((size_t)(nt * 4 + ks) * 64 + l) * 8]);
            acc = __builtin_amdgcn_mfma_f32_16x16x32_bf16(af, bf, acc, 0, 0, 0);
        }
        #pragma unroll
        for (int r = 0; r < 4; ++r) {
            float v = acc[r];
            float vn = __shfl_xor(v, 1, 64);
            if ((l & 1) == 0) {
                int row = lk * 4 + r, col = nt * 16 + lr;
                O[(size_t)(n0 + row) * 64 + (col >> 1)] = pack2bf(v, vn);
            }
        }
    }
}

// ---------------- fused atom-embed + rms + 3 node GEMMs (16 nodes/block) ----------------
__global__ __launch_bounds__(256)
void k_embedgemm(const int* __restrict__ af, const float* __restrict__ aemb,
                 float* __restrict__ x, int* __restrict__ deg,
                 const ushort* __restrict__ Wvx, const ushort* __restrict__ Wa1sx,
                 const ushort* __restrict__ Wa1dx,
                 uint* __restrict__ Vb, uint* __restrict__ Psb, uint* __restrict__ Pdb)
{
    __shared__ ushort a_s[16][136];
    const int tid = threadIdx.x, n0 = blockIdx.x * 16;
    if (tid < 16) deg[n0 + tid] = 0;

    {
        int ni = tid >> 4, c8 = (tid & 15) * 8;
        int n = n0 + ni;
        float v[8];
        #pragma unroll
        for (int q = 0; q < 8; ++q) v[q] = 0.f;
        #pragma unroll
        for (int f = 0; f < 4; ++f) {
            int idx = af[n * 4 + f];
            const float* er = &aemb[(size_t)(f * 10 + idx) * 128 + c8];
            float4 e0 = *reinterpret_cast<const float4*>(er);
            float4 e1 = *reinterpret_cast<const float4*>(er + 4);
            v[0] += e0.x; v[1] += e0.y; v[2] += e0.z; v[3] += e0.w;
            v[4] += e1.x; v[5] += e1.y; v[6] += e1.z; v[7] += e1.w;
        }
        float* xr = &x[(size_t)n * 128 + c8];
        *reinterpret_cast<float4*>(xr)     = make_float4(v[0], v[1], v[2], v[3]);
        *reinterpret_cast<float4*>(xr + 4) = make_float4(v[4], v[5], v[6], v[7]);
        float ss = 0.f;
        #pragma unroll
        for (int q = 0; q < 8; ++q) ss += v[q] * v[q];
        #pragma unroll
        for (int m = 1; m < 16; m <<= 1) ss += __shfl_xor(ss, m, 16);
        float r = rsqrtf(ss * (1.0f / 1152.0f) + 1e-6f);
        uint4 pk;
        pk.x = pack2bf(v[0] * r, v[1] * r);
        pk.y = pack2bf(v[2] * r, v[3] * r);
        pk.z = pack2bf(v[4] * r, v[5] * r);
        pk.w = pack2bf(v[6] * r, v[7] * r);
        *reinterpret_cast<uint4*>(&a_s[ni][c8]) = pk;
    }
    __syncthreads();
    node_gemm3(a_s, tid, n0, Wvx, Wa1sx, Wa1dx, Vb, Psb, Pdb);
}

// ---------------- CSR build ----------------
__global__ __launch_bounds__(256)
void k_hist(const int* __restrict__ eidx, int* __restrict__ deg)
{
    int e = blockIdx.x * 256 + threadIdx.x;
    if (e < NE) atomicAdd(&deg[eidx[NE + e]], 1);
}

__global__ __launch_bounds__(1024)
void k_scan(const int* __restrict__ deg, int* __restrict__ off, int* __restrict__ cursor)
{
    __shared__ int part[1024];
    const int t = threadIdx.x;
    const int base = t * 6;
    int loc[6]; int s = 0;
    #pragma unroll
    for (int i = 0; i < 6; ++i) {
        int d = (base + i < NN) ? deg[base + i] : 0;
        loc[i] = s; s += d;
    }
    part[t] = s;
    __syncthreads();
    for (int o = 1; o < 1024; o <<= 1) {
        int v = (t >= o) ? part[t - o] : 0;
        __syncthreads();
        part[t] += v;
        __syncthreads();
    }
    int pre = (t > 0) ? part[t - 1] : 0;
    #pragma unroll
    for (int i = 0; i < 6; ++i) {
        if (base + i < NN) {
            int v = pre + loc[i];
            off[base + i] = v;
            cursor[base + i] = v;
        }
    }
    if (t == 1023) off[NN] = part[1023];
}

__global__ __launch_bounds__(256)
void k_fill(const int* __restrict__ eidx, const int* __restrict__ bondf,
            const float* __restrict__ dist, int* __restrict__ cursor,
            int* __restrict__ srcp, int* __restrict__ dstp,
            float* __restrict__ distp, int* __restrict__ cbp)
{
    int e = blockIdx.x * 256 + threadIdx.x;
    if (e < NE) {
        int d = eidx[NE + e];
        int p = atomicAdd(&cursor[d], 1);
        srcp[p] = eidx[e];
        dstp[p] = d;
        distp[p] = dist[e];
        cbp[p] = bondf[e * 3 + 0] * 64 + bondf[e * 3 + 1] * 8 + bondf[e * 3 + 2];
    }
}

// ---------------- attention: two-phase LDS (proven structure), CSR-ordered inputs ----------------
__global__ __launch_bounds__(256)
void k_attn(const int* __restrict__ srcp, const int* __restrict__ dstp,
            const float* __restrict__ distp, const int* __restrict__ cbp,
            const uint* __restrict__ Psb, const uint* __restrict__ Pdb,
            const uint* __restrict__ TAbl, const float* __restrict__ TGl,
            const uint* __restrict__ BAcbl, const float* __restrict__ BGcl,
            const float* __restrict__ Wa2l,
            float* __restrict__ num, float* __restrict__ exs)
{
    __shared__ float t_s[32][132];
    __shared__ float gate_s[32][8];
    const int tid = threadIdx.x;
    const int p0 = blockIdx.x * 32;

    {   // phase A: per (edge, 16-channel group)
        const int ei = tid >> 3, g = tid & 7;
        const int p = min(p0 + ei, NE - 1);
        const int sn = srcp[p], dn = dstp[p];
        const float d = distp[p];
        const int cb = cbp[p];
        float u = d * ((float)TBM / 5.0f);
        int i = min((int)u, TBM - 1);
        float f = u - (float)i, f1 = 1.f - f;

        uint ps[8], pd[8], t0[8], t1v[8], ba[8];
        {
            const uint4* pp = reinterpret_cast<const uint4*>(&Psb[(size_t)sn * 64 + g * 8]);
            uint4 a = pp[0], b = pp[1];
            ps[0]=a.x; ps[1]=a.y; ps[2]=a.z; ps[3]=a.w; ps[4]=b.x; ps[5]=b.y; ps[6]=b.z; ps[7]=b.w;
            pp = reinterpret_cast<const uint4*>(&Pdb[(size_t)dn * 64 + g * 8]);
            a = pp[0]; b = pp[1];
            pd[0]=a.x; pd[1]=a.y; pd[2]=a.z; pd[3]=a.w; pd[4]=b.x; pd[5]=b.y; pd[6]=b.z; pd[7]=b.w;
            pp = reinterpret_cast<const uint4*>(&TAbl[(size_t)i * 64 + g * 8]);
            a = pp[0]; b = pp[1];
            t0[0]=a.x; t0[1]=a.y; t0[2]=a.z; t0[3]=a.w; t0[4]=b.x; t0[5]=b.y; t0[6]=b.z; t0[7]=b.w;
            pp = reinterpret_cast<const uint4*>(&TAbl[(size_t)(i + 1) * 64 + g * 8]);
            a = pp[0]; b = pp[1];
            t1v[0]=a.x; t1v[1]=a.y; t1v[2]=a.z; t1v[3]=a.w; t1v[4]=b.x; t1v[5]=b.y; t1v[6]=b.z; t1v[7]=b.w;
            pp = reinterpret_cast<const uint4*>(&BAcbl[(size_t)cb * 64 + g * 8]);
            a = pp[0]; b = pp[1];
            ba[0]=a.x; ba[1]=a.y; ba[2]=a.z; ba[3]=a.w; ba[4]=b.x; ba[5]=b.y; ba[6]=b.z; ba[7]=b.w;
        }
        float* tr = &t_s[ei][g * 16];
        #pragma unroll
        for (int q = 0; q < 8; ++q) {
            float2 vs = up2(ps[q]), vd = up2(pd[q]), v0 = up2(t0[q]), v1 = up2(t1v[q]), vb = up2(ba[q]);
            tr[2 * q + 0] = siluf(vs.x + vd.x + f1 * v0.x + f * v1.x + vb.x);
            tr[2 * q + 1] = siluf(vs.y + vd.y + f1 * v0.y + f * v1.y + vb.y);
        }
        if (g == 0) {
            const float4* tg0 = reinterpret_cast<const float4*>(&TGl[(size_t)i * 8]);
            const float4* bg4 = reinterpret_cast<const float4*>(&BGcl[(size_t)cb * 8]);
            #pragma unroll
            for (int q = 0; q < 2; ++q) {
                float4 g0 = tg0[q], g1 = tg0[q + 2], bb = bg4[q];
                gate_s[ei][4 * q + 0] = f1 * g0.x + f * g1.x + bb.x;
                gate_s[ei][4 * q + 1] = f1 * g0.y + f * g1.y + bb.y;
                gate_s[ei][4 * q + 2] = f1 * g0.z + f * g1.z + bb.z;
                gate_s[ei][4 * q + 3] = f1 * g0.w + f * g1.w + bb.w;
            }
        }
    }
    __syncthreads();

    {   // phase B: per (edge, head)
        const int ei = tid >> 3, h = tid & 7;
        const int p = p0 + ei;
        float lg = 0.f;
        for (int j4 = 0; j4 < 128; j4 += 4) {
            const float4 tv = *reinterpret_cast<const float4*>(&t_s[ei][j4]);
            lg += tv.x * Wa2l[(j4 + 0) * 8 + h] + tv.y * Wa2l[(j4 + 1) * 8 + h]
                + tv.z * Wa2l[(j4 + 2) * 8 + h] + tv.w * Wa2l[(j4 + 3) * 8 + h];
        }
        if (p < NE) {
            float ex = __expf(lg);
            num[(size_t)p * 8 + h] = ex * sigmf(gate_s[ei][h]);
            exs[(size_t)p * 8 + h] = ex;
        }
    }
}

// ---------------- fused aggregate (+denominator) + out_proj ----------------
__global__ __launch_bounds__(128)
void k_aggo(const int* __restrict__ off, const int* __restrict__ srcp,
            const float* __restrict__ num, const float* __restrict__ exs,
            const uint* __restrict__ Vb, const float* __restrict__ Wol,
            float* __restrict__ x)
{
    __shared__ float a_s[128];
    const int n = blockIdx.x, c = threadIdx.x;
    const int s = off[n], t = off[n + 1];
    const int h = c >> 4, cd = c >> 1, sel = c & 1;
    float acc = 0.f, es = 0.f;
    int p = s;
    for (; p + 4 <= t; p += 4) {
        int sn0 = srcp[p + 0], sn1 = srcp[p + 1], sn2 = srcp[p + 2], sn3 = srcp[p + 3];
        float cf0 = num[(size_t)(p + 0) * 8 + h];
        float cf1 = num[(size_t)(p + 1) * 8 + h];
        float cf2 = num[(size_t)(p + 2) * 8 + h];
        float cf3 = num[(size_t)(p + 3) * 8 + h];
        es += exs[(size_t)(p + 0) * 8 + h] + exs[(size_t)(p + 1) * 8 + h]
            + exs[(size_t)(p + 2) * 8 + h] + exs[(size_t)(p + 3) * 8 + h];
        uint u0 = Vb[(size_t)sn0 * 64 + cd];
        uint u1 = Vb[(size_t)sn1 * 64 + cd];
        uint u2 = Vb[(size_t)sn2 * 64 + cd];
        uint u3 = Vb[(size_t)sn3 * 64 + cd];
        float v0 = sel ? __uint_as_float(u0 & 0xffff0000u) : __uint_as_float(u0 << 16);
        float v1 = sel ? __uint_as_float(u1 & 0xffff0000u) : __uint_as_float(u1 << 16);
        float v2 = sel ? __uint_as_float(u2 & 0xffff0000u) : __uint_as_float(u2 << 16);
        float v3 = sel ? __uint_as_float(u3 & 0xffff0000u) : __uint_as_float(u3 << 16);
        acc += cf0 * v0 + cf1 * v1 + cf2 * v2 + cf3 * v3;
    }
    for (; p < t; ++p) {
        int sn = srcp[p];
        float cf = num[(size_t)p * 8 + h];
        es += exs[(size_t)p * 8 + h];
        uint u = Vb[(size_t)sn * 64 + cd];
        float v = sel ? __uint_as_float(u & 0xffff0000u) : __uint_as_float(u << 16);
        acc += cf * v;
    }
    a_s[c] = acc / (es + 1e-9f);
    __syncthreads();
    float o = 0.f;
    #pragma unroll 4
    for (int j4 = 0; j4 < 128; j4 += 4) {
        const float4 a4 = *reinterpret_cast<const float4*>(&a_s[j4]);
        o += a4.x * Wol[(j4 + 0) * 128 + c] + a4.y * Wol[(j4 + 1) * 128 + c]
           + a4.z * Wol[(j4 + 2) * 128 + c] + a4.w * Wol[(j4 + 3) * 128 + c];
    }
    x[n * 128 + c] += o;
}

// ---------------- fused rms + FFN (+ next-layer GEMMs, or finalize) ----------------
template<int LAST>
__global__ __launch_bounds__(256)
void k_ffn_fused(float* __restrict__ x, const ushort* __restrict__ Wf1xl,
                 const ushort* __restrict__ Wf2xl, float* __restrict__ out,
                 const ushort* __restrict__ WvxN, const ushort* __restrict__ Wa1sxN,
                 const ushort* __restrict__ Wa1dxN,
                 uint* __restrict__ Vb, uint* __restrict__ Psb, uint* __restrict__ Pdb)
{
    __shared__ ushort a_s[16][136];
    __shared__ ushort h_s[16][520];
    __shared__ float xf_s[16][132];
    const int tid = threadIdx.x;
    const int n0 = blockIdx.x * 16;

    {   // rms prologue + stash x_old
        int ni = tid >> 4, c8 = (tid & 15) * 8;
        const float* xr = &x[(size_t)(n0 + ni) * 128 + c8];
        float4 v0 = *reinterpret_cast<const float4*>(xr);
        float4 v1 = *reinterpret_cast<const float4*>(xr + 4);
        *reinterpret_cast<float4*>(&xf_s[ni][c8]) = v0;
        *reinterpret_cast<float4*>(&xf_s[ni][c8 + 4]) = v1;
        float ss = v0.x * v0.x + v0.y * v0.y + v0.z * v0.z + v0.w * v0.w
                 + v1.x * v1.x + v1.y * v1.y + v1.z * v1.z + v1.w * v1.w;
        #pragma unroll
        for (int m = 1; m < 16; m <<= 1) ss += __shfl_xor(ss, m, 16);
        float r = rsqrtf(ss * (1.0f / 1152.0f) + 1e-6f);
        uint4 pk;
        pk.x = pack2bf(v0.x * r, v0.y * r);
        pk.y = pack2bf(v0.z * r, v0.w * r);
        pk.z = pack2bf(v1.x * r, v1.y * r);
        pk.w = pack2bf(v1.z * r, v1.w * r);
        *reinterpret_cast<uint4*>(&a_s[ni][c8]) = pk;
    }
    __syncthreads();

    const int l  = tid & 63;
    const int wq = tid >> 6;
    const int lr = l & 15, lk = l >> 4;

    float4v acc[8];
    #pragma unroll
    for (int nf = 0; nf < 8; ++nf) acc[nf] = (float4v){0.f, 0.f, 0.f, 0.f};
    #pragma unroll
    for (int ks = 0; ks < 4; ++ks) {
        short8v af = *reinterpret_cast<const short8v*>(&a_s[lr][lk * 8 + ks * 32]);
        #pragma unroll
        for (int nf = 0; nf < 8; ++nf) {
            int nt = wq * 8 + nf;
            short8v bf = *reinterpret_cast<const short8v*>(&Wf1xl[((size_t)(nt * 4 + ks) * 64 + l) * 8]);
            acc[nf] = __builtin_amdgcn_mfma_f32_16x16x32_bf16(af, bf, acc[nf], 0, 0, 0);
        }
    }
    #pragma unroll
    for (int nf = 0; nf < 8; ++nf) {
        #pragma unroll
        for (int r = 0; r < 4; ++r) {
            float v = siluf(acc[nf][r]);
            float vn = __shfl_xor(v, 1, 64);
            if ((l & 1) == 0) {
                int row = lk * 4 + r;
                int col = wq * 128 + nf * 16 + lr;
                *reinterpret_cast<uint*>(&h_s[row][col]) = pack2bf(v, vn);
            }
        }
    }
    __syncthreads();

    float4v acc2[2];
    acc2[0] = (float4v){0.f, 0.f, 0.f, 0.f};
    acc2[1] = (float4v){0.f, 0.f, 0.f, 0.f};
    #pragma unroll 4
    for (int ks = 0; ks < 16; ++ks) {
        short8v af = *reinterpret_cast<const short8v*>(&h_s[lr][lk * 8 + ks * 32]);
        #pragma unroll
        for (int nf = 0; nf < 2; ++nf) {
            int nt = wq * 2 + nf;
            short8v bf = *reinterpret_cast<const short8v*>(&Wf2xl[((size_t)(nt * 16 + ks) * 64 + l) * 8]);
            acc2[nf] = __builtin_amdgcn_mfma_f32_16x16x32_bf16(af, bf, acc2[nf], 0, 0, 0);
        }
    }
    #pragma unroll
    for (int nf = 0; nf < 2; ++nf) {
        #pragma unroll
        for (int r = 0; r < 4; ++r) {
            int row = lk * 4 + r;
            int col = wq * 32 + nf * 16 + lr;
            xf_s[row][col] += acc2[nf][r];
        }
    }
    __syncthreads();

    int ni = tid >> 4, c8 = (tid & 15) * 8;
    float4 v0 = *reinterpret_cast<const float4*>(&xf_s[ni][c8]);
    float4 v1 = *reinterpret_cast<const float4*>(&xf_s[ni][c8 + 4]);
    float ss = v0.x * v0.x + v0.y * v0.y + v0.z * v0.z + v0.w * v0.w
             + v1.x * v1.x + v1.y * v1.y + v1.z * v1.z + v1.w * v1.w;
    #pragma unroll
    for (int m = 1; m < 16; m <<= 1) ss += __shfl_xor(ss, m, 16);
    float r = rsqrtf(ss * (1.0f / 1152.0f) + 1e-6f);

    if (!LAST) {
        float* xr = &x[(size_t)(n0 + ni) * 128 + c8];
        *reinterpret_cast<float4*>(xr)     = v0;
        *reinterpret_cast<float4*>(xr + 4) = v1;
        uint4 pk;
        pk.x = pack2bf(v0.x * r, v0.y * r);
        pk.y = pack2bf(v0.z * r, v0.w * r);
        pk.z = pack2bf(v1.x * r, v1.y * r);
        pk.w = pack2bf(v1.z * r, v1.w * r);
        __syncthreads();
        *reinterpret_cast<uint4*>(&a_s[ni][c8]) = pk;
        __syncthreads();
        node_gemm3(a_s, tid, n0, WvxN, Wa1sxN, Wa1dxN, Vb, Psb, Pdb);
    } else {
        size_t base = (size_t)(n0 + ni) * 1152 + c8;
        *reinterpret_cast<float4*>(&out[base])     = make_float4(v0.x * r, v0.y * r, v0.z * r, v0.w * r);
        *reinterpret_cast<float4*>(&out[base + 4]) = make_float4(v1.x * r, v1.y * r, v1.z * r, v1.w * r);
        const float4 z4 = make_float4(0.f, 0.f, 0.f, 0.f);
        #pragma unroll
        for (int k = 1; k < 9; ++k) {
            *reinterpret_cast<float4*>(&out[base + (size_t)k * 128]) = z4;
            *reinterpret_cast<float4*>(&out[base + (size_t)k * 128 + 4]) = z4;
        }
    }
}

extern "C" void kernel_launch(void* const* d_in, const int* in_sizes, int n_in,
                              void* d_out, int out_size, void* d_ws, size_t ws_size,
                              hipStream_t stream)
{
    const int*   atom_feats = (const int*)d_in[0];
    const int*   bond_feats = (const int*)d_in[1];
    const int*   edge_index = (const int*)d_in[2];
    const float* edge_dist  = (const float*)d_in[3];
    const float* atom_emb   = (const float*)d_in[4];
    const float* bond_emb   = (const float*)d_in[5];
    const float* W_rbf1     = (const float*)d_in[6];
    const float* b_rbf1     = (const float*)d_in[7];
    const float* W_rbf2     = (const float*)d_in[8];
    const float* b_rbf2     = (const float*)d_in[9];
    const float* Wa1        = (const float*)d_in[10];
    const float* Wa2        = (const float*)d_in[11];
    const float* Wv         = (const float*)d_in[12];
    const float* Wg         = (const float*)d_in[13];
    const float* Wo         = (const float*)d_in[14];
    const float* Wf1        = (const float*)d_in[15];
    const float* Wf2        = (const float*)d_in[16];
    float* out = (float*)d_out;

    float* ws   = (float*)d_ws;
    float* x    = ws;                           // NN*128
    float* num  = x    + NN * 128;              // NE*8 (CSR order)
    float* exs  = num  + (size_t)NE * 8;        // NE*8
    float* W2A  = exs  + (size_t)NE * 8;        // 2*16384
    float* W2G  = W2A  + 2 * 16384;             // 2*1024
    float* bA   = W2G  + 2 * 1024;              // 2*128
    float* bG   = bA   + 2 * 128;               // 16
    float* TG   = bG   + 16;                    // 2*TROWS*8
    float* BGc  = TG   + 2 * (size_t)TROWS * 8; // 2*512*8
    float* distp = BGc + 2 * 512 * 8;           // NE
    uint* Vb    = (uint*)(distp + NE);          // NN*64
    uint* Psb   = Vb  + NN * 64;
    uint* Pdb   = Psb + NN * 64;
    uint* TAb   = Pdb + NN * 64;                // 2*TROWS*64
    uint* BAcb  = TAb + 2 * (size_t)TROWS * 64; // 2*512*64
    ushort* Wf1x  = (ushort*)(BAcb + 2 * 512 * 64);  // 2*65536
    ushort* Wf2x  = Wf1x  + 2 * 65536;
    ushort* Wvx   = Wf2x  + 2 * 65536;
    ushort* Wa1sx = Wvx   + 2 * 16384;
    ushort* Wa1dx = Wa1sx + 2 * 16384;
    int* deg    = (int*)(Wa1dx + 2 * 16384);
    int* off    = deg + NN;
    int* cursor = off + NN + 1;
    int* srcp   = cursor + NN;                  // NE
    int* dstp   = srcp + NE;                    // NE
    int* cbp    = dstp + NE;                    // NE

    // tables + packed weights (once per call)
    k_w2a<<<dim3(18, 2), 256, 0, stream>>>(W_rbf2, b_rbf2, Wa1, Wg, W2A, W2G, bA, bG);
    k_bondtabs<<<dim3(512, 2), 128, 0, stream>>>(bond_emb, Wa1, Wg, BAcb, BGc);
    k_packw<<<dim3(352, 2), 64, 0, stream>>>(Wf1, Wf2, Wv, Wa1, Wf1x, Wf2x, Wvx, Wa1sx, Wa1dx);
    k_t1ta<<<dim3((TBM + 8) / 8, 2), 256, 0, stream>>>(W_rbf1, b_rbf1, W2A, W2G, bA, bG, TAb, TG);

    // embed + layer-0 rms/GEMMs (also zeroes deg)
    k_embedgemm<<<NN / 16, 256, 0, stream>>>(atom_feats, atom_emb, x, deg,
                                             Wvx, Wa1sx, Wa1dx, Vb, Psb, Pdb);

    // CSR (dst is layer-invariant)
    k_hist<<<(NE + 255) / 256, 256, 0, stream>>>(edge_index, deg);
    k_scan<<<1, 1024, 0, stream>>>(deg, off, cursor);
    k_fill<<<(NE + 255) / 256, 256, 0, stream>>>(edge_index, bond_feats, edge_dist,
                                                 cursor, srcp, dstp, distp, cbp);

    for (int l = 0; l < 2; ++l) {
        k_attn<<<(NE + 31) / 32, 256, 0, stream>>>(srcp, dstp, distp, cbp,
            Psb, Pdb,
            TAb + (size_t)l * TROWS * 64, TG + (size_t)l * TROWS * 8,
            BAcb + (size_t)l * 512 * 64, BGc + (size_t)l * 512 * 8,
            Wa2 + (size_t)l * 128 * 8, num, exs);
        k_aggo<<<NN, 128, 0, stream>>>(off, srcp, num, exs, Vb,
                                       Wo + (size_t)l * 128 * 128, x);
        if (l == 0)
            k_ffn_fused<0><<<NN / 16, 256, 0, stream>>>(x,
                Wf1x, Wf2x, out,
                Wvx + 16384, Wa1sx + 16384, Wa1dx + 16384, Vb, Psb, Pdb);
        else
            k_ffn_fused<1><<<NN / 16, 256, 0, stream>>>(x,
                Wf1x + 65536, Wf2x + 65536, out,
                Wvx, Wa1sx, Wa1dx, Vb, Psb, Pdb);
    }
}

// Round 10
// 211.883 us; speedup vs baseline: 1.5226x; 1.1108x over previous
//
#include <hip/hip_runtime.h>

#define NN 6000
#define NE 150000
#define TBM 2048
#define TROWS (TBM + 1)

typedef unsigned int uint;
typedef unsigned short ushort;
typedef __attribute__((ext_vector_type(8))) short short8v;
typedef __attribute__((ext_vector_type(4))) float float4v;

__device__ __forceinline__ float siluf(float x) { return x / (1.f + __expf(-x)); }
__device__ __forceinline__ float sigmf(float x) { return 1.f / (1.f + __expf(-x)); }
__device__ __forceinline__ uint pack2bf(float lo, float hi) {
    uint ul = __float_as_uint(lo);
    ul = (ul + 0x7fffu + ((ul >> 16) & 1u)) >> 16;
    uint uh = __float_as_uint(hi);
    uh = ((uh + 0x7fffu + ((uh >> 16) & 1u)) >> 16) << 16;
    return ul | uh;
}
__device__ __forceinline__ ushort f2bf(float f) {
    uint u = __float_as_uint(f);
    return (ushort)((u + 0x7fffu + ((u >> 16) & 1u)) >> 16);
}
__device__ __forceinline__ float2 up2(uint u) {
    return make_float2(__uint_as_float(u << 16), __uint_as_float(u & 0xffff0000u));
}

// ================ k_prep: w2a (bx<18) | bondtabs (18..274) | packw (274..363) ================
__global__ __launch_bounds__(256)
void k_prep(const float* __restrict__ W2, const float* __restrict__ b2,
            const float* __restrict__ Wa1, const float* __restrict__ Wg,
            const float* __restrict__ bemb,
            const float* __restrict__ Wf1, const float* __restrict__ Wf2,
            const float* __restrict__ Wv, const float* __restrict__ Wa2,
            float* __restrict__ W2A, float* __restrict__ W2G,
            float* __restrict__ bA, float* __restrict__ bG,
            uint* __restrict__ BAcb, float* __restrict__ BGc,
            ushort* __restrict__ Wf1x, ushort* __restrict__ Wf2x,
            ushort* __restrict__ Wvx, ushort* __restrict__ Wa1sx,
            ushort* __restrict__ Wa1dx, ushort* __restrict__ Wa2x)
{
    __shared__ float w2_s[8][132];
    const int l = blockIdx.y, bx = blockIdx.x, tid = threadIdx.x;
    const float* Wa1e = Wa1 + (size_t)l * 384 * 128 + 256 * 128;
    const float* Wgl  = Wg  + (size_t)l * 128 * 8;

    if (bx < 16) {
        const int i0 = bx * 8;
        for (int q = tid; q < 8 * 32; q += 256) {
            int ni = q >> 5, j4 = (q & 31) * 4;
            *reinterpret_cast<float4*>(&w2_s[ni][j4]) =
                *reinterpret_cast<const float4*>(&W2[(size_t)(i0 + ni) * 128 + j4]);
        }
        __syncthreads();
        const int j = tid & 127, ng = tid >> 7;
        float a[4] = {0.f, 0.f, 0.f, 0.f};
        #pragma unroll 4
        for (int k4 = 0; k4 < 128; k4 += 4) {
            float w0 = Wa1e[(k4 + 0) * 128 + j];
            float w1 = Wa1e[(k4 + 1) * 128 + j];
            float w2v = Wa1e[(k4 + 2) * 128 + j];
            float w3 = Wa1e[(k4 + 3) * 128 + j];
            #pragma unroll
            for (int r = 0; r < 4; ++r) {
                const float4 xv = *reinterpret_cast<const float4*>(&w2_s[ng * 4 + r][k4]);
                a[r] += xv.x * w0 + xv.y * w1 + xv.z * w2v + xv.w * w3;
            }
        }
        #pragma unroll
        for (int r = 0; r < 4; ++r)
            W2A[(size_t)l * 16384 + (size_t)(i0 + ng * 4 + r) * 128 + j] = a[r];
    } else if (bx == 16) {
        const int i = tid & 127, hq = tid >> 7;
        float a[4] = {0.f, 0.f, 0.f, 0.f};
        for (int k = 0; k < 128; ++k) {
            float w = W2[(size_t)i * 128 + k];
            const float4 g4 = *reinterpret_cast<const float4*>(&Wgl[k * 8 + hq * 4]);
            a[0] += w * g4.x; a[1] += w * g4.y; a[2] += w * g4.z; a[3] += w * g4.w;
        }
        #pragma unroll
        for (int q = 0; q < 4; ++q)
            W2G[(size_t)l * 1024 + (size_t)i * 8 + hq * 4 + q] = a[q];
    } else if (bx == 17) {
        if (tid < 128) {
            float s = 0.f;
            for (int k = 0; k < 128; ++k) s += b2[k] * Wa1e[k * 128 + tid];
            bA[l * 128 + tid] = s;
        } else if (tid < 136) {
            int h = tid - 128;
            float s = 0.f;
            for (int k = 0; k < 128; ++k) s += b2[k] * Wgl[k * 8 + h];
            bG[l * 8 + h] = s;
        }
    } else if (bx < 274) {
        // bond-combo tables, 2 cb per block
        const int cb = (bx - 18) * 2 + (tid >> 7);
        const int c = tid & 127;
        const int b[3] = {cb >> 6, (cb >> 3) & 7, cb & 7};
        float s = 0.f;
        #pragma unroll
        for (int f = 0; f < 3; ++f) {
            const float* er = &bemb[(size_t)(f * 8 + b[f]) * 128];
            for (int k = 0; k < 128; ++k)
                s += er[k] * Wa1e[k * 128 + c];
        }
        float hi = __shfl_down(s, 1, 64);
        if ((c & 1) == 0)
            BAcb[(size_t)l * 512 * 64 + (size_t)cb * 64 + (c >> 1)] = pack2bf(s, hi);
        if (c < 8) {
            float g = 0.f;
            #pragma unroll
            for (int f = 0; f < 3; ++f) {
                const float* er = &bemb[(size_t)(f * 8 + b[f]) * 128];
                for (int k = 0; k < 128; ++k)
                    g += er[k] * Wgl[k * 8 + c];
            }
            BGc[(size_t)l * 512 * 8 + (size_t)cb * 8 + c] = g;
        }
    } else {
        // weight packing: 4 sub-blocks per block
        const int sub = (bx - 274) * 4 + (tid >> 6);
        const int lane = tid & 63;
        if (sub < 128) {
            const int nt = sub >> 2, kt = sub & 3;
            const float* src = Wf1 + (size_t)l * 65536;
            ushort* dst = Wf1x + (size_t)l * 65536 + ((size_t)sub * 64 + lane) * 8;
            #pragma unroll
            for (int j = 0; j < 8; ++j)
                dst[j] = f2bf(src[(size_t)(kt * 32 + (lane >> 4) * 8 + j) * 512 + nt * 16 + (lane & 15)]);
        } else if (sub < 256) {
            const int b2x = sub - 128;
            const int nt = b2x >> 4, kt = b2x & 15;
            const float* src = Wf2 + (size_t)l * 65536;
            ushort* dst = Wf2x + (size_t)l * 65536 + ((size_t)b2x * 64 + lane) * 8;
            #pragma unroll
            for (int j = 0; j < 8; ++j)
                dst[j] = f2bf(src[(size_t)(kt * 32 + (lane >> 4) * 8 + j) * 128 + nt * 16 + (lane & 15)]);
        } else if (sub < 352) {
            const int b3 = sub - 256;
            const int mat = b3 >> 5, blk = b3 & 31;
            const int nt = blk >> 2, kt = blk & 3;
            const float* src;
            ushort* dst;
            if (mat == 0)      { src = Wv  + (size_t)l * 16384;             dst = Wvx   + (size_t)l * 16384; }
            else if (mat == 1) { src = Wa1 + (size_t)l * 384 * 128;         dst = Wa1sx + (size_t)l * 16384; }
            else               { src = Wa1 + (size_t)l * 384 * 128 + 16384; dst = Wa1dx + (size_t)l * 16384; }
            dst += ((size_t)blk * 64 + lane) * 8;
            #pragma unroll
            for (int j = 0; j < 8; ++j)
                dst[j] = f2bf(src[(size_t)(kt * 32 + (lane >> 4) * 8 + j) * 128 + nt * 16 + (lane & 15)]);
        } else {
            // Wa2x: B-fragments for phase-B MFMA, N=16 (cols 8..15 zero)
            const int kt = sub - 352;        // 0..3
            const int col = lane & 15;
            const float* src = Wa2 + (size_t)l * 128 * 8;
            ushort* dst = Wa2x + (size_t)l * 2048 + ((size_t)kt * 64 + lane) * 8;
            #pragma unroll
            for (int j = 0; j < 8; ++j) {
                int krow = kt * 32 + (lane >> 4) * 8 + j;
                dst[j] = (col < 8) ? f2bf(src[(size_t)krow * 8 + col]) : (ushort)0;
            }
        }
    }
}

// ---------------- shared device helper: 3 node GEMMs from a_s ----------------
__device__ __forceinline__
void node_gemm3(const ushort a_s[16][136], int tid, int n0,
                const ushort* __restrict__ Wvx, const ushort* __restrict__ Wa1sx,
                const ushort* __restrict__ Wa1dx,
                uint* __restrict__ Vb, uint* __restrict__ Psb, uint* __restrict__ Pdb)
{
    const int l = tid & 63, wq = tid >> 6;
    const int lr = l & 15, lk = l >> 4;
    #pragma unroll
    for (int jb = 0; jb < 6; ++jb) {
        int job = wq * 6 + jb;
        int mat = job >> 3, nt = job & 7;
        const ushort* W = (mat == 0) ? Wvx : (mat == 1 ? Wa1sx : Wa1dx);
        uint* O = (mat == 0) ? Vb : (mat == 1 ? Psb : Pdb);
        float4v acc = (float4v){0.f, 0.f, 0.f, 0.f};
        #pragma unroll
        for (int ks = 0; ks < 4; ++ks) {
            short8v af = *reinterpret_cast<const short8v*>(&a_s[lr][lk * 8 + ks * 32]);
            short8v bf = *reinterpret_cast<const short8v*>(&W[((size_t)(nt * 4 + ks) * 64 + l) * 8]);
            acc = __builtin_amdgcn_mfma_f32_16x16x32_bf16(af, bf, acc, 0, 0, 0);
        }
        #pragma unroll
        for (int r = 0; r < 4; ++r) {
            float v = acc[r];
            float vn = __shfl_xor(v, 1, 64);
            if ((l & 1) == 0) {
                int row = lk * 4 + r, col = nt * 16 + lr;
                O[(size_t)(n0 + row) * 64 + (col >> 1)] = pack2bf(v, vn);
            }
        }
    }
}

// ================ k_prep2: t1ta (bx<514) | embed+gemm (bx>=514) ================
__global__ __launch_bounds__(256)
void k_prep2(const float* __restrict__ W1, const float* __restrict__ b1,
             const float* __restrict__ W2A, const float* __restrict__ W2G,
             const float* __restrict__ bA, const float* __restrict__ bG,
             uint* __restrict__ TAb, float* __restrict__ TG,
             const int* __restrict__ af, const float* __restrict__ aemb,
             float* __restrict__ x, int* __restrict__ deg,
             const ushort* __restrict__ Wvx, const ushort* __restrict__ Wa1sx,
             const ushort* __restrict__ Wa1dx,
             uint* __restrict__ Vb, uint* __restrict__ Psb, uint* __restrict__ Pdb)
{
    __shared__ float rbf_s[8][32];
    __shared__ int   bs_s[8];
    __shared__ float t1_s[8][132];
    __shared__ ushort a_s[16][136];
    const int tid = threadIdx.x, bx = blockIdx.x;

    if (bx < 514) {
        const int l = (bx >= 257) ? 1 : 0;
        const int r0 = (bx - l * 257) * 8;
        {
            int ri = tid >> 5, j = tid & 31;
            int row = min(r0 + ri, TBM);
            float d = (float)row * (5.0f / TBM);
            const float step = 5.0f / 511.0f;
            const float invw = 512.0f / 5.0f;
            int b0 = (int)(d * (511.0f / 5.0f) + 0.5f);
            int bs = min(max(b0 - 16, 0), 512 - 32);
            if (j == 0) bs_s[ri] = bs;
            float z = (d - (float)(bs + j) * step) * invw;
            rbf_s[ri][j] = __expf(-z * z);
        }
        __syncthreads();
        #pragma unroll
        for (int pass = 0; pass < 4; ++pass) {
            int idx = pass * 256 + tid;
            int ri = idx >> 7, c = idx & 127;
            int bs = bs_s[ri];
            float t = b1[c];
            #pragma unroll
            for (int j = 0; j < 32; ++j)
                t += rbf_s[ri][j] * W1[(bs + j) * 128 + c];
            t1_s[ri][c] = siluf(t);
        }
        __syncthreads();

        const float* W2Al = W2A + (size_t)l * 16384;
        const int c = tid & 127, ng = tid >> 7;
        float a[4];
        #pragma unroll
        for (int r = 0; r < 4; ++r) a[r] = bA[l * 128 + c];
        #pragma unroll 4
        for (int k4 = 0; k4 < 128; k4 += 4) {
            float w0 = W2Al[(k4 + 0) * 128 + c];
            float w1 = W2Al[(k4 + 1) * 128 + c];
            float w2v = W2Al[(k4 + 2) * 128 + c];
            float w3 = W2Al[(k4 + 3) * 128 + c];
            #pragma unroll
            for (int r = 0; r < 4; ++r) {
                const float4 xv = *reinterpret_cast<const float4*>(&t1_s[ng * 4 + r][k4]);
                a[r] += xv.x * w0 + xv.y * w1 + xv.z * w2v + xv.w * w3;
            }
        }
        #pragma unroll
        for (int r = 0; r < 4; ++r) {
            float hi = __shfl_down(a[r], 1, 64);
            int row = r0 + ng * 4 + r;
            if (((c & 1) == 0) && row <= TBM)
                TAb[(size_t)l * TROWS * 64 + (size_t)row * 64 + (c >> 1)] = pack2bf(a[r], hi);
        }
        if (tid < 64) {
            int ri = tid >> 3, h = tid & 7;
            int row = r0 + ri;
            if (row <= TBM) {
                const float* W2Gl = W2G + (size_t)l * 1024;
                float s = bG[l * 8 + h];
                #pragma unroll 8
                for (int k = 0; k < 128; ++k)
                    s += t1_s[ri][k] * W2Gl[k * 8 + h];
                TG[(size_t)l * TROWS * 8 + (size_t)row * 8 + h] = s;
            }
        }
    } else {
        const int n0 = (bx - 514) * 16;
        if (tid < 16) deg[n0 + tid] = 0;
        {
            int ni = tid >> 4, c8 = (tid & 15) * 8;
            int n = n0 + ni;
            float v[8];
            #pragma unroll
            for (int q = 0; q < 8; ++q) v[q] = 0.f;
            #pragma unroll
            for (int f = 0; f < 4; ++f) {
                int idx = af[n * 4 + f];
                const float* er = &aemb[(size_t)(f * 10 + idx) * 128 + c8];
                float4 e0 = *reinterpret_cast<const float4*>(er);
                float4 e1 = *reinterpret_cast<const float4*>(er + 4);
                v[0] += e0.x; v[1] += e0.y; v[2] += e0.z; v[3] += e0.w;
                v[4] += e1.x; v[5] += e1.y; v[6] += e1.z; v[7] += e1.w;
            }
            float* xr = &x[(size_t)n * 128 + c8];
            *reinterpret_cast<float4*>(xr)     = make_float4(v[0], v[1], v[2], v[3]);
            *reinterpret_cast<float4*>(xr + 4) = make_float4(v[4], v[5], v[6], v[7]);
            float ss = 0.f;
            #pragma unroll
            for (int q = 0; q < 8; ++q) ss += v[q] * v[q];
            #pragma unroll
            for (int m = 1; m < 16; m <<= 1) ss += __shfl_xor(ss, m, 16);
            float r = rsqrtf(ss * (1.0f / 1152.0f) + 1e-6f);
            uint4 pk;
            pk.x = pack2bf(v[0] * r, v[1] * r);
            pk.y = pack2bf(v[2] * r, v[3] * r);
            pk.z = pack2bf(v[4] * r, v[5] * r);
            pk.w = pack2bf(v[6] * r, v[7] * r);
            *reinterpret_cast<uint4*>(&a_s[ni][c8]) = pk;
        }
        __syncthreads();
        node_gemm3(a_s, tid, n0, Wvx, Wa1sx, Wa1dx, Vb, Psb, Pdb);
    }
}

// ---------------- CSR build ----------------
__global__ __launch_bounds__(256)
void k_hist(const int* __restrict__ eidx, int* __restrict__ deg)
{
    int e = blockIdx.x * 256 + threadIdx.x;
    if (e < NE) atomicAdd(&deg[eidx[NE + e]], 1);
}

__global__ __launch_bounds__(1024)
void k_scan(const int* __restrict__ deg, int* __restrict__ off, int* __restrict__ cursor)
{
    __shared__ int part[1024];
    const int t = threadIdx.x;
    const int base = t * 6;
    int loc[6]; int s = 0;
    #pragma unroll
    for (int i = 0; i < 6; ++i) {
        int d = (base + i < NN) ? deg[base + i] : 0;
        loc[i] = s; s += d;
    }
    part[t] = s;
    __syncthreads();
    for (int o = 1; o < 1024; o <<= 1) {
        int v = (t >= o) ? part[t - o] : 0;
        __syncthreads();
        part[t] += v;
        __syncthreads();
    }
    int pre = (t > 0) ? part[t - 1] : 0;
    #pragma unroll
    for (int i = 0; i < 6; ++i) {
        if (base + i < NN) {
            int v = pre + loc[i];
            off[base + i] = v;
            cursor[base + i] = v;
        }
    }
    if (t == 1023) off[NN] = part[1023];
}

__global__ __launch_bounds__(256)
void k_fill(const int* __restrict__ eidx, const int* __restrict__ bondf,
            const float* __restrict__ dist, int* __restrict__ cursor,
            int* __restrict__ srcp, int* __restrict__ dstp,
            float* __restrict__ distp, int* __restrict__ cbp)
{
    int e = blockIdx.x * 256 + threadIdx.x;
    if (e < NE) {
        int d = eidx[NE + e];
        int p = atomicAdd(&cursor[d], 1);
        srcp[p] = eidx[e];
        dstp[p] = d;
        distp[p] = dist[e];
        cbp[p] = bondf[e * 3 + 0] * 64 + bondf[e * 3 + 1] * 8 + bondf[e * 3 + 2];
    }
}

// ---------------- attention: LDS phase A (bf16 t) + MFMA phase B ----------------
__global__ __launch_bounds__(256)
void k_attn(const int* __restrict__ srcp, const int* __restrict__ dstp,
            const float* __restrict__ distp, const int* __restrict__ cbp,
            const uint* __restrict__ Psb, const uint* __restrict__ Pdb,
            const uint* __restrict__ TAbl, const float* __restrict__ TGl,
            const uint* __restrict__ BAcbl, const float* __restrict__ BGcl,
            const ushort* __restrict__ Wa2xl,
            float* __restrict__ num, float* __restrict__ exs)
{
    __shared__ ushort t_s[32][136];
    __shared__ float gate_s[32][8];
    const int tid = threadIdx.x;
    const int p0 = blockIdx.x * 32;

    {   // phase A: per (edge, 16-channel group); t -> bf16 LDS
        const int ei = tid >> 3, g = tid & 7;
        const int p = min(p0 + ei, NE - 1);
        const int sn = srcp[p], dn = dstp[p];
        const float d = distp[p];
        const int cb = cbp[p];
        float u = d * ((float)TBM / 5.0f);
        int i = min((int)u, TBM - 1);
        float f = u - (float)i, f1 = 1.f - f;

        uint ps[8], pd[8], t0[8], t1v[8], ba[8];
        {
            const uint4* pp = reinterpret_cast<const uint4*>(&Psb[(size_t)sn * 64 + g * 8]);
            uint4 a = pp[0], b = pp[1];
            ps[0]=a.x; ps[1]=a.y; ps[2]=a.z; ps[3]=a.w; ps[4]=b.x; ps[5]=b.y; ps[6]=b.z; ps[7]=b.w;
            pp = reinterpret_cast<const uint4*>(&Pdb[(size_t)dn * 64 + g * 8]);
            a = pp[0]; b = pp[1];
            pd[0]=a.x; pd[1]=a.y; pd[2]=a.z; pd[3]=a.w; pd[4]=b.x; pd[5]=b.y; pd[6]=b.z; pd[7]=b.w;
            pp = reinterpret_cast<const uint4*>(&TAbl[(size_t)i * 64 + g * 8]);
            a = pp[0]; b = pp[1];
            t0[0]=a.x; t0[1]=a.y; t0[2]=a.z; t0[3]=a.w; t0[4]=b.x; t0[5]=b.y; t0[6]=b.z; t0[7]=b.w;
            pp = reinterpret_cast<const uint4*>(&TAbl[(size_t)(i + 1) * 64 + g * 8]);
            a = pp[0]; b = pp[1];
            t1v[0]=a.x; t1v[1]=a.y; t1v[2]=a.z; t1v[3]=a.w; t1v[4]=b.x; t1v[5]=b.y; t1v[6]=b.z; t1v[7]=b.w;
            pp = reinterpret_cast<const uint4*>(&BAcbl[(size_t)cb * 64 + g * 8]);
            a = pp[0]; b = pp[1];
            ba[0]=a.x; ba[1]=a.y; ba[2]=a.z; ba[3]=a.w; ba[4]=b.x; ba[5]=b.y; ba[6]=b.z; ba[7]=b.w;
        }
        uint tw[8];
        #pragma unroll
        for (int q = 0; q < 8; ++q) {
            float2 vs = up2(ps[q]), vd = up2(pd[q]), v0 = up2(t0[q]), v1 = up2(t1v[q]), vb = up2(ba[q]);
            float s0 = siluf(vs.x + vd.x + f1 * v0.x + f * v1.x + vb.x);
            float s1 = siluf(vs.y + vd.y + f1 * v0.y + f * v1.y + vb.y);
            tw[q] = pack2bf(s0, s1);
        }
        uint4* tp = reinterpret_cast<uint4*>(&t_s[ei][g * 16]);
        tp[0] = make_uint4(tw[0], tw[1], tw[2], tw[3]);
        tp[1] = make_uint4(tw[4], tw[5], tw[6], tw[7]);
        if (g == 0) {
            const float4* tg0 = reinterpret_cast<const float4*>(&TGl[(size_t)i * 8]);
            const float4* bg4 = reinterpret_cast<const float4*>(&BGcl[(size_t)cb * 8]);
            #pragma unroll
            for (int q = 0; q < 2; ++q) {
                float4 g0 = tg0[q], g1 = tg0[q + 2], bb = bg4[q];
                gate_s[ei][4 * q + 0] = f1 * g0.x + f * g1.x + bb.x;
                gate_s[ei][4 * q + 1] = f1 * g0.y + f * g1.y + bb.y;
                gate_s[ei][4 * q + 2] = f1 * g0.z + f * g1.z + bb.z;
                gate_s[ei][4 * q + 3] = f1 * g0.w + f * g1.w + bb.w;
            }
        }
    }
    __syncthreads();

    {   // phase B: logits = t @ Wa2 via MFMA; waves 0,1 each take 16 edges
        const int wq = tid >> 6, l = tid & 63;
        if (wq < 2) {
            const int lr = l & 15, lk = l >> 4;
            float4v acc = (float4v){0.f, 0.f, 0.f, 0.f};
            #pragma unroll
            for (int ks = 0; ks < 4; ++ks) {
                short8v af = *reinterpret_cast<const short8v*>(&t_s[wq * 16 + lr][lk * 8 + ks * 32]);
                short8v bf = *reinterpret_cast<const short8v*>(&Wa2xl[((size_t)ks * 64 + l) * 8]);
                acc = __builtin_amdgcn_mfma_f32_16x16x32_bf16(af, bf, acc, 0, 0, 0);
            }
            const int h = l & 15;
            if (h < 8) {
                #pragma unroll
                for (int r = 0; r < 4; ++r) {
                    int ei = wq * 16 + lk * 4 + r;
                    int p = p0 + ei;
                    if (p < NE) {
                        float ex = __expf(acc[r]);
                        num[(size_t)p * 8 + h] = ex * sigmf(gate_s[ei][h]);
                        exs[(size_t)p * 8 + h] = ex;
                    }
                }
            }
        }
    }
}

// ---------------- fused aggregate (+denominator) + out_proj; 2 nodes/block ----------------
__global__ __launch_bounds__(256)
void k_aggo(const int* __restrict__ off, const int* __restrict__ srcp,
            const float* __restrict__ num, const float* __restrict__ exs,
            const uint* __restrict__ Vb, const float* __restrict__ Wol,
            float* __restrict__ x)
{
    __shared__ float a_s[2][128];
    const int tid = threadIdx.x;
    const int nh = tid >> 7;
    const int n = blockIdx.x * 2 + nh;
    const int c = tid & 127;
    const int s = off[n], t = off[n + 1];
    const int h = c >> 4, cd = c >> 1, sel = c & 1;
    float acc = 0.f, es = 0.f;
    int p = s;
    for (; p + 8 <= t; p += 8) {
        int sn[8]; float cf[8]; uint u[8];
        #pragma unroll
        for (int q = 0; q < 8; ++q) sn[q] = srcp[p + q];
        #pragma unroll
        for (int q = 0; q < 8; ++q) cf[q] = num[(size_t)(p + q) * 8 + h];
        #pragma unroll
        for (int q = 0; q < 8; ++q) u[q] = Vb[(size_t)sn[q] * 64 + cd];
        #pragma unroll
        for (int q = 0; q < 8; ++q) es += exs[(size_t)(p + q) * 8 + h];
        #pragma unroll
        for (int q = 0; q < 8; ++q) {
            float v = sel ? __uint_as_float(u[q] & 0xffff0000u) : __uint_as_float(u[q] << 16);
            acc += cf[q] * v;
        }
    }
    for (; p < t; ++p) {
        int sn = srcp[p];
        float cf = num[(size_t)p * 8 + h];
        es += exs[(size_t)p * 8 + h];
        uint u = Vb[(size_t)sn * 64 + cd];
        float v = sel ? __uint_as_float(u & 0xffff0000u) : __uint_as_float(u << 16);
        acc += cf * v;
    }
    a_s[nh][c] = acc / (es + 1e-9f);
    __syncthreads();
    float o = 0.f;
    #pragma unroll 4
    for (int j4 = 0; j4 < 128; j4 += 4) {
        const float4 a4 = *reinterpret_cast<const float4*>(&a_s[nh][j4]);
        o += a4.x * Wol[(j4 + 0) * 128 + c] + a4.y * Wol[(j4 + 1) * 128 + c]
           + a4.z * Wol[(j4 + 2) * 128 + c] + a4.w * Wol[(j4 + 3) * 128 + c];
    }
    x[(size_t)n * 128 + c] += o;
}

// ---------------- fused rms + FFN (+ next-layer GEMMs, or finalize) ----------------
template<int LAST>
__global__ __launch_bounds__(256)
void k_ffn_fused(float* __restrict__ x, const ushort* __restrict__ Wf1xl,
                 const ushort* __restrict__ Wf2xl, float* __restrict__ out,
                 const ushort* __restrict__ WvxN, const ushort* __restrict__ Wa1sxN,
                 const ushort* __restrict__ Wa1dxN,
                 uint* __restrict__ Vb, uint* __restrict__ Psb, uint* __restrict__ Pdb)
{
    __shared__ ushort a_s[16][136];
    __shared__ ushort h_s[16][520];
    __shared__ float xf_s[16][132];
    const int tid = threadIdx.x;
    const int n0 = blockIdx.x * 16;

    {
        int ni = tid >> 4, c8 = (tid & 15) * 8;
        const float* xr = &x[(size_t)(n0 + ni) * 128 + c8];
        float4 v0 = *reinterpret_cast<const float4*>(xr);
        float4 v1 = *reinterpret_cast<const float4*>(xr + 4);
        *reinterpret_cast<float4*>(&xf_s[ni][c8]) = v0;
        *reinterpret_cast<float4*>(&xf_s[ni][c8 + 4]) = v1;
        float ss = v0.x * v0.x + v0.y * v0.y + v0.z * v0.z + v0.w * v0.w
                 + v1.x * v1.x + v1.y * v1.y + v1.z * v1.z + v1.w * v1.w;
        #pragma unroll
        for (int m = 1; m < 16; m <<= 1) ss += __shfl_xor(ss, m, 16);
        float r = rsqrtf(ss * (1.0f / 1152.0f) + 1e-6f);
        uint4 pk;
        pk.x = pack2bf(v0.x * r, v0.y * r);
        pk.y = pack2bf(v0.z * r, v0.w * r);
        pk.z = pack2bf(v1.x * r, v1.y * r);
        pk.w = pack2bf(v1.z * r, v1.w * r);
        *reinterpret_cast<uint4*>(&a_s[ni][c8]) = pk;
    }
    __syncthreads();

    const int l  = tid & 63;
    const int wq = tid >> 6;
    const int lr = l & 15, lk = l >> 4;

    float4v acc[8];
    #pragma unroll
    for (int nf = 0; nf < 8; ++nf) acc[nf] = (float4v){0.f, 0.f, 0.f, 0.f};
    #pragma unroll
    for (int ks = 0; ks < 4; ++ks) {
        short8v af = *reinterpret_cast<const short8v*>(&a_s[lr][lk * 8 + ks * 32]);
        #pragma unroll
        for (int nf = 0; nf < 8; ++nf) {
            int nt = wq * 8 + nf;
            short8v bf = *reinterpret_cast<const short8v*>(&Wf1xl[((size_t)(nt * 4 + ks) * 64 + l) * 8]);
            acc[nf] = __builtin_amdgcn_mfma_f32_16x16x32_bf16(af, bf, acc[nf], 0, 0, 0);
        }
    }
    #pragma unroll
    for (int nf = 0; nf < 8; ++nf) {
        #pragma unroll
        for (int r = 0; r < 4; ++r) {
            float v = siluf(acc[nf][r]);
            float vn = __shfl_xor(v, 1, 64);
            if ((l & 1) == 0) {
                int row = lk * 4 + r;
                int col = wq * 128 + nf * 16 + lr;
                *reinterpret_cast<uint*>(&h_s[row][col]) = pack2bf(v, vn);
            }
        }
    }
    __syncthreads();

    float4v acc2[2];
    acc2[0] = (float4v){0.f, 0.f, 0.f, 0.f};
    acc2[1] = (float4v){0.f, 0.f, 0.f, 0.f};
    #pragma unroll 4
    for (int ks = 0; ks < 16; ++ks) {
        short8v af = *reinterpret_cast<const short8v*>(&h_s[lr][lk * 8 + ks * 32]);
        #pragma unroll
        for (int nf = 0; nf < 2; ++nf) {
            int nt = wq * 2 + nf;
            short8v bf = *reinterpret_cast<const short8v*>(&Wf2xl[((size_t)(nt * 16 + ks) * 64 + l) * 8]);
            acc2[nf] = __builtin_amdgcn_mfma_f32_16x16x32_bf16(af, bf, acc2[nf], 0, 0, 0);
        }
    }
    #pragma unroll
    for (int nf = 0; nf < 2; ++nf) {
        #pragma unroll
        for (int r = 0; r < 4; ++r) {
            int row = lk * 4 + r;
            int col = wq * 32 + nf * 16 + lr;
            xf_s[row][col] += acc2[nf][r];
        }
    }
    __syncthreads();

    int ni = tid >> 4, c8 = (tid & 15) * 8;
    float4 v0 = *reinterpret_cast<const float4*>(&xf_s[ni][c8]);
    float4 v1 = *reinterpret_cast<const float4*>(&xf_s[ni][c8 + 4]);
    float ss = v0.x * v0.x + v0.y * v0.y + v0.z * v0.z + v0.w * v0.w
             + v1.x * v1.x + v1.y * v1.y + v1.z * v1.z + v1.w * v1.w;
    #pragma unroll
    for (int m = 1; m < 16; m <<= 1) ss += __shfl_xor(ss, m, 16);
    float r = rsqrtf(ss * (1.0f / 1152.0f) + 1e-6f);

    if (!LAST) {
        float* xr = &x[(size_t)(n0 + ni) * 128 + c8];
        *reinterpret_cast<float4*>(xr)     = v0;
        *reinterpret_cast<float4*>(xr + 4) = v1;
        uint4 pk;
        pk.x = pack2bf(v0.x * r, v0.y * r);
        pk.y = pack2bf(v0.z * r, v0.w * r);
        pk.z = pack2bf(v1.x * r, v1.y * r);
        pk.w = pack2bf(v1.z * r, v1.w * r);
        __syncthreads();
        *reinterpret_cast<uint4*>(&a_s[ni][c8]) = pk;
        __syncthreads();
        node_gemm3(a_s, tid, n0, WvxN, Wa1sxN, Wa1dxN, Vb, Psb, Pdb);
    } else {
        size_t base = (size_t)(n0 + ni) * 1152 + c8;
        *reinterpret_cast<float4*>(&out[base])     = make_float4(v0.x * r, v0.y * r, v0.z * r, v0.w * r);
        *reinterpret_cast<float4*>(&out[base + 4]) = make_float4(v1.x * r, v1.y * r, v1.z * r, v1.w * r);
        const float4 z4 = make_float4(0.f, 0.f, 0.f, 0.f);
        #pragma unroll
        for (int k = 1; k < 9; ++k) {
            *reinterpret_cast<float4*>(&out[base + (size_t)k * 128]) = z4;
            *reinterpret_cast<float4*>(&out[base + (size_t)k * 128 + 4]) = z4;
        }
    }
}

extern "C" void kernel_launch(void* const* d_in, const int* in_sizes, int n_in,
                              void* d_out, int out_size, void* d_ws, size_t ws_size,
                              hipStream_t stream)
{
    const int*   atom_feats = (const int*)d_in[0];
    const int*   bond_feats = (const int*)d_in[1];
    const int*   edge_index = (const int*)d_in[2];
    const float* edge_dist  = (const float*)d_in[3];
    const float* atom_emb   = (const float*)d_in[4];
    const float* bond_emb   = (const float*)d_in[5];
    const float* W_rbf1     = (const float*)d_in[6];
    const float* b_rbf1     = (const float*)d_in[7];
    const float* W_rbf2     = (const float*)d_in[8];
    const float* b_rbf2     = (const float*)d_in[9];
    const float* Wa1        = (const float*)d_in[10];
    const float* Wa2        = (const float*)d_in[11];
    const float* Wv         = (const float*)d_in[12];
    const float* Wg         = (const float*)d_in[13];
    const float* Wo         = (const float*)d_in[14];
    const float* Wf1        = (const float*)d_in[15];
    const float* Wf2        = (const float*)d_in[16];
    float* out = (float*)d_out;

    float* ws   = (float*)d_ws;
    float* x    = ws;                           // NN*128
    float* num  = x    + NN * 128;              // NE*8 (CSR order)
    float* exs  = num  + (size_t)NE * 8;        // NE*8
    float* W2A  = exs  + (size_t)NE * 8;        // 2*16384
    float* W2G  = W2A  + 2 * 16384;             // 2*1024
    float* bA   = W2G  + 2 * 1024;              // 2*128
    float* bG   = bA   + 2 * 128;               // 16
    float* TG   = bG   + 16;                    // 2*TROWS*8
    float* BGc  = TG   + 2 * (size_t)TROWS * 8; // 2*512*8
    float* distp = BGc + 2 * 512 * 8;           // NE
    uint* Vb    = (uint*)(distp + NE);          // NN*64
    uint* Psb   = Vb  + NN * 64;
    uint* Pdb   = Psb + NN * 64;
    uint* TAb   = Pdb + NN * 64;                // 2*TROWS*64
    uint* BAcb  = TAb + 2 * (size_t)TROWS * 64; // 2*512*64
    ushort* Wf1x  = (ushort*)(BAcb + 2 * 512 * 64);  // 2*65536
    ushort* Wf2x  = Wf1x  + 2 * 65536;
    ushort* Wvx   = Wf2x  + 2 * 65536;
    ushort* Wa1sx = Wvx   + 2 * 16384;
    ushort* Wa1dx = Wa1sx + 2 * 16384;
    ushort* Wa2x  = Wa1dx + 2 * 16384;               // 2*2048
    int* deg    = (int*)(Wa2x + 2 * 2048);
    int* off    = deg + NN;
    int* cursor = off + NN + 1;
    int* srcp   = cursor + NN;                  // NE
    int* dstp   = srcp + NE;                    // NE
    int* cbp    = dstp + NE;                    // NE

    // merged table/pack prep (w2a | bondtabs | packw+Wa2x)
    k_prep<<<dim3(363, 2), 256, 0, stream>>>(W_rbf2, b_rbf2, Wa1, Wg, bond_emb,
        Wf1, Wf2, Wv, Wa2, W2A, W2G, bA, bG, BAcb, BGc,
        Wf1x, Wf2x, Wvx, Wa1sx, Wa1dx, Wa2x);
    // t1ta (depends on W2A) + embed/layer-0 GEMMs (independent), merged
    k_prep2<<<514 + NN / 16, 256, 0, stream>>>(W_rbf1, b_rbf1, W2A, W2G, bA, bG, TAb, TG,
        atom_feats, atom_emb, x, deg, Wvx, Wa1sx, Wa1dx, Vb, Psb, Pdb);

    // CSR (dst is layer-invariant)
    k_hist<<<(NE + 255) / 256, 256, 0, stream>>>(edge_index, deg);
    k_scan<<<1, 1024, 0, stream>>>(deg, off, cursor);
    k_fill<<<(NE + 255) / 256, 256, 0, stream>>>(edge_index, bond_feats, edge_dist,
                                                 cursor, srcp, dstp, distp, cbp);

    for (int l = 0; l < 2; ++l) {
        k_attn<<<(NE + 31) / 32, 256, 0, stream>>>(srcp, dstp, distp, cbp,
            Psb, Pdb,
            TAb + (size_t)l * TROWS * 64, TG + (size_t)l * TROWS * 8,
            BAcb + (size_t)l * 512 * 64, BGc + (size_t)l * 512 * 8,
            Wa2x + (size_t)l * 2048, num, exs);
        k_aggo<<<NN / 2, 256, 0, stream>>>(off, srcp, num, exs, Vb,
                                           Wo + (size_t)l * 128 * 128, x);
        if (l == 0)
            k_ffn_fused<0><<<NN / 16, 256, 0, stream>>>(x,
                Wf1x, Wf2x, out,
                Wvx + 16384, Wa1sx + 16384, Wa1dx + 16384, Vb, Psb, Pdb);
        else
            k_ffn_fused<1><<<NN / 16, 256, 0, stream>>>(x,
                Wf1x + 65536, Wf2x + 65536, out,
                Wvx, Wa1sx, Wa1dx, Vb, Psb, Pdb);
    }
}

// Round 11
// 167.621 us; speedup vs baseline: 1.9246x; 1.2641x over previous
//
#include <hip/hip_runtime.h>

#define NN 6000
#define NE 150000
#define TBM 2048
#define TROWS (TBM + 1)

typedef unsigned int uint;
typedef unsigned short ushort;
typedef __attribute__((ext_vector_type(8))) short short8v;
typedef __attribute__((ext_vector_type(4))) float float4v;

__device__ __forceinline__ float siluf(float x) { return x / (1.f + __expf(-x)); }
__device__ __forceinline__ float sigmf(float x) { return 1.f / (1.f + __expf(-x)); }
__device__ __forceinline__ uint pack2bf(float lo, float hi) {
    uint ul = __float_as_uint(lo);
    ul = (ul + 0x7fffu + ((ul >> 16) & 1u)) >> 16;
    uint uh = __float_as_uint(hi);
    uh = ((uh + 0x7fffu + ((uh >> 16) & 1u)) >> 16) << 16;
    return ul | uh;
}
__device__ __forceinline__ ushort f2bf(float f) {
    uint u = __float_as_uint(f);
    return (ushort)((u + 0x7fffu + ((u >> 16) & 1u)) >> 16);
}
__device__ __forceinline__ float2 up2(uint u) {
    return make_float2(__uint_as_float(u << 16), __uint_as_float(u & 0xffff0000u));
}

// ================ k_prep: w2a | bondtabs | packw (+Wa2x, Wox) ================
__global__ __launch_bounds__(256)
void k_prep(const float* __restrict__ W2, const float* __restrict__ b2,
            const float* __restrict__ Wa1, const float* __restrict__ Wg,
            const float* __restrict__ bemb,
            const float* __restrict__ Wf1, const float* __restrict__ Wf2,
            const float* __restrict__ Wv, const float* __restrict__ Wa2,
            const float* __restrict__ Wo,
            float* __restrict__ W2A, float* __restrict__ W2G,
            float* __restrict__ bA, float* __restrict__ bG,
            uint* __restrict__ BAcb, float* __restrict__ BGc,
            ushort* __restrict__ Wf1x, ushort* __restrict__ Wf2x,
            ushort* __restrict__ Wvx, ushort* __restrict__ Wa1sx,
            ushort* __restrict__ Wa1dx, ushort* __restrict__ Wa2x,
            ushort* __restrict__ Wox)
{
    __shared__ float w2_s[8][132];
    const int l = blockIdx.y, bx = blockIdx.x, tid = threadIdx.x;
    const float* Wa1e = Wa1 + (size_t)l * 384 * 128 + 256 * 128;
    const float* Wgl  = Wg  + (size_t)l * 128 * 8;

    if (bx < 16) {
        const int i0 = bx * 8;
        for (int q = tid; q < 8 * 32; q += 256) {
            int ni = q >> 5, j4 = (q & 31) * 4;
            *reinterpret_cast<float4*>(&w2_s[ni][j4]) =
                *reinterpret_cast<const float4*>(&W2[(size_t)(i0 + ni) * 128 + j4]);
        }
        __syncthreads();
        const int j = tid & 127, ng = tid >> 7;
        float a[4] = {0.f, 0.f, 0.f, 0.f};
        #pragma unroll 4
        for (int k4 = 0; k4 < 128; k4 += 4) {
            float w0 = Wa1e[(k4 + 0) * 128 + j];
            float w1 = Wa1e[(k4 + 1) * 128 + j];
            float w2v = Wa1e[(k4 + 2) * 128 + j];
            float w3 = Wa1e[(k4 + 3) * 128 + j];
            #pragma unroll
            for (int r = 0; r < 4; ++r) {
                const float4 xv = *reinterpret_cast<const float4*>(&w2_s[ng * 4 + r][k4]);
                a[r] += xv.x * w0 + xv.y * w1 + xv.z * w2v + xv.w * w3;
            }
        }
        #pragma unroll
        for (int r = 0; r < 4; ++r)
            W2A[(size_t)l * 16384 + (size_t)(i0 + ng * 4 + r) * 128 + j] = a[r];
    } else if (bx == 16) {
        const int i = tid & 127, hq = tid >> 7;
        float a[4] = {0.f, 0.f, 0.f, 0.f};
        for (int k = 0; k < 128; ++k) {
            float w = W2[(size_t)i * 128 + k];
            const float4 g4 = *reinterpret_cast<const float4*>(&Wgl[k * 8 + hq * 4]);
            a[0] += w * g4.x; a[1] += w * g4.y; a[2] += w * g4.z; a[3] += w * g4.w;
        }
        #pragma unroll
        for (int q = 0; q < 4; ++q)
            W2G[(size_t)l * 1024 + (size_t)i * 8 + hq * 4 + q] = a[q];
    } else if (bx == 17) {
        if (tid < 128) {
            float s = 0.f;
            for (int k = 0; k < 128; ++k) s += b2[k] * Wa1e[k * 128 + tid];
            bA[l * 128 + tid] = s;
        } else if (tid < 136) {
            int h = tid - 128;
            float s = 0.f;
            for (int k = 0; k < 128; ++k) s += b2[k] * Wgl[k * 8 + h];
            bG[l * 8 + h] = s;
        }
    } else if (bx < 274) {
        const int cb = (bx - 18) * 2 + (tid >> 7);
        const int c = tid & 127;
        const int b[3] = {cb >> 6, (cb >> 3) & 7, cb & 7};
        float s = 0.f;
        #pragma unroll
        for (int f = 0; f < 3; ++f) {
            const float* er = &bemb[(size_t)(f * 8 + b[f]) * 128];
            for (int k = 0; k < 128; ++k)
                s += er[k] * Wa1e[k * 128 + c];
        }
        float hi = __shfl_down(s, 1, 64);
        if ((c & 1) == 0)
            BAcb[(size_t)l * 512 * 64 + (size_t)cb * 64 + (c >> 1)] = pack2bf(s, hi);
        if (c < 8) {
            float g = 0.f;
            #pragma unroll
            for (int f = 0; f < 3; ++f) {
                const float* er = &bemb[(size_t)(f * 8 + b[f]) * 128];
                for (int k = 0; k < 128; ++k)
                    g += er[k] * Wgl[k * 8 + c];
            }
            BGc[(size_t)l * 512 * 8 + (size_t)cb * 8 + c] = g;
        }
    } else {
        const int sub = (bx - 274) * 4 + (tid >> 6);   // 0..387
        const int lane = tid & 63;
        if (sub < 128) {
            const int nt = sub >> 2, kt = sub & 3;
            const float* src = Wf1 + (size_t)l * 65536;
            ushort* dst = Wf1x + (size_t)l * 65536 + ((size_t)sub * 64 + lane) * 8;
            #pragma unroll
            for (int j = 0; j < 8; ++j)
                dst[j] = f2bf(src[(size_t)(kt * 32 + (lane >> 4) * 8 + j) * 512 + nt * 16 + (lane & 15)]);
        } else if (sub < 256) {
            const int b2x = sub - 128;
            const int nt = b2x >> 4, kt = b2x & 15;
            const float* src = Wf2 + (size_t)l * 65536;
            ushort* dst = Wf2x + (size_t)l * 65536 + ((size_t)b2x * 64 + lane) * 8;
            #pragma unroll
            for (int j = 0; j < 8; ++j)
                dst[j] = f2bf(src[(size_t)(kt * 32 + (lane >> 4) * 8 + j) * 128 + nt * 16 + (lane & 15)]);
        } else if (sub < 352) {
            const int b3 = sub - 256;
            const int mat = b3 >> 5, blk = b3 & 31;
            const int nt = blk >> 2, kt = blk & 3;
            const float* src;
            ushort* dst;
            if (mat == 0)      { src = Wv  + (size_t)l * 16384;             dst = Wvx   + (size_t)l * 16384; }
            else if (mat == 1) { src = Wa1 + (size_t)l * 384 * 128;         dst = Wa1sx + (size_t)l * 16384; }
            else               { src = Wa1 + (size_t)l * 384 * 128 + 16384; dst = Wa1dx + (size_t)l * 16384; }
            dst += ((size_t)blk * 64 + lane) * 8;
            #pragma unroll
            for (int j = 0; j < 8; ++j)
                dst[j] = f2bf(src[(size_t)(kt * 32 + (lane >> 4) * 8 + j) * 128 + nt * 16 + (lane & 15)]);
        } else if (sub < 356) {
            const int kt = sub - 352;
            const int col = lane & 15;
            const float* src = Wa2 + (size_t)l * 128 * 8;
            ushort* dst = Wa2x + (size_t)l * 2048 + ((size_t)kt * 64 + lane) * 8;
            #pragma unroll
            for (int j = 0; j < 8; ++j) {
                int krow = kt * 32 + (lane >> 4) * 8 + j;
                dst[j] = (col < 8) ? f2bf(src[(size_t)krow * 8 + col]) : (ushort)0;
            }
        } else {
            const int blk = sub - 356;       // 0..31
            const int nt = blk >> 2, kt = blk & 3;
            const float* src = Wo + (size_t)l * 16384;
            ushort* dst = Wox + (size_t)l * 16384 + ((size_t)blk * 64 + lane) * 8;
            #pragma unroll
            for (int j = 0; j < 8; ++j)
                dst[j] = f2bf(src[(size_t)(kt * 32 + (lane >> 4) * 8 + j) * 128 + nt * 16 + (lane & 15)]);
        }
    }
}

// ---------------- shared device helper: 3 node GEMMs from a_s ----------------
__device__ __forceinline__
void node_gemm3(const ushort a_s[16][136], int tid, int n0,
                const ushort* __restrict__ Wvx, const ushort* __restrict__ Wa1sx,
                const ushort* __restrict__ Wa1dx,
                uint* __restrict__ Vb, uint* __restrict__ Psb, uint* __restrict__ Pdb)
{
    const int l = tid & 63, wq = tid >> 6;
    const int lr = l & 15, lk = l >> 4;
    #pragma unroll
    for (int jb = 0; jb < 6; ++jb) {
        int job = wq * 6 + jb;
        int mat = job >> 3, nt = job & 7;
        const ushort* W = (mat == 0) ? Wvx : (mat == 1 ? Wa1sx : Wa1dx);
        uint* O = (mat == 0) ? Vb : (mat == 1 ? Psb : Pdb);
        float4v acc = (float4v){0.f, 0.f, 0.f, 0.f};
        #pragma unroll
        for (int ks = 0; ks < 4; ++ks) {
            short8v af = *reinterpret_cast<const short8v*>(&a_s[lr][lk * 8 + ks * 32]);
            short8v bf = *reinterpret_cast<const short8v*>(&W[((size_t)(nt * 4 + ks) * 64 + l) * 8]);
            acc = __builtin_amdgcn_mfma_f32_16x16x32_bf16(af, bf, acc, 0, 0, 0);
        }
        #pragma unroll
        for (int r = 0; r < 4; ++r) {
            float v = acc[r];
            float vn = __shfl_xor(v, 1, 64);
            if ((l & 1) == 0) {
                int row = lk * 4 + r, col = nt * 16 + lr;
                O[(size_t)(n0 + row) * 64 + (col >> 1)] = pack2bf(v, vn);
            }
        }
    }
}

// ================ k_prep2: t1ta (bx<514) | embed+gemm (bx>=514) ================
__global__ __launch_bounds__(256)
void k_prep2(const float* __restrict__ W1, const float* __restrict__ b1,
             const float* __restrict__ W2A, const float* __restrict__ W2G,
             const float* __restrict__ bA, const float* __restrict__ bG,
             uint* __restrict__ TAb, float* __restrict__ TG,
             const int* __restrict__ af, const float* __restrict__ aemb,
             float* __restrict__ x, int* __restrict__ deg,
             const ushort* __restrict__ Wvx, const ushort* __restrict__ Wa1sx,
             const ushort* __restrict__ Wa1dx,
             uint* __restrict__ Vb, uint* __restrict__ Psb, uint* __restrict__ Pdb)
{
    __shared__ float rbf_s[8][32];
    __shared__ int   bs_s[8];
    __shared__ float t1_s[8][132];
    __shared__ ushort a_s[16][136];
    const int tid = threadIdx.x, bx = blockIdx.x;

    if (bx < 514) {
        const int l = (bx >= 257) ? 1 : 0;
        const int r0 = (bx - l * 257) * 8;
        {
            int ri = tid >> 5, j = tid & 31;
            int row = min(r0 + ri, TBM);
            float d = (float)row * (5.0f / TBM);
            const float step = 5.0f / 511.0f;
            const float invw = 512.0f / 5.0f;
            int b0 = (int)(d * (511.0f / 5.0f) + 0.5f);
            int bs = min(max(b0 - 16, 0), 512 - 32);
            if (j == 0) bs_s[ri] = bs;
            float z = (d - (float)(bs + j) * step) * invw;
            rbf_s[ri][j] = __expf(-z * z);
        }
        __syncthreads();
        #pragma unroll
        for (int pass = 0; pass < 4; ++pass) {
            int idx = pass * 256 + tid;
            int ri = idx >> 7, c = idx & 127;
            int bs = bs_s[ri];
            float t = b1[c];
            #pragma unroll
            for (int j = 0; j < 32; ++j)
                t += rbf_s[ri][j] * W1[(bs + j) * 128 + c];
            t1_s[ri][c] = siluf(t);
        }
        __syncthreads();

        const float* W2Al = W2A + (size_t)l * 16384;
        const int c = tid & 127, ng = tid >> 7;
        float a[4];
        #pragma unroll
        for (int r = 0; r < 4; ++r) a[r] = bA[l * 128 + c];
        #pragma unroll 4
        for (int k4 = 0; k4 < 128; k4 += 4) {
            float w0 = W2Al[(k4 + 0) * 128 + c];
            float w1 = W2Al[(k4 + 1) * 128 + c];
            float w2v = W2Al[(k4 + 2) * 128 + c];
            float w3 = W2Al[(k4 + 3) * 128 + c];
            #pragma unroll
            for (int r = 0; r < 4; ++r) {
                const float4 xv = *reinterpret_cast<const float4*>(&t1_s[ng * 4 + r][k4]);
                a[r] += xv.x * w0 + xv.y * w1 + xv.z * w2v + xv.w * w3;
            }
        }
        #pragma unroll
        for (int r = 0; r < 4; ++r) {
            float hi = __shfl_down(a[r], 1, 64);
            int row = r0 + ng * 4 + r;
            if (((c & 1) == 0) && row <= TBM)
                TAb[(size_t)l * TROWS * 64 + (size_t)row * 64 + (c >> 1)] = pack2bf(a[r], hi);
        }
        if (tid < 64) {
            int ri = tid >> 3, h = tid & 7;
            int row = r0 + ri;
            if (row <= TBM) {
                const float* W2Gl = W2G + (size_t)l * 1024;
                float s = bG[l * 8 + h];
                #pragma unroll 8
                for (int k = 0; k < 128; ++k)
                    s += t1_s[ri][k] * W2Gl[k * 8 + h];
                TG[(size_t)l * TROWS * 8 + (size_t)row * 8 + h] = s;
            }
        }
    } else {
        const int n0 = (bx - 514) * 16;
        if (tid < 16) deg[n0 + tid] = 0;
        {
            int ni = tid >> 4, c8 = (tid & 15) * 8;
            int n = n0 + ni;
            float v[8];
            #pragma unroll
            for (int q = 0; q < 8; ++q) v[q] = 0.f;
            #pragma unroll
            for (int f = 0; f < 4; ++f) {
                int idx = af[n * 4 + f];
                const float* er = &aemb[(size_t)(f * 10 + idx) * 128 + c8];
                float4 e0 = *reinterpret_cast<const float4*>(er);
                float4 e1 = *reinterpret_cast<const float4*>(er + 4);
                v[0] += e0.x; v[1] += e0.y; v[2] += e0.z; v[3] += e0.w;
                v[4] += e1.x; v[5] += e1.y; v[6] += e1.z; v[7] += e1.w;
            }
            float* xr = &x[(size_t)n * 128 + c8];
            *reinterpret_cast<float4*>(xr)     = make_float4(v[0], v[1], v[2], v[3]);
            *reinterpret_cast<float4*>(xr + 4) = make_float4(v[4], v[5], v[6], v[7]);
            float ss = 0.f;
            #pragma unroll
            for (int q = 0; q < 8; ++q) ss += v[q] * v[q];
            #pragma unroll
            for (int m = 1; m < 16; m <<= 1) ss += __shfl_xor(ss, m, 16);
            float r = rsqrtf(ss * (1.0f / 1152.0f) + 1e-6f);
            uint4 pk;
            pk.x = pack2bf(v[0] * r, v[1] * r);
            pk.y = pack2bf(v[2] * r, v[3] * r);
            pk.z = pack2bf(v[4] * r, v[5] * r);
            pk.w = pack2bf(v[6] * r, v[7] * r);
            *reinterpret_cast<uint4*>(&a_s[ni][c8]) = pk;
        }
        __syncthreads();
        node_gemm3(a_s, tid, n0, Wvx, Wa1sx, Wa1dx, Vb, Psb, Pdb);
    }
}

// ---------------- CSR build ----------------
__global__ __launch_bounds__(256)
void k_hist(const int* __restrict__ eidx, int* __restrict__ deg)
{
    int e = blockIdx.x * 256 + threadIdx.x;
    if (e < NE) atomicAdd(&deg[eidx[NE + e]], 1);
}

__global__ __launch_bounds__(1024)
void k_scan(const int* __restrict__ deg, int* __restrict__ off, int* __restrict__ cursor)
{
    __shared__ int part[1024];
    const int t = threadIdx.x;
    const int base = t * 6;
    int loc[6]; int s = 0;
    #pragma unroll
    for (int i = 0; i < 6; ++i) {
        int d = (base + i < NN) ? deg[base + i] : 0;
        loc[i] = s; s += d;
    }
    part[t] = s;
    __syncthreads();
    for (int o = 1; o < 1024; o <<= 1) {
        int v = (t >= o) ? part[t - o] : 0;
        __syncthreads();
        part[t] += v;
        __syncthreads();
    }
    int pre = (t > 0) ? part[t - 1] : 0;
    #pragma unroll
    for (int i = 0; i < 6; ++i) {
        if (base + i < NN) {
            int v = pre + loc[i];
            off[base + i] = v;
            cursor[base + i] = v;
        }
    }
    if (t == 1023) off[NN] = part[1023];
}

__global__ __launch_bounds__(256)
void k_fill(const int* __restrict__ eidx, const int* __restrict__ bondf,
            const float* __restrict__ dist, int* __restrict__ cursor,
            int* __restrict__ srcp, int* __restrict__ dstp,
            float* __restrict__ distp, int* __restrict__ cbp)
{
    int e = blockIdx.x * 256 + threadIdx.x;
    if (e < NE) {
        int d = eidx[NE + e];
        int p = atomicAdd(&cursor[d], 1);
        srcp[p] = eidx[e];
        dstp[p] = d;
        distp[p] = dist[e];
        cbp[p] = bondf[e * 3 + 0] * 64 + bondf[e * 3 + 1] * 8 + bondf[e * 3 + 2];
    }
}

// ---------------- attention: LDS phase A (bf16 t) + MFMA phase B; float2 nex out ----------------
__global__ __launch_bounds__(256)
void k_attn(const int* __restrict__ srcp, const int* __restrict__ dstp,
            const float* __restrict__ distp, const int* __restrict__ cbp,
            const uint* __restrict__ Psb, const uint* __restrict__ Pdb,
            const uint* __restrict__ TAbl, const float* __restrict__ TGl,
            const uint* __restrict__ BAcbl, const float* __restrict__ BGcl,
            const ushort* __restrict__ Wa2xl,
            float2* __restrict__ nex)
{
    __shared__ ushort t_s[32][136];
    __shared__ float gate_s[32][8];
    const int tid = threadIdx.x;
    const int p0 = blockIdx.x * 32;

    {   // phase A
        const int ei = tid >> 3, g = tid & 7;
        const int p = min(p0 + ei, NE - 1);
        const int sn = srcp[p], dn = dstp[p];
        const float d = distp[p];
        const int cb = cbp[p];
        float u = d * ((float)TBM / 5.0f);
        int i = min((int)u, TBM - 1);
        float f = u - (float)i, f1 = 1.f - f;

        uint ps[8], pd[8], t0[8], t1v[8], ba[8];
        {
            const uint4* pp = reinterpret_cast<const uint4*>(&Psb[(size_t)sn * 64 + g * 8]);
            uint4 a = pp[0], b = pp[1];
            ps[0]=a.x; ps[1]=a.y; ps[2]=a.z; ps[3]=a.w; ps[4]=b.x; ps[5]=b.y; ps[6]=b.z; ps[7]=b.w;
            pp = reinterpret_cast<const uint4*>(&Pdb[(size_t)dn * 64 + g * 8]);
            a = pp[0]; b = pp[1];
            pd[0]=a.x; pd[1]=a.y; pd[2]=a.z; pd[3]=a.w; pd[4]=b.x; pd[5]=b.y; pd[6]=b.z; pd[7]=b.w;
            pp = reinterpret_cast<const uint4*>(&TAbl[(size_t)i * 64 + g * 8]);
            a = pp[0]; b = pp[1];
            t0[0]=a.x; t0[1]=a.y; t0[2]=a.z; t0[3]=a.w; t0[4]=b.x; t0[5]=b.y; t0[6]=b.z; t0[7]=b.w;
            pp = reinterpret_cast<const uint4*>(&TAbl[(size_t)(i + 1) * 64 + g * 8]);
            a = pp[0]; b = pp[1];
            t1v[0]=a.x; t1v[1]=a.y; t1v[2]=a.z; t1v[3]=a.w; t1v[4]=b.x; t1v[5]=b.y; t1v[6]=b.z; t1v[7]=b.w;
            pp = reinterpret_cast<const uint4*>(&BAcbl[(size_t)cb * 64 + g * 8]);
            a = pp[0]; b = pp[1];
            ba[0]=a.x; ba[1]=a.y; ba[2]=a.z; ba[3]=a.w; ba[4]=b.x; ba[5]=b.y; ba[6]=b.z; ba[7]=b.w;
        }
        uint tw[8];
        #pragma unroll
        for (int q = 0; q < 8; ++q) {
            float2 vs = up2(ps[q]), vd = up2(pd[q]), v0 = up2(t0[q]), v1 = up2(t1v[q]), vb = up2(ba[q]);
            float s0 = siluf(vs.x + vd.x + f1 * v0.x + f * v1.x + vb.x);
            float s1 = siluf(vs.y + vd.y + f1 * v0.y + f * v1.y + vb.y);
            tw[q] = pack2bf(s0, s1);
        }
        uint4* tp = reinterpret_cast<uint4*>(&t_s[ei][g * 16]);
        tp[0] = make_uint4(tw[0], tw[1], tw[2], tw[3]);
        tp[1] = make_uint4(tw[4], tw[5], tw[6], tw[7]);
        if (g == 0) {
            const float4* tg0 = reinterpret_cast<const float4*>(&TGl[(size_t)i * 8]);
            const float4* bg4 = reinterpret_cast<const float4*>(&BGcl[(size_t)cb * 8]);
            #pragma unroll
            for (int q = 0; q < 2; ++q) {
                float4 g0 = tg0[q], g1 = tg0[q + 2], bb = bg4[q];
                gate_s[ei][4 * q + 0] = f1 * g0.x + f * g1.x + bb.x;
                gate_s[ei][4 * q + 1] = f1 * g0.y + f * g1.y + bb.y;
                gate_s[ei][4 * q + 2] = f1 * g0.z + f * g1.z + bb.z;
                gate_s[ei][4 * q + 3] = f1 * g0.w + f * g1.w + bb.w;
            }
        }
    }
    __syncthreads();

    {   // phase B: logits via MFMA
        const int wq = tid >> 6, l = tid & 63;
        if (wq < 2) {
            const int lr = l & 15, lk = l >> 4;
            float4v acc = (float4v){0.f, 0.f, 0.f, 0.f};
            #pragma unroll
            for (int ks = 0; ks < 4; ++ks) {
                short8v af = *reinterpret_cast<const short8v*>(&t_s[wq * 16 + lr][lk * 8 + ks * 32]);
                short8v bf = *reinterpret_cast<const short8v*>(&Wa2xl[((size_t)ks * 64 + l) * 8]);
                acc = __builtin_amdgcn_mfma_f32_16x16x32_bf16(af, bf, acc, 0, 0, 0);
            }
            const int h = l & 15;
            if (h < 8) {
                #pragma unroll
                for (int r = 0; r < 4; ++r) {
                    int ei = wq * 16 + lk * 4 + r;
                    int p = p0 + ei;
                    if (p < NE) {
                        float ex = __expf(acc[r]);
                        nex[(size_t)p * 8 + h] = make_float2(ex * sigmf(gate_s[ei][h]), ex);
                    }
                }
            }
        }
    }
}

// ======== k_layer_fused: segment-gather + agg@Wo (MFMA) + rms + FFN (+ next gemm3 / finalize) ========
template<int LAST>
__global__ __launch_bounds__(256)
void k_layer_fused(float* __restrict__ x,
                   const int* __restrict__ off, const int* __restrict__ srcp,
                   const float2* __restrict__ nex, const uint* __restrict__ Vb,
                   const ushort* __restrict__ Woxl,
                   const ushort* __restrict__ Wf1xl, const ushort* __restrict__ Wf2xl,
                   float* __restrict__ out,
                   const ushort* __restrict__ WvxN, const ushort* __restrict__ Wa1sxN,
                   const ushort* __restrict__ Wa1dxN,
                   uint* __restrict__ VbO, uint* __restrict__ Psb, uint* __restrict__ Pdb)
{
    __shared__ ushort a_s[16][136];
    __shared__ ushort h_s[16][520];
    __shared__ float xf_s[16][132];
    const int tid = threadIdx.x;
    const int n0 = blockIdx.x * 16;
    const int ni = tid >> 4, c8 = (tid & 15) * 8;

    {   // phase 0: stash x_old
        const float* xr = &x[(size_t)(n0 + ni) * 128 + c8];
        *reinterpret_cast<float4*>(&xf_s[ni][c8])     = *reinterpret_cast<const float4*>(xr);
        *reinterpret_cast<float4*>(&xf_s[ni][c8 + 4]) = *reinterpret_cast<const float4*>(xr + 4);
    }

    {   // phase 1: segment gather; 16 threads/node, 8 channels each
        const int n = n0 + ni;
        const int h = (tid & 15) >> 1;
        const int cd4 = (tid & 15) * 4;
        const int s = off[n], t = off[n + 1];
        float acc[8];
        #pragma unroll
        for (int q = 0; q < 8; ++q) acc[q] = 0.f;
        float es = 0.f;
        int p = s;
        for (; p + 4 <= t; p += 4) {
            int sn0 = srcp[p + 0], sn1 = srcp[p + 1], sn2 = srcp[p + 2], sn3 = srcp[p + 3];
            float2 ne0 = nex[(size_t)(p + 0) * 8 + h];
            float2 ne1 = nex[(size_t)(p + 1) * 8 + h];
            float2 ne2 = nex[(size_t)(p + 2) * 8 + h];
            float2 ne3 = nex[(size_t)(p + 3) * 8 + h];
            uint4 u0 = *reinterpret_cast<const uint4*>(&Vb[(size_t)sn0 * 64 + cd4]);
            uint4 u1 = *reinterpret_cast<const uint4*>(&Vb[(size_t)sn1 * 64 + cd4]);
            uint4 u2 = *reinterpret_cast<const uint4*>(&Vb[(size_t)sn2 * 64 + cd4]);
            uint4 u3 = *reinterpret_cast<const uint4*>(&Vb[(size_t)sn3 * 64 + cd4]);
            es += ne0.y + ne1.y + ne2.y + ne3.y;
            uint uu[4][4] = {{u0.x,u0.y,u0.z,u0.w},{u1.x,u1.y,u1.z,u1.w},
                             {u2.x,u2.y,u2.z,u2.w},{u3.x,u3.y,u3.z,u3.w}};
            float cf[4] = {ne0.x, ne1.x, ne2.x, ne3.x};
            #pragma unroll
            for (int e = 0; e < 4; ++e) {
                #pragma unroll
                for (int q = 0; q < 4; ++q) {
                    float2 v = up2(uu[e][q]);
                    acc[2 * q + 0] += cf[e] * v.x;
                    acc[2 * q + 1] += cf[e] * v.y;
                }
            }
        }
        for (; p < t; ++p) {
            int sn = srcp[p];
            float2 ne = nex[(size_t)p * 8 + h];
            uint4 u = *reinterpret_cast<const uint4*>(&Vb[(size_t)sn * 64 + cd4]);
            es += ne.y;
            uint uu[4] = {u.x, u.y, u.z, u.w};
            #pragma unroll
            for (int q = 0; q < 4; ++q) {
                float2 v = up2(uu[q]);
                acc[2 * q + 0] += ne.x * v.x;
                acc[2 * q + 1] += ne.x * v.y;
            }
        }
        float sinv = 1.f / (es + 1e-9f);
        uint4 pk;
        pk.x = pack2bf(acc[0] * sinv, acc[1] * sinv);
        pk.y = pack2bf(acc[2] * sinv, acc[3] * sinv);
        pk.z = pack2bf(acc[4] * sinv, acc[5] * sinv);
        pk.w = pack2bf(acc[6] * sinv, acc[7] * sinv);
        *reinterpret_cast<uint4*>(&a_s[ni][c8]) = pk;
    }
    __syncthreads();

    const int l  = tid & 63;
    const int wq = tid >> 6;
    const int lr = l & 15, lk = l >> 4;

    {   // phase 2: x_new = x_old + agg @ Wo (MFMA)
        float4v acc2[2];
        acc2[0] = (float4v){0.f, 0.f, 0.f, 0.f};
        acc2[1] = (float4v){0.f, 0.f, 0.f, 0.f};
        #pragma unroll
        for (int ks = 0; ks < 4; ++ks) {
            short8v af = *reinterpret_cast<const short8v*>(&a_s[lr][lk * 8 + ks * 32]);
            #pragma unroll
            for (int nf = 0; nf < 2; ++nf) {
                int nt = wq * 2 + nf;
                short8v bf = *reinterpret_cast<const short8v*>(&Woxl[((size_t)(nt * 4 + ks) * 64 + l) * 8]);
                acc2[nf] = __builtin_amdgcn_mfma_f32_16x16x32_bf16(af, bf, acc2[nf], 0, 0, 0);
            }
        }
        #pragma unroll
        for (int nf = 0; nf < 2; ++nf) {
            #pragma unroll
            for (int r = 0; r < 4; ++r)
                xf_s[lk * 4 + r][(wq * 2 + nf) * 16 + lr] += acc2[nf][r];
        }
    }
    __syncthreads();

    {   // phase 3: rms(x_new) -> a_s (overwrites agg)
        float4 v0 = *reinterpret_cast<const float4*>(&xf_s[ni][c8]);
        float4 v1 = *reinterpret_cast<const float4*>(&xf_s[ni][c8 + 4]);
        float ss = v0.x * v0.x + v0.y * v0.y + v0.z * v0.z + v0.w * v0.w
                 + v1.x * v1.x + v1.y * v1.y + v1.z * v1.z + v1.w * v1.w;
        #pragma unroll
        for (int m = 1; m < 16; m <<= 1) ss += __shfl_xor(ss, m, 16);
        float r = rsqrtf(ss * (1.0f / 1152.0f) + 1e-6f);
        uint4 pk;
        pk.x = pack2bf(v0.x * r, v0.y * r);
        pk.y = pack2bf(v0.z * r, v0.w * r);
        pk.z = pack2bf(v1.x * r, v1.y * r);
        pk.w = pack2bf(v1.z * r, v1.w * r);
        __syncthreads();   // phase-2 a_s reads done before overwrite
        *reinterpret_cast<uint4*>(&a_s[ni][c8]) = pk;
    }
    __syncthreads();

    {   // phase 4: FFN GEMM1 -> h_s
        float4v acc[8];
        #pragma unroll
        for (int nf = 0; nf < 8; ++nf) acc[nf] = (float4v){0.f, 0.f, 0.f, 0.f};
        #pragma unroll
        for (int ks = 0; ks < 4; ++ks) {
            short8v af = *reinterpret_cast<const short8v*>(&a_s[lr][lk * 8 + ks * 32]);
            #pragma unroll
            for (int nf = 0; nf < 8; ++nf) {
                int nt = wq * 8 + nf;
                short8v bf = *reinterpret_cast<const short8v*>(&Wf1xl[((size_t)(nt * 4 + ks) * 64 + l) * 8]);
                acc[nf] = __builtin_amdgcn_mfma_f32_16x16x32_bf16(af, bf, acc[nf], 0, 0, 0);
            }
        }
        #pragma unroll
        for (int nf = 0; nf < 8; ++nf) {
            #pragma unroll
            for (int r = 0; r < 4; ++r) {
                float v = siluf(acc[nf][r]);
                float vn = __shfl_xor(v, 1, 64);
                if ((l & 1) == 0) {
                    int row = lk * 4 + r;
                    int col = wq * 128 + nf * 16 + lr;
                    *reinterpret_cast<uint*>(&h_s[row][col]) = pack2bf(v, vn);
                }
            }
        }
    }
    __syncthreads();

    {   // phase 5: FFN GEMM2 -> delta into xf_s
        float4v acc2[2];
        acc2[0] = (float4v){0.f, 0.f, 0.f, 0.f};
        acc2[1] = (float4v){0.f, 0.f, 0.f, 0.f};
        #pragma unroll 4
        for (int ks = 0; ks < 16; ++ks) {
            short8v af = *reinterpret_cast<const short8v*>(&h_s[lr][lk * 8 + ks * 32]);
            #pragma unroll
            for (int nf = 0; nf < 2; ++nf) {
                int nt = wq * 2 + nf;
                short8v bf = *reinterpret_cast<const short8v*>(&Wf2xl[((size_t)(nt * 16 + ks) * 64 + l) * 8]);
                acc2[nf] = __builtin_amdgcn_mfma_f32_16x16x32_bf16(af, bf, acc2[nf], 0, 0, 0);
            }
        }
        #pragma unroll
        for (int nf = 0; nf < 2; ++nf) {
            #pragma unroll
            for (int r = 0; r < 4; ++r)
                xf_s[lk * 4 + r][(wq * 2 + nf) * 16 + lr] += acc2[nf][r];
        }
    }
    __syncthreads();

    {   // phase 6: final rms -> x + a_s + gemm3, or out
        float4 v0 = *reinterpret_cast<const float4*>(&xf_s[ni][c8]);
        float4 v1 = *reinterpret_cast<const float4*>(&xf_s[ni][c8 + 4]);
        float ss = v0.x * v0.x + v0.y * v0.y + v0.z * v0.z + v0.w * v0.w
                 + v1.x * v1.x + v1.y * v1.y + v1.z * v1.z + v1.w * v1.w;
        #pragma unroll
        for (int m = 1; m < 16; m <<= 1) ss += __shfl_xor(ss, m, 16);
        float r = rsqrtf(ss * (1.0f / 1152.0f) + 1e-6f);

        if (!LAST) {
            float* xr = &x[(size_t)(n0 + ni) * 128 + c8];
            *reinterpret_cast<float4*>(xr)     = v0;
            *reinterpret_cast<float4*>(xr + 4) = v1;
            uint4 pk;
            pk.x = pack2bf(v0.x * r, v0.y * r);
            pk.y = pack2bf(v0.z * r, v0.w * r);
            pk.z = pack2bf(v1.x * r, v1.y * r);
            pk.w = pack2bf(v1.z * r, v1.w * r);
            __syncthreads();
            *reinterpret_cast<uint4*>(&a_s[ni][c8]) = pk;
            __syncthreads();
            node_gemm3(a_s, tid, n0, WvxN, Wa1sxN, Wa1dxN, VbO, Psb, Pdb);
        } else {
            size_t base = (size_t)(n0 + ni) * 1152 + c8;
            *reinterpret_cast<float4*>(&out[base])     = make_float4(v0.x * r, v0.y * r, v0.z * r, v0.w * r);
            *reinterpret_cast<float4*>(&out[base + 4]) = make_float4(v1.x * r, v1.y * r, v1.z * r, v1.w * r);
            const float4 z4 = make_float4(0.f, 0.f, 0.f, 0.f);
            #pragma unroll
            for (int k = 1; k < 9; ++k) {
                *reinterpret_cast<float4*>(&out[base + (size_t)k * 128]) = z4;
                *reinterpret_cast<float4*>(&out[base + (size_t)k * 128 + 4]) = z4;
            }
        }
    }
}

extern "C" void kernel_launch(void* const* d_in, const int* in_sizes, int n_in,
                              void* d_out, int out_size, void* d_ws, size_t ws_size,
                              hipStream_t stream)
{
    const int*   atom_feats = (const int*)d_in[0];
    const int*   bond_feats = (const int*)d_in[1];
    const int*   edge_index = (const int*)d_in[2];
    const float* edge_dist  = (const float*)d_in[3];
    const float* atom_emb   = (const float*)d_in[4];
    const float* bond_emb   = (const float*)d_in[5];
    const float* W_rbf1     = (const float*)d_in[6];
    const float* b_rbf1     = (const float*)d_in[7];
    const float* W_rbf2     = (const float*)d_in[8];
    const float* b_rbf2     = (const float*)d_in[9];
    const float* Wa1        = (const float*)d_in[10];
    const float* Wa2        = (const float*)d_in[11];
    const float* Wv         = (const float*)d_in[12];
    const float* Wg         = (const float*)d_in[13];
    const float* Wo         = (const float*)d_in[14];
    const float* Wf1        = (const float*)d_in[15];
    const float* Wf2        = (const float*)d_in[16];
    float* out = (float*)d_out;

    float* ws   = (float*)d_ws;
    float* x    = ws;                           // NN*128
    float2* nex = (float2*)(x + NN * 128);      // NE*8 float2
    float* W2A  = (float*)(nex + (size_t)NE * 8);   // 2*16384
    float* W2G  = W2A  + 2 * 16384;             // 2*1024
    float* bA   = W2G  + 2 * 1024;              // 2*128
    float* bG   = bA   + 2 * 128;               // 16
    float* TG   = bG   + 16;                    // 2*TROWS*8
    float* BGc  = TG   + 2 * (size_t)TROWS * 8; // 2*512*8
    float* distp = BGc + 2 * 512 * 8;           // NE
    uint* Vb    = (uint*)(distp + NE);          // NN*64
    uint* Psb   = Vb  + NN * 64;
    uint* Pdb   = Psb + NN * 64;
    uint* TAb   = Pdb + NN * 64;                // 2*TROWS*64
    uint* BAcb  = TAb + 2 * (size_t)TROWS * 64; // 2*512*64
    ushort* Wf1x  = (ushort*)(BAcb + 2 * 512 * 64);  // 2*65536
    ushort* Wf2x  = Wf1x  + 2 * 65536;
    ushort* Wvx   = Wf2x  + 2 * 65536;
    ushort* Wa1sx = Wvx   + 2 * 16384;
    ushort* Wa1dx = Wa1sx + 2 * 16384;
    ushort* Wa2x  = Wa1dx + 2 * 16384;               // 2*2048
    ushort* Wox   = Wa2x  + 2 * 2048;                // 2*16384
    int* deg    = (int*)(Wox + 2 * 16384);
    int* off    = deg + NN;
    int* cursor = off + NN + 1;
    int* srcp   = cursor + NN;                  // NE
    int* dstp   = srcp + NE;                    // NE
    int* cbp    = dstp + NE;                    // NE

    k_prep<<<dim3(371, 2), 256, 0, stream>>>(W_rbf2, b_rbf2, Wa1, Wg, bond_emb,
        Wf1, Wf2, Wv, Wa2, Wo, W2A, W2G, bA, bG, BAcb, BGc,
        Wf1x, Wf2x, Wvx, Wa1sx, Wa1dx, Wa2x, Wox);
    k_prep2<<<514 + NN / 16, 256, 0, stream>>>(W_rbf1, b_rbf1, W2A, W2G, bA, bG, TAb, TG,
        atom_feats, atom_emb, x, deg, Wvx, Wa1sx, Wa1dx, Vb, Psb, Pdb);

    k_hist<<<(NE + 255) / 256, 256, 0, stream>>>(edge_index, deg);
    k_scan<<<1, 1024, 0, stream>>>(deg, off, cursor);
    k_fill<<<(NE + 255) / 256, 256, 0, stream>>>(edge_index, bond_feats, edge_dist,
                                                 cursor, srcp, dstp, distp, cbp);

    for (int l = 0; l < 2; ++l) {
        k_attn<<<(NE + 31) / 32, 256, 0, stream>>>(srcp, dstp, distp, cbp,
            Psb, Pdb,
            TAb + (size_t)l * TROWS * 64, TG + (size_t)l * TROWS * 8,
            BAcb + (size_t)l * 512 * 64, BGc + (size_t)l * 512 * 8,
            Wa2x + (size_t)l * 2048, nex);
        if (l == 0)
            k_layer_fused<0><<<NN / 16, 256, 0, stream>>>(x, off, srcp, nex, Vb,
                Wox, Wf1x, Wf2x, out,
                Wvx + 16384, Wa1sx + 16384, Wa1dx + 16384, Vb, Psb, Pdb);
        else
            k_layer_fused<1><<<NN / 16, 256, 0, stream>>>(x, off, srcp, nex, Vb,
                Wox + 16384, Wf1x + 65536, Wf2x + 65536, out,
                Wvx, Wa1sx, Wa1dx, Vb, Psb, Pdb);
    }
}

// Round 12
// 155.420 us; speedup vs baseline: 2.0757x; 1.0785x over previous
//
#include <hip/hip_runtime.h>

#define NN 6000
#define NE 150000
#define TBM 2048
#define TROWS (TBM + 1)

typedef unsigned int uint;
typedef unsigned short ushort;
typedef __attribute__((ext_vector_type(8))) short short8v;
typedef __attribute__((ext_vector_type(4))) float float4v;

__device__ __forceinline__ float siluf(float x) { return x / (1.f + __expf(-x)); }
__device__ __forceinline__ float sigmf(float x) { return 1.f / (1.f + __expf(-x)); }
__device__ __forceinline__ uint pack2bf(float lo, float hi) {
    uint ul = __float_as_uint(lo);
    ul = (ul + 0x7fffu + ((ul >> 16) & 1u)) >> 16;
    uint uh = __float_as_uint(hi);
    uh = ((uh + 0x7fffu + ((uh >> 16) & 1u)) >> 16) << 16;
    return ul | uh;
}
__device__ __forceinline__ ushort f2bf(float f) {
    uint u = __float_as_uint(f);
    return (ushort)((u + 0x7fffu + ((u >> 16) & 1u)) >> 16);
}
__device__ __forceinline__ float2 up2(uint u) {
    return make_float2(__uint_as_float(u << 16), __uint_as_float(u & 0xffff0000u));
}

// ================ k_prep: w2a | bondtabs | packw (+Wa2x, Wox) ================
__global__ __launch_bounds__(256)
void k_prep(const float* __restrict__ W2, const float* __restrict__ b2,
            const float* __restrict__ Wa1, const float* __restrict__ Wg,
            const float* __restrict__ bemb,
            const float* __restrict__ Wf1, const float* __restrict__ Wf2,
            const float* __restrict__ Wv, const float* __restrict__ Wa2,
            const float* __restrict__ Wo,
            float* __restrict__ W2A, float* __restrict__ W2G,
            float* __restrict__ bA, float* __restrict__ bG,
            uint* __restrict__ BAcb, float* __restrict__ BGc,
            ushort* __restrict__ Wf1x, ushort* __restrict__ Wf2x,
            ushort* __restrict__ Wvx, ushort* __restrict__ Wa1sx,
            ushort* __restrict__ Wa1dx, ushort* __restrict__ Wa2x,
            ushort* __restrict__ Wox)
{
    __shared__ float w2_s[8][132];
    const int l = blockIdx.y, bx = blockIdx.x, tid = threadIdx.x;
    const float* Wa1e = Wa1 + (size_t)l * 384 * 128 + 256 * 128;
    const float* Wgl  = Wg  + (size_t)l * 128 * 8;

    if (bx < 16) {
        const int i0 = bx * 8;
        for (int q = tid; q < 8 * 32; q += 256) {
            int ni = q >> 5, j4 = (q & 31) * 4;
            *reinterpret_cast<float4*>(&w2_s[ni][j4]) =
                *reinterpret_cast<const float4*>(&W2[(size_t)(i0 + ni) * 128 + j4]);
        }
        __syncthreads();
        const int j = tid & 127, ng = tid >> 7;
        float a[4] = {0.f, 0.f, 0.f, 0.f};
        #pragma unroll 4
        for (int k4 = 0; k4 < 128; k4 += 4) {
            float w0 = Wa1e[(k4 + 0) * 128 + j];
            float w1 = Wa1e[(k4 + 1) * 128 + j];
            float w2v = Wa1e[(k4 + 2) * 128 + j];
            float w3 = Wa1e[(k4 + 3) * 128 + j];
            #pragma unroll
            for (int r = 0; r < 4; ++r) {
                const float4 xv = *reinterpret_cast<const float4*>(&w2_s[ng * 4 + r][k4]);
                a[r] += xv.x * w0 + xv.y * w1 + xv.z * w2v + xv.w * w3;
            }
        }
        #pragma unroll
        for (int r = 0; r < 4; ++r)
            W2A[(size_t)l * 16384 + (size_t)(i0 + ng * 4 + r) * 128 + j] = a[r];
    } else if (bx == 16) {
        const int i = tid & 127, hq = tid >> 7;
        float a[4] = {0.f, 0.f, 0.f, 0.f};
        for (int k = 0; k < 128; ++k) {
            float w = W2[(size_t)i * 128 + k];
            const float4 g4 = *reinterpret_cast<const float4*>(&Wgl[k * 8 + hq * 4]);
            a[0] += w * g4.x; a[1] += w * g4.y; a[2] += w * g4.z; a[3] += w * g4.w;
        }
        #pragma unroll
        for (int q = 0; q < 4; ++q)
            W2G[(size_t)l * 1024 + (size_t)i * 8 + hq * 4 + q] = a[q];
    } else if (bx == 17) {
        if (tid < 128) {
            float s = 0.f;
            for (int k = 0; k < 128; ++k) s += b2[k] * Wa1e[k * 128 + tid];
            bA[l * 128 + tid] = s;
        } else if (tid < 136) {
            int h = tid - 128;
            float s = 0.f;
            for (int k = 0; k < 128; ++k) s += b2[k] * Wgl[k * 8 + h];
            bG[l * 8 + h] = s;
        }
    } else if (bx < 274) {
        const int cb = (bx - 18) * 2 + (tid >> 7);
        const int c = tid & 127;
        const int b[3] = {cb >> 6, (cb >> 3) & 7, cb & 7};
        float s = 0.f;
        #pragma unroll
        for (int f = 0; f < 3; ++f) {
            const float* er = &bemb[(size_t)(f * 8 + b[f]) * 128];
            for (int k = 0; k < 128; ++k)
                s += er[k] * Wa1e[k * 128 + c];
        }
        float hi = __shfl_down(s, 1, 64);
        if ((c & 1) == 0)
            BAcb[(size_t)l * 512 * 64 + (size_t)cb * 64 + (c >> 1)] = pack2bf(s, hi);
        if (c < 8) {
            float g = 0.f;
            #pragma unroll
            for (int f = 0; f < 3; ++f) {
                const float* er = &bemb[(size_t)(f * 8 + b[f]) * 128];
                for (int k = 0; k < 128; ++k)
                    g += er[k] * Wgl[k * 8 + c];
            }
            BGc[(size_t)l * 512 * 8 + (size_t)cb * 8 + c] = g;
        }
    } else {
        const int sub = (bx - 274) * 4 + (tid >> 6);
        const int lane = tid & 63;
        if (sub < 128) {
            const int nt = sub >> 2, kt = sub & 3;
            const float* src = Wf1 + (size_t)l * 65536;
            ushort* dst = Wf1x + (size_t)l * 65536 + ((size_t)sub * 64 + lane) * 8;
            #pragma unroll
            for (int j = 0; j < 8; ++j)
                dst[j] = f2bf(src[(size_t)(kt * 32 + (lane >> 4) * 8 + j) * 512 + nt * 16 + (lane & 15)]);
        } else if (sub < 256) {
            const int b2x = sub - 128;
            const int nt = b2x >> 4, kt = b2x & 15;
            const float* src = Wf2 + (size_t)l * 65536;
            ushort* dst = Wf2x + (size_t)l * 65536 + ((size_t)b2x * 64 + lane) * 8;
            #pragma unroll
            for (int j = 0; j < 8; ++j)
                dst[j] = f2bf(src[(size_t)(kt * 32 + (lane >> 4) * 8 + j) * 128 + nt * 16 + (lane & 15)]);
        } else if (sub < 352) {
            const int b3 = sub - 256;
            const int mat = b3 >> 5, blk = b3 & 31;
            const int nt = blk >> 2, kt = blk & 3;
            const float* src;
            ushort* dst;
            if (mat == 0)      { src = Wv  + (size_t)l * 16384;             dst = Wvx   + (size_t)l * 16384; }
            else if (mat == 1) { src = Wa1 + (size_t)l * 384 * 128;         dst = Wa1sx + (size_t)l * 16384; }
            else               { src = Wa1 + (size_t)l * 384 * 128 + 16384; dst = Wa1dx + (size_t)l * 16384; }
            dst += ((size_t)blk * 64 + lane) * 8;
            #pragma unroll
            for (int j = 0; j < 8; ++j)
                dst[j] = f2bf(src[(size_t)(kt * 32 + (lane >> 4) * 8 + j) * 128 + nt * 16 + (lane & 15)]);
        } else if (sub < 356) {
            const int kt = sub - 352;
            const int col = lane & 15;
            const float* src = Wa2 + (size_t)l * 128 * 8;
            ushort* dst = Wa2x + (size_t)l * 2048 + ((size_t)kt * 64 + lane) * 8;
            #pragma unroll
            for (int j = 0; j < 8; ++j) {
                int krow = kt * 32 + (lane >> 4) * 8 + j;
                dst[j] = (col < 8) ? f2bf(src[(size_t)krow * 8 + col]) : (ushort)0;
            }
        } else {
            const int blk = sub - 356;
            const int nt = blk >> 2, kt = blk & 3;
            const float* src = Wo + (size_t)l * 16384;
            ushort* dst = Wox + (size_t)l * 16384 + ((size_t)blk * 64 + lane) * 8;
            #pragma unroll
            for (int j = 0; j < 8; ++j)
                dst[j] = f2bf(src[(size_t)(kt * 32 + (lane >> 4) * 8 + j) * 128 + nt * 16 + (lane & 15)]);
        }
    }
}

// ---------------- node GEMMs helper: 4-wave (256-thread) version ----------------
__device__ __forceinline__
void node_gemm3(const ushort a_s[16][136], int tid, int n0,
                const ushort* __restrict__ Wvx, const ushort* __restrict__ Wa1sx,
                const ushort* __restrict__ Wa1dx,
                uint* __restrict__ Vb, uint* __restrict__ Psb, uint* __restrict__ Pdb)
{
    const int l = tid & 63, wq = tid >> 6;
    const int lr = l & 15, lk = l >> 4;
    #pragma unroll
    for (int jb = 0; jb < 6; ++jb) {
        int job = wq * 6 + jb;
        int mat = job >> 3, nt = job & 7;
        const ushort* W = (mat == 0) ? Wvx : (mat == 1 ? Wa1sx : Wa1dx);
        uint* O = (mat == 0) ? Vb : (mat == 1 ? Psb : Pdb);
        float4v acc = (float4v){0.f, 0.f, 0.f, 0.f};
        #pragma unroll
        for (int ks = 0; ks < 4; ++ks) {
            short8v af = *reinterpret_cast<const short8v*>(&a_s[lr][lk * 8 + ks * 32]);
            short8v bf = *reinterpret_cast<const short8v*>(&W[((size_t)(nt * 4 + ks) * 64 + l) * 8]);
            acc = __builtin_amdgcn_mfma_f32_16x16x32_bf16(af, bf, acc, 0, 0, 0);
        }
        #pragma unroll
        for (int r = 0; r < 4; ++r) {
            float v = acc[r];
            float vn = __shfl_xor(v, 1, 64);
            if ((l & 1) == 0) {
                int row = lk * 4 + r, col = nt * 16 + lr;
                O[(size_t)(n0 + row) * 64 + (col >> 1)] = pack2bf(v, vn);
            }
        }
    }
}

// ---------------- node GEMMs helper: 8-wave (512-thread) version ----------------
__device__ __forceinline__
void node_gemm3_8w(const ushort a_s[16][136], int tid, int n0,
                   const ushort* __restrict__ Wvx, const ushort* __restrict__ Wa1sx,
                   const ushort* __restrict__ Wa1dx,
                   uint* __restrict__ Vb, uint* __restrict__ Psb, uint* __restrict__ Pdb)
{
    const int l = tid & 63, w = tid >> 6;
    const int lr = l & 15, lk = l >> 4;
    #pragma unroll
    for (int jb = 0; jb < 3; ++jb) {
        int job = w * 3 + jb;
        int mat = job >> 3, nt = job & 7;
        const ushort* W = (mat == 0) ? Wvx : (mat == 1 ? Wa1sx : Wa1dx);
        uint* O = (mat == 0) ? Vb : (mat == 1 ? Psb : Pdb);
        float4v acc = (float4v){0.f, 0.f, 0.f, 0.f};
        #pragma unroll
        for (int ks = 0; ks < 4; ++ks) {
            short8v af = *reinterpret_cast<const short8v*>(&a_s[lr][lk * 8 + ks * 32]);
            short8v bf = *reinterpret_cast<const short8v*>(&W[((size_t)(nt * 4 + ks) * 64 + l) * 8]);
            acc = __builtin_amdgcn_mfma_f32_16x16x32_bf16(af, bf, acc, 0, 0, 0);
        }
        #pragma unroll
        for (int r = 0; r < 4; ++r) {
            float v = acc[r];
            float vn = __shfl_xor(v, 1, 64);
            if ((l & 1) == 0) {
                int row = lk * 4 + r, col = nt * 16 + lr;
                O[(size_t)(n0 + row) * 64 + (col >> 1)] = pack2bf(v, vn);
            }
        }
    }
}

// ================ k_prep2: t1ta (bx<514) | embed+gemm (bx>=514) ================
__global__ __launch_bounds__(256)
void k_prep2(const float* __restrict__ W1, const float* __restrict__ b1,
             const float* __restrict__ W2A, const float* __restrict__ W2G,
             const float* __restrict__ bA, const float* __restrict__ bG,
             uint* __restrict__ TAb, float* __restrict__ TG,
             const int* __restrict__ af, const float* __restrict__ aemb,
             float* __restrict__ x, int* __restrict__ deg,
             const ushort* __restrict__ Wvx, const ushort* __restrict__ Wa1sx,
             const ushort* __restrict__ Wa1dx,
             uint* __restrict__ Vb, uint* __restrict__ Psb, uint* __restrict__ Pdb)
{
    __shared__ float rbf_s[8][32];
    __shared__ int   bs_s[8];
    __shared__ float t1_s[8][132];
    __shared__ ushort a_s[16][136];
    const int tid = threadIdx.x, bx = blockIdx.x;

    if (bx < 514) {
        const int l = (bx >= 257) ? 1 : 0;
        const int r0 = (bx - l * 257) * 8;
        {
            int ri = tid >> 5, j = tid & 31;
            int row = min(r0 + ri, TBM);
            float d = (float)row * (5.0f / TBM);
            const float step = 5.0f / 511.0f;
            const float invw = 512.0f / 5.0f;
            int b0 = (int)(d * (511.0f / 5.0f) + 0.5f);
            int bs = min(max(b0 - 16, 0), 512 - 32);
            if (j == 0) bs_s[ri] = bs;
            float z = (d - (float)(bs + j) * step) * invw;
            rbf_s[ri][j] = __expf(-z * z);
        }
        __syncthreads();
        #pragma unroll
        for (int pass = 0; pass < 4; ++pass) {
            int idx = pass * 256 + tid;
            int ri = idx >> 7, c = idx & 127;
            int bs = bs_s[ri];
            float t = b1[c];
            #pragma unroll
            for (int j = 0; j < 32; ++j)
                t += rbf_s[ri][j] * W1[(bs + j) * 128 + c];
            t1_s[ri][c] = siluf(t);
        }
        __syncthreads();

        const float* W2Al = W2A + (size_t)l * 16384;
        const int c = tid & 127, ng = tid >> 7;
        float a[4];
        #pragma unroll
        for (int r = 0; r < 4; ++r) a[r] = bA[l * 128 + c];
        #pragma unroll 4
        for (int k4 = 0; k4 < 128; k4 += 4) {
            float w0 = W2Al[(k4 + 0) * 128 + c];
            float w1 = W2Al[(k4 + 1) * 128 + c];
            float w2v = W2Al[(k4 + 2) * 128 + c];
            float w3 = W2Al[(k4 + 3) * 128 + c];
            #pragma unroll
            for (int r = 0; r < 4; ++r) {
                const float4 xv = *reinterpret_cast<const float4*>(&t1_s[ng * 4 + r][k4]);
                a[r] += xv.x * w0 + xv.y * w1 + xv.z * w2v + xv.w * w3;
            }
        }
        #pragma unroll
        for (int r = 0; r < 4; ++r) {
            float hi = __shfl_down(a[r], 1, 64);
            int row = r0 + ng * 4 + r;
            if (((c & 1) == 0) && row <= TBM)
                TAb[(size_t)l * TROWS * 64 + (size_t)row * 64 + (c >> 1)] = pack2bf(a[r], hi);
        }
        if (tid < 64) {
            int ri = tid >> 3, h = tid & 7;
            int row = r0 + ri;
            if (row <= TBM) {
                const float* W2Gl = W2G + (size_t)l * 1024;
                float s = bG[l * 8 + h];
                #pragma unroll 8
                for (int k = 0; k < 128; ++k)
                    s += t1_s[ri][k] * W2Gl[k * 8 + h];
                TG[(size_t)l * TROWS * 8 + (size_t)row * 8 + h] = s;
            }
        }
    } else {
        const int n0 = (bx - 514) * 16;
        if (tid < 16) deg[n0 + tid] = 0;
        {
            int ni = tid >> 4, c8 = (tid & 15) * 8;
            int n = n0 + ni;
            float v[8];
            #pragma unroll
            for (int q = 0; q < 8; ++q) v[q] = 0.f;
            #pragma unroll
            for (int f = 0; f < 4; ++f) {
                int idx = af[n * 4 + f];
                const float* er = &aemb[(size_t)(f * 10 + idx) * 128 + c8];
                float4 e0 = *reinterpret_cast<const float4*>(er);
                float4 e1 = *reinterpret_cast<const float4*>(er + 4);
                v[0] += e0.x; v[1] += e0.y; v[2] += e0.z; v[3] += e0.w;
                v[4] += e1.x; v[5] += e1.y; v[6] += e1.z; v[7] += e1.w;
            }
            float* xr = &x[(size_t)n * 128 + c8];
            *reinterpret_cast<float4*>(xr)     = make_float4(v[0], v[1], v[2], v[3]);
            *reinterpret_cast<float4*>(xr + 4) = make_float4(v[4], v[5], v[6], v[7]);
            float ss = 0.f;
            #pragma unroll
            for (int q = 0; q < 8; ++q) ss += v[q] * v[q];
            #pragma unroll
            for (int m = 1; m < 16; m <<= 1) ss += __shfl_xor(ss, m, 16);
            float r = rsqrtf(ss * (1.0f / 1152.0f) + 1e-6f);
            uint4 pk;
            pk.x = pack2bf(v[0] * r, v[1] * r);
            pk.y = pack2bf(v[2] * r, v[3] * r);
            pk.z = pack2bf(v[4] * r, v[5] * r);
            pk.w = pack2bf(v[6] * r, v[7] * r);
            *reinterpret_cast<uint4*>(&a_s[ni][c8]) = pk;
        }
        __syncthreads();
        node_gemm3(a_s, tid, n0, Wvx, Wa1sx, Wa1dx, Vb, Psb, Pdb);
    }
}

// ---------------- CSR build ----------------
__global__ __launch_bounds__(256)
void k_hist(const int* __restrict__ eidx, int* __restrict__ deg)
{
    int e = blockIdx.x * 256 + threadIdx.x;
    if (e < NE) atomicAdd(&deg[eidx[NE + e]], 1);
}

__global__ __launch_bounds__(1024)
void k_scan(const int* __restrict__ deg, int* __restrict__ off, int* __restrict__ cursor)
{
    __shared__ int part[1024];
    const int t = threadIdx.x;
    const int base = t * 6;
    int loc[6]; int s = 0;
    #pragma unroll
    for (int i = 0; i < 6; ++i) {
        int d = (base + i < NN) ? deg[base + i] : 0;
        loc[i] = s; s += d;
    }
    part[t] = s;
    __syncthreads();
    for (int o = 1; o < 1024; o <<= 1) {
        int v = (t >= o) ? part[t - o] : 0;
        __syncthreads();
        part[t] += v;
        __syncthreads();
    }
    int pre = (t > 0) ? part[t - 1] : 0;
    #pragma unroll
    for (int i = 0; i < 6; ++i) {
        if (base + i < NN) {
            int v = pre + loc[i];
            off[base + i] = v;
            cursor[base + i] = v;
        }
    }
    if (t == 1023) off[NN] = part[1023];
}

__global__ __launch_bounds__(256)
void k_fill(const int* __restrict__ eidx, const int* __restrict__ bondf,
            const float* __restrict__ dist, int* __restrict__ cursor,
            int* __restrict__ srcp, int4* __restrict__ erec)
{
    int e = blockIdx.x * 256 + threadIdx.x;
    if (e < NE) {
        int d = eidx[NE + e];
        int p = atomicAdd(&cursor[d], 1);
        int sn = eidx[e];
        srcp[p] = sn;
        erec[p] = make_int4(sn, d, __float_as_int(dist[e]),
                            bondf[e * 3 + 0] * 64 + bondf[e * 3 + 1] * 8 + bondf[e * 3 + 2]);
    }
}

// ---------------- attention: LDS phase A (bf16 t) + MFMA phase B; float2 nex out ----------------
__global__ __launch_bounds__(256)
void k_attn(const int4* __restrict__ erec,
            const uint* __restrict__ Psb, const uint* __restrict__ Pdb,
            const uint* __restrict__ TAbl, const float* __restrict__ TGl,
            const uint* __restrict__ BAcbl, const float* __restrict__ BGcl,
            const ushort* __restrict__ Wa2xl,
            float2* __restrict__ nex)
{
    __shared__ ushort t_s[32][136];
    __shared__ float gate_s[32][8];
    const int tid = threadIdx.x;
    const int p0 = blockIdx.x * 32;

    {   // phase A
        const int ei = tid >> 3, g = tid & 7;
        const int p = min(p0 + ei, NE - 1);
        const int4 er = erec[p];
        const int sn = er.x, dn = er.y;
        const float d = __int_as_float(er.z);
        const int cb = er.w;
        float u = d * ((float)TBM / 5.0f);
        int i = min((int)u, TBM - 1);
        float f = u - (float)i, f1 = 1.f - f;

        uint ps[8], pd[8], t0[8], t1v[8], ba[8];
        {
            const uint4* pp = reinterpret_cast<const uint4*>(&Psb[(size_t)sn * 64 + g * 8]);
            uint4 a = pp[0], b = pp[1];
            ps[0]=a.x; ps[1]=a.y; ps[2]=a.z; ps[3]=a.w; ps[4]=b.x; ps[5]=b.y; ps[6]=b.z; ps[7]=b.w;
            pp = reinterpret_cast<const uint4*>(&Pdb[(size_t)dn * 64 + g * 8]);
            a = pp[0]; b = pp[1];
            pd[0]=a.x; pd[1]=a.y; pd[2]=a.z; pd[3]=a.w; pd[4]=b.x; pd[5]=b.y; pd[6]=b.z; pd[7]=b.w;
            pp = reinterpret_cast<const uint4*>(&TAbl[(size_t)i * 64 + g * 8]);
            a = pp[0]; b = pp[1];
            t0[0]=a.x; t0[1]=a.y; t0[2]=a.z; t0[3]=a.w; t0[4]=b.x; t0[5]=b.y; t0[6]=b.z; t0[7]=b.w;
            pp = reinterpret_cast<const uint4*>(&TAbl[(size_t)(i + 1) * 64 + g * 8]);
            a = pp[0]; b = pp[1];
            t1v[0]=a.x; t1v[1]=a.y; t1v[2]=a.z; t1v[3]=a.w; t1v[4]=b.x; t1v[5]=b.y; t1v[6]=b.z; t1v[7]=b.w;
            pp = reinterpret_cast<const uint4*>(&BAcbl[(size_t)cb * 64 + g * 8]);
            a = pp[0]; b = pp[1];
            ba[0]=a.x; ba[1]=a.y; ba[2]=a.z; ba[3]=a.w; ba[4]=b.x; ba[5]=b.y; ba[6]=b.z; ba[7]=b.w;
        }
        uint tw[8];
        #pragma unroll
        for (int q = 0; q < 8; ++q) {
            float2 vs = up2(ps[q]), vd = up2(pd[q]), v0 = up2(t0[q]), v1 = up2(t1v[q]), vb = up2(ba[q]);
            float s0 = siluf(vs.x + vd.x + f1 * v0.x + f * v1.x + vb.x);
            float s1 = siluf(vs.y + vd.y + f1 * v0.y + f * v1.y + vb.y);
            tw[q] = pack2bf(s0, s1);
        }
        uint4* tp = reinterpret_cast<uint4*>(&t_s[ei][g * 16]);
        tp[0] = make_uint4(tw[0], tw[1], tw[2], tw[3]);
        tp[1] = make_uint4(tw[4], tw[5], tw[6], tw[7]);
        if (g == 0) {
            const float4* tg0 = reinterpret_cast<const float4*>(&TGl[(size_t)i * 8]);
            const float4* bg4 = reinterpret_cast<const float4*>(&BGcl[(size_t)cb * 8]);
            #pragma unroll
            for (int q = 0; q < 2; ++q) {
                float4 g0 = tg0[q], g1 = tg0[q + 2], bb = bg4[q];
                gate_s[ei][4 * q + 0] = f1 * g0.x + f * g1.x + bb.x;
                gate_s[ei][4 * q + 1] = f1 * g0.y + f * g1.y + bb.y;
                gate_s[ei][4 * q + 2] = f1 * g0.z + f * g1.z + bb.z;
                gate_s[ei][4 * q + 3] = f1 * g0.w + f * g1.w + bb.w;
            }
        }
    }
    __syncthreads();

    {   // phase B: logits via MFMA
        const int wq = tid >> 6, l = tid & 63;
        if (wq < 2) {
            const int lr = l & 15, lk = l >> 4;
            float4v acc = (float4v){0.f, 0.f, 0.f, 0.f};
            #pragma unroll
            for (int ks = 0; ks < 4; ++ks) {
                short8v af = *reinterpret_cast<const short8v*>(&t_s[wq * 16 + lr][lk * 8 + ks * 32]);
                short8v bf = *reinterpret_cast<const short8v*>(&Wa2xl[((size_t)ks * 64 + l) * 8]);
                acc = __builtin_amdgcn_mfma_f32_16x16x32_bf16(af, bf, acc, 0, 0, 0);
            }
            const int h = l & 15;
            if (h < 8) {
                #pragma unroll
                for (int r = 0; r < 4; ++r) {
                    int ei = wq * 16 + lk * 4 + r;
                    int p = p0 + ei;
                    if (p < NE) {
                        float ex = __expf(acc[r]);
                        nex[(size_t)p * 8 + h] = make_float2(ex * sigmf(gate_s[ei][h]), ex);
                    }
                }
            }
        }
    }
}

// ======== k_layer_fused (512 thr): gather + agg@Wo + rms + FFN (+ next gemm3 / finalize) ========
template<int LAST>
__global__ __launch_bounds__(512)
void k_layer_fused(float* __restrict__ x,
                   const int* __restrict__ off, const int* __restrict__ srcp,
                   const float2* __restrict__ nex, const uint* __restrict__ Vb,
                   const ushort* __restrict__ Woxl,
                   const ushort* __restrict__ Wf1xl, const ushort* __restrict__ Wf2xl,
                   float* __restrict__ out,
                   const ushort* __restrict__ WvxN, const ushort* __restrict__ Wa1sxN,
                   const ushort* __restrict__ Wa1dxN,
                   uint* __restrict__ VbO, uint* __restrict__ Psb, uint* __restrict__ Pdb)
{
    __shared__ ushort a_s[16][136];
    __shared__ ushort h_s[16][520];
    __shared__ float xf_s[16][132];
    const int tid = threadIdx.x;
    const int n0 = blockIdx.x * 16;
    const int ni = tid >> 5;            // 16 nodes, 32 threads each
    const int ci = tid & 31;            // 4 channels per thread
    const int c4 = ci * 4;

    {   // phase 0: stash x_old (4 floats/thread)
        *reinterpret_cast<float4*>(&xf_s[ni][c4]) =
            *reinterpret_cast<const float4*>(&x[(size_t)(n0 + ni) * 128 + c4]);
    }

    {   // phase 1: segment gather; 32 threads/node, 4 channels each
        const int n = n0 + ni;
        const int h = ci >> 2;
        const int cd2 = ci * 2;         // uint index: 2 uints = 4 bf16 channels
        const int s = off[n], t = off[n + 1];
        float a0 = 0.f, a1 = 0.f, a2 = 0.f, a3 = 0.f, es = 0.f;
        int p = s;
        for (; p + 4 <= t; p += 4) {
            int sn0 = srcp[p + 0], sn1 = srcp[p + 1], sn2 = srcp[p + 2], sn3 = srcp[p + 3];
            float2 ne0 = nex[(size_t)(p + 0) * 8 + h];
            float2 ne1 = nex[(size_t)(p + 1) * 8 + h];
            float2 ne2 = nex[(size_t)(p + 2) * 8 + h];
            float2 ne3 = nex[(size_t)(p + 3) * 8 + h];
            uint2 u0 = *reinterpret_cast<const uint2*>(&Vb[(size_t)sn0 * 64 + cd2]);
            uint2 u1 = *reinterpret_cast<const uint2*>(&Vb[(size_t)sn1 * 64 + cd2]);
            uint2 u2 = *reinterpret_cast<const uint2*>(&Vb[(size_t)sn2 * 64 + cd2]);
            uint2 u3 = *reinterpret_cast<const uint2*>(&Vb[(size_t)sn3 * 64 + cd2]);
            es += ne0.y + ne1.y + ne2.y + ne3.y;
            float2 v;
            v = up2(u0.x); a0 += ne0.x * v.x; a1 += ne0.x * v.y;
            v = up2(u0.y); a2 += ne0.x * v.x; a3 += ne0.x * v.y;
            v = up2(u1.x); a0 += ne1.x * v.x; a1 += ne1.x * v.y;
            v = up2(u1.y); a2 += ne1.x * v.x; a3 += ne1.x * v.y;
            v = up2(u2.x); a0 += ne2.x * v.x; a1 += ne2.x * v.y;
            v = up2(u2.y); a2 += ne2.x * v.x; a3 += ne2.x * v.y;
            v = up2(u3.x); a0 += ne3.x * v.x; a1 += ne3.x * v.y;
            v = up2(u3.y); a2 += ne3.x * v.x; a3 += ne3.x * v.y;
        }
        for (; p < t; ++p) {
            int sn = srcp[p];
            float2 ne = nex[(size_t)p * 8 + h];
            uint2 u = *reinterpret_cast<const uint2*>(&Vb[(size_t)sn * 64 + cd2]);
            es += ne.y;
            float2 v;
            v = up2(u.x); a0 += ne.x * v.x; a1 += ne.x * v.y;
            v = up2(u.y); a2 += ne.x * v.x; a3 += ne.x * v.y;
        }
        float sinv = 1.f / (es + 1e-9f);
        uint2 pk;
        pk.x = pack2bf(a0 * sinv, a1 * sinv);
        pk.y = pack2bf(a2 * sinv, a3 * sinv);
        *reinterpret_cast<uint2*>(&a_s[ni][c4]) = pk;
    }
    __syncthreads();

    const int l  = tid & 63;
    const int w  = tid >> 6;            // 8 waves
    const int lr = l & 15, lk = l >> 4;

    {   // phase 2: x_new = x_old + agg @ Wo (MFMA); wave w -> N-tile w
        float4v acc = (float4v){0.f, 0.f, 0.f, 0.f};
        #pragma unroll
        for (int ks = 0; ks < 4; ++ks) {
            short8v af = *reinterpret_cast<const short8v*>(&a_s[lr][lk * 8 + ks * 32]);
            short8v bf = *reinterpret_cast<const short8v*>(&Woxl[((size_t)(w * 4 + ks) * 64 + l) * 8]);
            acc = __builtin_amdgcn_mfma_f32_16x16x32_bf16(af, bf, acc, 0, 0, 0);
        }
        #pragma unroll
        for (int r = 0; r < 4; ++r)
            xf_s[lk * 4 + r][w * 16 + lr] += acc[r];
    }
    __syncthreads();

    {   // phase 3: rms(x_new) -> a_s
        float4 v = *reinterpret_cast<const float4*>(&xf_s[ni][c4]);
        float ss = v.x * v.x + v.y * v.y + v.z * v.z + v.w * v.w;
        #pragma unroll
        for (int m = 1; m < 32; m <<= 1) ss += __shfl_xor(ss, m, 32);
        float r = rsqrtf(ss * (1.0f / 1152.0f) + 1e-6f);
        uint2 pk;
        pk.x = pack2bf(v.x * r, v.y * r);
        pk.y = pack2bf(v.z * r, v.w * r);
        *reinterpret_cast<uint2*>(&a_s[ni][c4]) = pk;
    }
    __syncthreads();

    {   // phase 4: FFN GEMM1 -> h_s; wave w -> N-tiles w*4..w*4+3
        float4v acc[4];
        #pragma unroll
        for (int nf = 0; nf < 4; ++nf) acc[nf] = (float4v){0.f, 0.f, 0.f, 0.f};
        #pragma unroll
        for (int ks = 0; ks < 4; ++ks) {
            short8v af = *reinterpret_cast<const short8v*>(&a_s[lr][lk * 8 + ks * 32]);
            #pragma unroll
            for (int nf = 0; nf < 4; ++nf) {
                int nt = w * 4 + nf;
                short8v bf = *reinterpret_cast<const short8v*>(&Wf1xl[((size_t)(nt * 4 + ks) * 64 + l) * 8]);
                acc[nf] = __builtin_amdgcn_mfma_f32_16x16x32_bf16(af, bf, acc[nf], 0, 0, 0);
            }
        }
        #pragma unroll
        for (int nf = 0; nf < 4; ++nf) {
            #pragma unroll
            for (int r = 0; r < 4; ++r) {
                float v = siluf(acc[nf][r]);
                float vn = __shfl_xor(v, 1, 64);
                if ((l & 1) == 0) {
                    int row = lk * 4 + r;
                    int col = (w * 4 + nf) * 16 + lr;
                    *reinterpret_cast<uint*>(&h_s[row][col]) = pack2bf(v, vn);
                }
            }
        }
    }
    __syncthreads();

    {   // phase 5: FFN GEMM2 -> delta into xf_s; wave w -> N-tile w
        float4v acc = (float4v){0.f, 0.f, 0.f, 0.f};
        #pragma unroll 4
        for (int ks = 0; ks < 16; ++ks) {
            short8v af = *reinterpret_cast<const short8v*>(&h_s[lr][lk * 8 + ks * 32]);
            short8v bf = *reinterpret_cast<const short8v*>(&Wf2xl[((size_t)(w * 16 + ks) * 64 + l) * 8]);
            acc = __builtin_amdgcn_mfma_f32_16x16x32_bf16(af, bf, acc, 0, 0, 0);
        }
        #pragma unroll
        for (int r = 0; r < 4; ++r)
            xf_s[lk * 4 + r][w * 16 + lr] += acc[r];
    }
    __syncthreads();

    {   // phase 6: final rms -> x + a_s + gemm3, or out
        float4 v = *reinterpret_cast<const float4*>(&xf_s[ni][c4]);
        float ss = v.x * v.x + v.y * v.y + v.z * v.z + v.w * v.w;
        #pragma unroll
        for (int m = 1; m < 32; m <<= 1) ss += __shfl_xor(ss, m, 32);
        float r = rsqrtf(ss * (1.0f / 1152.0f) + 1e-6f);

        if (!LAST) {
            *reinterpret_cast<float4*>(&x[(size_t)(n0 + ni) * 128 + c4]) = v;
            uint2 pk;
            pk.x = pack2bf(v.x * r, v.y * r);
            pk.y = pack2bf(v.z * r, v.w * r);
            *reinterpret_cast<uint2*>(&a_s[ni][c4]) = pk;
            __syncthreads();
            node_gemm3_8w(a_s, tid, n0, WvxN, Wa1sxN, Wa1dxN, VbO, Psb, Pdb);
        } else {
            size_t base = (size_t)(n0 + ni) * 1152 + c4;
            *reinterpret_cast<float4*>(&out[base]) = make_float4(v.x * r, v.y * r, v.z * r, v.w * r);
            const float4 z4 = make_float4(0.f, 0.f, 0.f, 0.f);
            #pragma unroll
            for (int k = 1; k < 9; ++k)
                *reinterpret_cast<float4*>(&out[base + (size_t)k * 128]) = z4;
        }
    }
}

extern "C" void kernel_launch(void* const* d_in, const int* in_sizes, int n_in,
                              void* d_out, int out_size, void* d_ws, size_t ws_size,
                              hipStream_t stream)
{
    const int*   atom_feats = (const int*)d_in[0];
    const int*   bond_feats = (const int*)d_in[1];
    const int*   edge_index = (const int*)d_in[2];
    const float* edge_dist  = (const float*)d_in[3];
    const float* atom_emb   = (const float*)d_in[4];
    const float* bond_emb   = (const float*)d_in[5];
    const float* W_rbf1     = (const float*)d_in[6];
    const float* b_rbf1     = (const float*)d_in[7];
    const float* W_rbf2     = (const float*)d_in[8];
    const float* b_rbf2     = (const float*)d_in[9];
    const float* Wa1        = (const float*)d_in[10];
    const float* Wa2        = (const float*)d_in[11];
    const float* Wv         = (const float*)d_in[12];
    const float* Wg         = (const float*)d_in[13];
    const float* Wo         = (const float*)d_in[14];
    const float* Wf1        = (const float*)d_in[15];
    const float* Wf2        = (const float*)d_in[16];
    float* out = (float*)d_out;

    float* ws   = (float*)d_ws;
    float* x    = ws;                           // NN*128
    float2* nex = (float2*)(x + NN * 128);      // NE*8 float2
    float* W2A  = (float*)(nex + (size_t)NE * 8);
    float* W2G  = W2A  + 2 * 16384;
    float* bA   = W2G  + 2 * 1024;
    float* bG   = bA   + 2 * 128;
    float* TG   = bG   + 16;
    float* BGc  = TG   + 2 * (size_t)TROWS * 8;
    uint* Vb    = (uint*)(BGc + 2 * 512 * 8);   // NN*64
    uint* Psb   = Vb  + NN * 64;
    uint* Pdb   = Psb + NN * 64;
    uint* TAb   = Pdb + NN * 64;                // 2*TROWS*64
    uint* BAcb  = TAb + 2 * (size_t)TROWS * 64; // 2*512*64
    ushort* Wf1x  = (ushort*)(BAcb + 2 * 512 * 64);
    ushort* Wf2x  = Wf1x  + 2 * 65536;
    ushort* Wvx   = Wf2x  + 2 * 65536;
    ushort* Wa1sx = Wvx   + 2 * 16384;
    ushort* Wa1dx = Wa1sx + 2 * 16384;
    ushort* Wa2x  = Wa1dx + 2 * 16384;
    ushort* Wox   = Wa2x  + 2 * 2048;
    int* deg    = (int*)(Wox + 2 * 16384);
    int* off    = deg + NN;
    int* cursor = off + NN + 1;
    int* srcp   = cursor + NN;                  // NE
    int4* erec  = (int4*)(srcp + NE);           // NE int4 (16B aligned: offset even)

    k_prep<<<dim3(371, 2), 256, 0, stream>>>(W_rbf2, b_rbf2, Wa1, Wg, bond_emb,
        Wf1, Wf2, Wv, Wa2, Wo, W2A, W2G, bA, bG, BAcb, BGc,
        Wf1x, Wf2x, Wvx, Wa1sx, Wa1dx, Wa2x, Wox);
    k_prep2<<<514 + NN / 16, 256, 0, stream>>>(W_rbf1, b_rbf1, W2A, W2G, bA, bG, TAb, TG,
        atom_feats, atom_emb, x, deg, Wvx, Wa1sx, Wa1dx, Vb, Psb, Pdb);

    k_hist<<<(NE + 255) / 256, 256, 0, stream>>>(edge_index, deg);
    k_scan<<<1, 1024, 0, stream>>>(deg, off, cursor);
    k_fill<<<(NE + 255) / 256, 256, 0, stream>>>(edge_index, bond_feats, edge_dist,
                                                 cursor, srcp, erec);

    for (int l = 0; l < 2; ++l) {
        k_attn<<<(NE + 31) / 32, 256, 0, stream>>>(erec,
            Psb, Pdb,
            TAb + (size_t)l * TROWS * 64, TG + (size_t)l * TROWS * 8,
            BAcb + (size_t)l * 512 * 64, BGc + (size_t)l * 512 * 8,
            Wa2x + (size_t)l * 2048, nex);
        if (l == 0)
            k_layer_fused<0><<<NN / 16, 512, 0, stream>>>(x, off, srcp, nex, Vb,
                Wox, Wf1x, Wf2x, out,
                Wvx + 16384, Wa1sx + 16384, Wa1dx + 16384, Vb, Psb, Pdb);
        else
            k_layer_fused<1><<<NN / 16, 512, 0, stream>>>(x, off, srcp, nex, Vb,
                Wox + 16384, Wf1x + 65536, Wf2x + 65536, out,
                Wvx, Wa1sx, Wa1dx, Vb, Psb, Pdb);
    }
}

// Round 13
// 149.285 us; speedup vs baseline: 2.1610x; 1.0411x over previous
//
#include <hip/hip_runtime.h>

#define NN 6000
#define NE 150000
#define TBM 2048
#define TROWS (TBM + 1)

typedef unsigned int uint;
typedef unsigned short ushort;
typedef __attribute__((ext_vector_type(8))) short short8v;
typedef __attribute__((ext_vector_type(4))) float float4v;

__device__ __forceinline__ float siluf(float x) { return x / (1.f + __expf(-x)); }
__device__ __forceinline__ float sigmf(float x) { return 1.f / (1.f + __expf(-x)); }
__device__ __forceinline__ uint pack2bf(float lo, float hi) {
    uint ul = __float_as_uint(lo);
    ul = (ul + 0x7fffu + ((ul >> 16) & 1u)) >> 16;
    uint uh = __float_as_uint(hi);
    uh = ((uh + 0x7fffu + ((uh >> 16) & 1u)) >> 16) << 16;
    return ul | uh;
}
__device__ __forceinline__ ushort f2bf(float f) {
    uint u = __float_as_uint(f);
    return (ushort)((u + 0x7fffu + ((u >> 16) & 1u)) >> 16);
}
__device__ __forceinline__ float2 up2(uint u) {
    return make_float2(__uint_as_float(u << 16), __uint_as_float(u & 0xffff0000u));
}

// ================ k_prep: w2a | bondtabs | packw (+Wa2x, Wox) | deg-zero ================
__global__ __launch_bounds__(256)
void k_prep(const float* __restrict__ W2, const float* __restrict__ b2,
            const float* __restrict__ Wa1, const float* __restrict__ Wg,
            const float* __restrict__ bemb,
            const float* __restrict__ Wf1, const float* __restrict__ Wf2,
            const float* __restrict__ Wv, const float* __restrict__ Wa2,
            const float* __restrict__ Wo,
            float* __restrict__ W2A, float* __restrict__ W2G,
            float* __restrict__ bA, float* __restrict__ bG,
            uint* __restrict__ BAcb, float* __restrict__ BGc,
            ushort* __restrict__ Wf1x, ushort* __restrict__ Wf2x,
            ushort* __restrict__ Wvx, ushort* __restrict__ Wa1sx,
            ushort* __restrict__ Wa1dx, ushort* __restrict__ Wa2x,
            ushort* __restrict__ Wox, int* __restrict__ deg)
{
    __shared__ float w2_s[8][132];
    const int l = blockIdx.y, bx = blockIdx.x, tid = threadIdx.x;
    const float* Wa1e = Wa1 + (size_t)l * 384 * 128 + 256 * 128;
    const float* Wgl  = Wg  + (size_t)l * 128 * 8;

    if (bx < 16) {
        const int i0 = bx * 8;
        for (int q = tid; q < 8 * 32; q += 256) {
            int ni = q >> 5, j4 = (q & 31) * 4;
            *reinterpret_cast<float4*>(&w2_s[ni][j4]) =
                *reinterpret_cast<const float4*>(&W2[(size_t)(i0 + ni) * 128 + j4]);
        }
        __syncthreads();
        const int j = tid & 127, ng = tid >> 7;
        float a[4] = {0.f, 0.f, 0.f, 0.f};
        #pragma unroll 4
        for (int k4 = 0; k4 < 128; k4 += 4) {
            float w0 = Wa1e[(k4 + 0) * 128 + j];
            float w1 = Wa1e[(k4 + 1) * 128 + j];
            float w2v = Wa1e[(k4 + 2) * 128 + j];
            float w3 = Wa1e[(k4 + 3) * 128 + j];
            #pragma unroll
            for (int r = 0; r < 4; ++r) {
                const float4 xv = *reinterpret_cast<const float4*>(&w2_s[ng * 4 + r][k4]);
                a[r] += xv.x * w0 + xv.y * w1 + xv.z * w2v + xv.w * w3;
            }
        }
        #pragma unroll
        for (int r = 0; r < 4; ++r)
            W2A[(size_t)l * 16384 + (size_t)(i0 + ng * 4 + r) * 128 + j] = a[r];
    } else if (bx == 16) {
        const int i = tid & 127, hq = tid >> 7;
        float a[4] = {0.f, 0.f, 0.f, 0.f};
        for (int k = 0; k < 128; ++k) {
            float w = W2[(size_t)i * 128 + k];
            const float4 g4 = *reinterpret_cast<const float4*>(&Wgl[k * 8 + hq * 4]);
            a[0] += w * g4.x; a[1] += w * g4.y; a[2] += w * g4.z; a[3] += w * g4.w;
        }
        #pragma unroll
        for (int q = 0; q < 4; ++q)
            W2G[(size_t)l * 1024 + (size_t)i * 8 + hq * 4 + q] = a[q];
    } else if (bx == 17) {
        if (tid < 128) {
            float s = 0.f;
            for (int k = 0; k < 128; ++k) s += b2[k] * Wa1e[k * 128 + tid];
            bA[l * 128 + tid] = s;
        } else if (tid < 136) {
            int h = tid - 128;
            float s = 0.f;
            for (int k = 0; k < 128; ++k) s += b2[k] * Wgl[k * 8 + h];
            bG[l * 8 + h] = s;
        } else if (l == 0) {
            // deg zeroing (runs before k_prep2's histogram blocks — inter-kernel ordering)
            for (int i = tid - 136; i < NN; i += 120) if (i >= 0) deg[i] = 0;
        }
    } else if (bx < 274) {
        const int cb = (bx - 18) * 2 + (tid >> 7);
        const int c = tid & 127;
        const int b[3] = {cb >> 6, (cb >> 3) & 7, cb & 7};
        float s = 0.f;
        #pragma unroll
        for (int f = 0; f < 3; ++f) {
            const float* er = &bemb[(size_t)(f * 8 + b[f]) * 128];
            for (int k = 0; k < 128; ++k)
                s += er[k] * Wa1e[k * 128 + c];
        }
        float hi = __shfl_down(s, 1, 64);
        if ((c & 1) == 0)
            BAcb[(size_t)l * 512 * 64 + (size_t)cb * 64 + (c >> 1)] = pack2bf(s, hi);
        if (c < 8) {
            float g = 0.f;
            #pragma unroll
            for (int f = 0; f < 3; ++f) {
                const float* er = &bemb[(size_t)(f * 8 + b[f]) * 128];
                for (int k = 0; k < 128; ++k)
                    g += er[k] * Wgl[k * 8 + c];
            }
            BGc[(size_t)l * 512 * 8 + (size_t)cb * 8 + c] = g;
        }
    } else {
        const int sub = (bx - 274) * 4 + (tid >> 6);
        const int lane = tid & 63;
        if (sub < 128) {
            const int nt = sub >> 2, kt = sub & 3;
            const float* src = Wf1 + (size_t)l * 65536;
            ushort* dst = Wf1x + (size_t)l * 65536 + ((size_t)sub * 64 + lane) * 8;
            #pragma unroll
            for (int j = 0; j < 8; ++j)
                dst[j] = f2bf(src[(size_t)(kt * 32 + (lane >> 4) * 8 + j) * 512 + nt * 16 + (lane & 15)]);
        } else if (sub < 256) {
            const int b2x = sub - 128;
            const int nt = b2x >> 4, kt = b2x & 15;
            const float* src = Wf2 + (size_t)l * 65536;
            ushort* dst = Wf2x + (size_t)l * 65536 + ((size_t)b2x * 64 + lane) * 8;
            #pragma unroll
            for (int j = 0; j < 8; ++j)
                dst[j] = f2bf(src[(size_t)(kt * 32 + (lane >> 4) * 8 + j) * 128 + nt * 16 + (lane & 15)]);
        } else if (sub < 352) {
            const int b3 = sub - 256;
            const int mat = b3 >> 5, blk = b3 & 31;
            const int nt = blk >> 2, kt = blk & 3;
            const float* src;
            ushort* dst;
            if (mat == 0)      { src = Wv  + (size_t)l * 16384;             dst = Wvx   + (size_t)l * 16384; }
            else if (mat == 1) { src = Wa1 + (size_t)l * 384 * 128;         dst = Wa1sx + (size_t)l * 16384; }
            else               { src = Wa1 + (size_t)l * 384 * 128 + 16384; dst = Wa1dx + (size_t)l * 16384; }
            dst += ((size_t)blk * 64 + lane) * 8;
            #pragma unroll
            for (int j = 0; j < 8; ++j)
                dst[j] = f2bf(src[(size_t)(kt * 32 + (lane >> 4) * 8 + j) * 128 + nt * 16 + (lane & 15)]);
        } else if (sub < 356) {
            const int kt = sub - 352;
            const int col = lane & 15;
            const float* src = Wa2 + (size_t)l * 128 * 8;
            ushort* dst = Wa2x + (size_t)l * 2048 + ((size_t)kt * 64 + lane) * 8;
            #pragma unroll
            for (int j = 0; j < 8; ++j) {
                int krow = kt * 32 + (lane >> 4) * 8 + j;
                dst[j] = (col < 8) ? f2bf(src[(size_t)krow * 8 + col]) : (ushort)0;
            }
        } else {
            const int blk = sub - 356;
            const int nt = blk >> 2, kt = blk & 3;
            const float* src = Wo + (size_t)l * 16384;
            ushort* dst = Wox + (size_t)l * 16384 + ((size_t)blk * 64 + lane) * 8;
            #pragma unroll
            for (int j = 0; j < 8; ++j)
                dst[j] = f2bf(src[(size_t)(kt * 32 + (lane >> 4) * 8 + j) * 128 + nt * 16 + (lane & 15)]);
        }
    }
}

// ---------------- node GEMMs helper: 4-wave (256-thread) version ----------------
__device__ __forceinline__
void node_gemm3(const ushort a_s[16][136], int tid, int n0,
                const ushort* __restrict__ Wvx, const ushort* __restrict__ Wa1sx,
                const ushort* __restrict__ Wa1dx,
                uint* __restrict__ Vb, uint* __restrict__ Psb, uint* __restrict__ Pdb)
{
    const int l = tid & 63, wq = tid >> 6;
    const int lr = l & 15, lk = l >> 4;
    #pragma unroll
    for (int jb = 0; jb < 6; ++jb) {
        int job = wq * 6 + jb;
        int mat = job >> 3, nt = job & 7;
        const ushort* W = (mat == 0) ? Wvx : (mat == 1 ? Wa1sx : Wa1dx);
        uint* O = (mat == 0) ? Vb : (mat == 1 ? Psb : Pdb);
        float4v acc = (float4v){0.f, 0.f, 0.f, 0.f};
        #pragma unroll
        for (int ks = 0; ks < 4; ++ks) {
            short8v af = *reinterpret_cast<const short8v*>(&a_s[lr][lk * 8 + ks * 32]);
            short8v bf = *reinterpret_cast<const short8v*>(&W[((size_t)(nt * 4 + ks) * 64 + l) * 8]);
            acc = __builtin_amdgcn_mfma_f32_16x16x32_bf16(af, bf, acc, 0, 0, 0);
        }
        #pragma unroll
        for (int r = 0; r < 4; ++r) {
            float v = acc[r];
            float vn = __shfl_xor(v, 1, 64);
            if ((l & 1) == 0) {
                int row = lk * 4 + r, col = nt * 16 + lr;
                O[(size_t)(n0 + row) * 64 + (col >> 1)] = pack2bf(v, vn);
            }
        }
    }
}

// ---------------- node GEMMs helper: 8-wave (512-thread) version ----------------
__device__ __forceinline__
void node_gemm3_8w(const ushort a_s[16][136], int tid, int n0,
                   const ushort* __restrict__ Wvx, const ushort* __restrict__ Wa1sx,
                   const ushort* __restrict__ Wa1dx,
                   uint* __restrict__ Vb, uint* __restrict__ Psb, uint* __restrict__ Pdb)
{
    const int l = tid & 63, w = tid >> 6;
    const int lr = l & 15, lk = l >> 4;
    #pragma unroll
    for (int jb = 0; jb < 3; ++jb) {
        int job = w * 3 + jb;
        int mat = job >> 3, nt = job & 7;
        const ushort* W = (mat == 0) ? Wvx : (mat == 1 ? Wa1sx : Wa1dx);
        uint* O = (mat == 0) ? Vb : (mat == 1 ? Psb : Pdb);
        float4v acc = (float4v){0.f, 0.f, 0.f, 0.f};
        #pragma unroll
        for (int ks = 0; ks < 4; ++ks) {
            short8v af = *reinterpret_cast<const short8v*>(&a_s[lr][lk * 8 + ks * 32]);
            short8v bf = *reinterpret_cast<const short8v*>(&W[((size_t)(nt * 4 + ks) * 64 + l) * 8]);
            acc = __builtin_amdgcn_mfma_f32_16x16x32_bf16(af, bf, acc, 0, 0, 0);
        }
        #pragma unroll
        for (int r = 0; r < 4; ++r) {
            float v = acc[r];
            float vn = __shfl_xor(v, 1, 64);
            if ((l & 1) == 0) {
                int row = lk * 4 + r, col = nt * 16 + lr;
                O[(size_t)(n0 + row) * 64 + (col >> 1)] = pack2bf(v, vn);
            }
        }
    }
}

// ================ k_prep2: t1ta (bx<514) | embed+gemm (514..889) | hist (>=889) ================
__global__ __launch_bounds__(256)
void k_prep2(const float* __restrict__ W1, const float* __restrict__ b1,
             const float* __restrict__ W2A, const float* __restrict__ W2G,
             const float* __restrict__ bA, const float* __restrict__ bG,
             uint* __restrict__ TAb, float* __restrict__ TG,
             const int* __restrict__ af, const float* __restrict__ aemb,
             float* __restrict__ x, int* __restrict__ deg,
             const int* __restrict__ eidx,
             const ushort* __restrict__ Wvx, const ushort* __restrict__ Wa1sx,
             const ushort* __restrict__ Wa1dx,
             uint* __restrict__ Vb, uint* __restrict__ Psb, uint* __restrict__ Pdb)
{
    __shared__ float rbf_s[8][32];
    __shared__ int   bs_s[8];
    __shared__ float t1_s[8][132];
    __shared__ ushort a_s[16][136];
    const int tid = threadIdx.x, bx = blockIdx.x;

    if (bx < 514) {
        const int l = (bx >= 257) ? 1 : 0;
        const int r0 = (bx - l * 257) * 8;
        {
            int ri = tid >> 5, j = tid & 31;
            int row = min(r0 + ri, TBM);
            float d = (float)row * (5.0f / TBM);
            const float step = 5.0f / 511.0f;
            const float invw = 512.0f / 5.0f;
            int b0 = (int)(d * (511.0f / 5.0f) + 0.5f);
            int bs = min(max(b0 - 16, 0), 512 - 32);
            if (j == 0) bs_s[ri] = bs;
            float z = (d - (float)(bs + j) * step) * invw;
            rbf_s[ri][j] = __expf(-z * z);
        }
        __syncthreads();
        #pragma unroll
        for (int pass = 0; pass < 4; ++pass) {
            int idx = pass * 256 + tid;
            int ri = idx >> 7, c = idx & 127;
            int bs = bs_s[ri];
            float t = b1[c];
            #pragma unroll
            for (int j = 0; j < 32; ++j)
                t += rbf_s[ri][j] * W1[(bs + j) * 128 + c];
            t1_s[ri][c] = siluf(t);
        }
        __syncthreads();

        const float* W2Al = W2A + (size_t)l * 16384;
        const int c = tid & 127, ng = tid >> 7;
        float a[4];
        #pragma unroll
        for (int r = 0; r < 4; ++r) a[r] = bA[l * 128 + c];
        #pragma unroll 4
        for (int k4 = 0; k4 < 128; k4 += 4) {
            float w0 = W2Al[(k4 + 0) * 128 + c];
            float w1 = W2Al[(k4 + 1) * 128 + c];
            float w2v = W2Al[(k4 + 2) * 128 + c];
            float w3 = W2Al[(k4 + 3) * 128 + c];
            #pragma unroll
            for (int r = 0; r < 4; ++r) {
                const float4 xv = *reinterpret_cast<const float4*>(&t1_s[ng * 4 + r][k4]);
                a[r] += xv.x * w0 + xv.y * w1 + xv.z * w2v + xv.w * w3;
            }
        }
        #pragma unroll
        for (int r = 0; r < 4; ++r) {
            float hi = __shfl_down(a[r], 1, 64);
            int row = r0 + ng * 4 + r;
            if (((c & 1) == 0) && row <= TBM)
                TAb[(size_t)l * TROWS * 64 + (size_t)row * 64 + (c >> 1)] = pack2bf(a[r], hi);
        }
        if (tid < 64) {
            int ri = tid >> 3, h = tid & 7;
            int row = r0 + ri;
            if (row <= TBM) {
                const float* W2Gl = W2G + (size_t)l * 1024;
                float s = bG[l * 8 + h];
                #pragma unroll 8
                for (int k = 0; k < 128; ++k)
                    s += t1_s[ri][k] * W2Gl[k * 8 + h];
                TG[(size_t)l * TROWS * 8 + (size_t)row * 8 + h] = s;
            }
        }
    } else if (bx < 889) {
        const int n0 = (bx - 514) * 16;
        {
            int ni = tid >> 4, c8 = (tid & 15) * 8;
            int n = n0 + ni;
            float v[8];
            #pragma unroll
            for (int q = 0; q < 8; ++q) v[q] = 0.f;
            #pragma unroll
            for (int f = 0; f < 4; ++f) {
                int idx = af[n * 4 + f];
                const float* er = &aemb[(size_t)(f * 10 + idx) * 128 + c8];
                float4 e0 = *reinterpret_cast<const float4*>(er);
                float4 e1 = *reinterpret_cast<const float4*>(er + 4);
                v[0] += e0.x; v[1] += e0.y; v[2] += e0.z; v[3] += e0.w;
                v[4] += e1.x; v[5] += e1.y; v[6] += e1.z; v[7] += e1.w;
            }
            float* xr = &x[(size_t)n * 128 + c8];
            *reinterpret_cast<float4*>(xr)     = make_float4(v[0], v[1], v[2], v[3]);
            *reinterpret_cast<float4*>(xr + 4) = make_float4(v[4], v[5], v[6], v[7]);
            float ss = 0.f;
            #pragma unroll
            for (int q = 0; q < 8; ++q) ss += v[q] * v[q];
            #pragma unroll
            for (int m = 1; m < 16; m <<= 1) ss += __shfl_xor(ss, m, 16);
            float r = rsqrtf(ss * (1.0f / 1152.0f) + 1e-6f);
            uint4 pk;
            pk.x = pack2bf(v[0] * r, v[1] * r);
            pk.y = pack2bf(v[2] * r, v[3] * r);
            pk.z = pack2bf(v[4] * r, v[5] * r);
            pk.w = pack2bf(v[6] * r, v[7] * r);
            *reinterpret_cast<uint4*>(&a_s[ni][c8]) = pk;
        }
        __syncthreads();
        node_gemm3(a_s, tid, n0, Wvx, Wa1sx, Wa1dx, Vb, Psb, Pdb);
    } else {
        int e = (bx - 889) * 256 + tid;
        if (e < NE) atomicAdd(&deg[eidx[NE + e]], 1);
    }
}

// ---------------- CSR scan + fill ----------------
__global__ __launch_bounds__(1024)
void k_scan(const int* __restrict__ deg, int* __restrict__ off, int* __restrict__ cursor)
{
    __shared__ int part[1024];
    const int t = threadIdx.x;
    const int base = t * 6;
    int loc[6]; int s = 0;
    #pragma unroll
    for (int i = 0; i < 6; ++i) {
        int d = (base + i < NN) ? deg[base + i] : 0;
        loc[i] = s; s += d;
    }
    part[t] = s;
    __syncthreads();
    for (int o = 1; o < 1024; o <<= 1) {
        int v = (t >= o) ? part[t - o] : 0;
        __syncthreads();
        part[t] += v;
        __syncthreads();
    }
    int pre = (t > 0) ? part[t - 1] : 0;
    #pragma unroll
    for (int i = 0; i < 6; ++i) {
        if (base + i < NN) {
            int v = pre + loc[i];
            off[base + i] = v;
            cursor[base + i] = v;
        }
    }
    if (t == 1023) off[NN] = part[1023];
}

__global__ __launch_bounds__(256)
void k_fill(const int* __restrict__ eidx, const int* __restrict__ bondf,
            const float* __restrict__ dist, int* __restrict__ cursor,
            int* __restrict__ srcp, int4* __restrict__ erec)
{
    int e = blockIdx.x * 256 + threadIdx.x;
    if (e < NE) {
        int d = eidx[NE + e];
        int p = atomicAdd(&cursor[d], 1);
        int sn = eidx[e];
        srcp[p] = sn;
        erec[p] = make_int4(sn, d, __float_as_int(dist[e]),
                            bondf[e * 3 + 0] * 64 + bondf[e * 3 + 1] * 8 + bondf[e * 3 + 2]);
    }
}

// ---------------- attention: 64 edges/block; LDS phase A (bf16 t) + MFMA phase B ----------------
__global__ __launch_bounds__(256)
void k_attn(const int4* __restrict__ erec,
            const uint* __restrict__ Psb, const uint* __restrict__ Pdb,
            const uint* __restrict__ TAbl, const float* __restrict__ TGl,
            const uint* __restrict__ BAcbl, const float* __restrict__ BGcl,
            const ushort* __restrict__ Wa2xl,
            uint* __restrict__ nexp)
{
    __shared__ ushort t_s[64][136];
    __shared__ float gate_s[64][8];
    const int tid = threadIdx.x;
    const int p0 = blockIdx.x * 64;

    #pragma unroll
    for (int half = 0; half < 2; ++half) {
        const int ei = (tid >> 3) + half * 32;
        const int g = tid & 7;
        const int p = min(p0 + ei, NE - 1);
        const int4 er = erec[p];
        const int sn = er.x, dn = er.y;
        const float d = __int_as_float(er.z);
        const int cb = er.w;
        float u = d * ((float)TBM / 5.0f);
        int i = min((int)u, TBM - 1);
        float f = u - (float)i, f1 = 1.f - f;

        uint ps[8], pd[8], t0[8], t1v[8], ba[8];
        {
            const uint4* pp = reinterpret_cast<const uint4*>(&Psb[(size_t)sn * 64 + g * 8]);
            uint4 a = pp[0], b = pp[1];
            ps[0]=a.x; ps[1]=a.y; ps[2]=a.z; ps[3]=a.w; ps[4]=b.x; ps[5]=b.y; ps[6]=b.z; ps[7]=b.w;
            pp = reinterpret_cast<const uint4*>(&Pdb[(size_t)dn * 64 + g * 8]);
            a = pp[0]; b = pp[1];
            pd[0]=a.x; pd[1]=a.y; pd[2]=a.z; pd[3]=a.w; pd[4]=b.x; pd[5]=b.y; pd[6]=b.z; pd[7]=b.w;
            pp = reinterpret_cast<const uint4*>(&TAbl[(size_t)i * 64 + g * 8]);
            a = pp[0]; b = pp[1];
            t0[0]=a.x; t0[1]=a.y; t0[2]=a.z; t0[3]=a.w; t0[4]=b.x; t0[5]=b.y; t0[6]=b.z; t0[7]=b.w;
            pp = reinterpret_cast<const uint4*>(&TAbl[(size_t)(i + 1) * 64 + g * 8]);
            a = pp[0]; b = pp[1];
            t1v[0]=a.x; t1v[1]=a.y; t1v[2]=a.z; t1v[3]=a.w; t1v[4]=b.x; t1v[5]=b.y; t1v[6]=b.z; t1v[7]=b.w;
            pp = reinterpret_cast<const uint4*>(&BAcbl[(size_t)cb * 64 + g * 8]);
            a = pp[0]; b = pp[1];
            ba[0]=a.x; ba[1]=a.y; ba[2]=a.z; ba[3]=a.w; ba[4]=b.x; ba[5]=b.y; ba[6]=b.z; ba[7]=b.w;
        }
        uint tw[8];
        #pragma unroll
        for (int q = 0; q < 8; ++q) {
            float2 vs = up2(ps[q]), vd = up2(pd[q]), v0 = up2(t0[q]), v1 = up2(t1v[q]), vb = up2(ba[q]);
            float s0 = siluf(vs.x + vd.x + f1 * v0.x + f * v1.x + vb.x);
            float s1 = siluf(vs.y + vd.y + f1 * v0.y + f * v1.y + vb.y);
            tw[q] = pack2bf(s0, s1);
        }
        uint4* tp = reinterpret_cast<uint4*>(&t_s[ei][g * 16]);
        tp[0] = make_uint4(tw[0], tw[1], tw[2], tw[3]);
        tp[1] = make_uint4(tw[4], tw[5], tw[6], tw[7]);
        if (g == 0) {
            const float4* tg0 = reinterpret_cast<const float4*>(&TGl[(size_t)i * 8]);
            const float4* bg4 = reinterpret_cast<const float4*>(&BGcl[(size_t)cb * 8]);
            #pragma unroll
            for (int q = 0; q < 2; ++q) {
                float4 g0 = tg0[q], g1 = tg0[q + 2], bb = bg4[q];
                gate_s[ei][4 * q + 0] = f1 * g0.x + f * g1.x + bb.x;
                gate_s[ei][4 * q + 1] = f1 * g0.y + f * g1.y + bb.y;
                gate_s[ei][4 * q + 2] = f1 * g0.z + f * g1.z + bb.z;
                gate_s[ei][4 * q + 3] = f1 * g0.w + f * g1.w + bb.w;
            }
        }
    }
    __syncthreads();

    {   // phase B: logits via MFMA; all 4 waves, 16 edges each
        const int wq = tid >> 6, l = tid & 63;
        const int lr = l & 15, lk = l >> 4;
        float4v acc = (float4v){0.f, 0.f, 0.f, 0.f};
        #pragma unroll
        for (int ks = 0; ks < 4; ++ks) {
            short8v af = *reinterpret_cast<const short8v*>(&t_s[wq * 16 + lr][lk * 8 + ks * 32]);
            short8v bf = *reinterpret_cast<const short8v*>(&Wa2xl[((size_t)ks * 64 + l) * 8]);
            acc = __builtin_amdgcn_mfma_f32_16x16x32_bf16(af, bf, acc, 0, 0, 0);
        }
        const int h = l & 15;
        if (h < 8) {
            #pragma unroll
            for (int r = 0; r < 4; ++r) {
                int ei = wq * 16 + lk * 4 + r;
                int p = p0 + ei;
                if (p < NE) {
                    float ex = __expf(acc[r]);
                    nexp[(size_t)p * 8 + h] = pack2bf(ex * sigmf(gate_s[ei][h]), ex);
                }
            }
        }
    }
}

// ======== k_layer_fused (512 thr): gather + agg@Wo + rms + FFN (+ next gemm3 / finalize) ========
template<int LAST>
__global__ __launch_bounds__(512)
void k_layer_fused(float* __restrict__ x,
                   const int* __restrict__ off, const int* __restrict__ srcp,
                   const uint* __restrict__ nexp, const uint* __restrict__ Vb,
                   const ushort* __restrict__ Woxl,
                   const ushort* __restrict__ Wf1xl, const ushort* __restrict__ Wf2xl,
                   float* __restrict__ out,
                   const ushort* __restrict__ WvxN, const ushort* __restrict__ Wa1sxN,
                   const ushort* __restrict__ Wa1dxN,
                   uint* __restrict__ VbO, uint* __restrict__ Psb, uint* __restrict__ Pdb)
{
    __shared__ ushort a_s[16][136];
    __shared__ ushort h_s[16][520];
    __shared__ float xf_s[16][132];
    const int tid = threadIdx.x;
    const int n0 = blockIdx.x * 16;
    const int ni = tid >> 5;
    const int ci = tid & 31;
    const int c4 = ci * 4;

    {   // phase 0: stash x_old
        *reinterpret_cast<float4*>(&xf_s[ni][c4]) =
            *reinterpret_cast<const float4*>(&x[(size_t)(n0 + ni) * 128 + c4]);
    }

    {   // phase 1: segment gather; 32 threads/node, 4 channels each
        const int n = n0 + ni;
        const int h = ci >> 2;
        const int cd2 = ci * 2;
        const int s = off[n], t = off[n + 1];
        float a0 = 0.f, a1 = 0.f, a2 = 0.f, a3 = 0.f, es = 0.f;
        int p = s;
        for (; p + 4 <= t; p += 4) {
            int sn0 = srcp[p + 0], sn1 = srcp[p + 1], sn2 = srcp[p + 2], sn3 = srcp[p + 3];
            float2 ne0 = up2(nexp[(size_t)(p + 0) * 8 + h]);
            float2 ne1 = up2(nexp[(size_t)(p + 1) * 8 + h]);
            float2 ne2 = up2(nexp[(size_t)(p + 2) * 8 + h]);
            float2 ne3 = up2(nexp[(size_t)(p + 3) * 8 + h]);
            uint2 u0 = *reinterpret_cast<const uint2*>(&Vb[(size_t)sn0 * 64 + cd2]);
            uint2 u1 = *reinterpret_cast<const uint2*>(&Vb[(size_t)sn1 * 64 + cd2]);
            uint2 u2 = *reinterpret_cast<const uint2*>(&Vb[(size_t)sn2 * 64 + cd2]);
            uint2 u3 = *reinterpret_cast<const uint2*>(&Vb[(size_t)sn3 * 64 + cd2]);
            es += ne0.y + ne1.y + ne2.y + ne3.y;
            float2 v;
            v = up2(u0.x); a0 += ne0.x * v.x; a1 += ne0.x * v.y;
            v = up2(u0.y); a2 += ne0.x * v.x; a3 += ne0.x * v.y;
            v = up2(u1.x); a0 += ne1.x * v.x; a1 += ne1.x * v.y;
            v = up2(u1.y); a2 += ne1.x * v.x; a3 += ne1.x * v.y;
            v = up2(u2.x); a0 += ne2.x * v.x; a1 += ne2.x * v.y;
            v = up2(u2.y); a2 += ne2.x * v.x; a3 += ne2.x * v.y;
            v = up2(u3.x); a0 += ne3.x * v.x; a1 += ne3.x * v.y;
            v = up2(u3.y); a2 += ne3.x * v.x; a3 += ne3.x * v.y;
        }
        for (; p < t; ++p) {
            int sn = srcp[p];
            float2 ne = up2(nexp[(size_t)p * 8 + h]);
            uint2 u = *reinterpret_cast<const uint2*>(&Vb[(size_t)sn * 64 + cd2]);
            es += ne.y;
            float2 v;
            v = up2(u.x); a0 += ne.x * v.x; a1 += ne.x * v.y;
            v = up2(u.y); a2 += ne.x * v.x; a3 += ne.x * v.y;
        }
        float sinv = 1.f / (es + 1e-9f);
        uint2 pk;
        pk.x = pack2bf(a0 * sinv, a1 * sinv);
        pk.y = pack2bf(a2 * sinv, a3 * sinv);
        *reinterpret_cast<uint2*>(&a_s[ni][c4]) = pk;
    }
    __syncthreads();

    const int l  = tid & 63;
    const int w  = tid >> 6;
    const int lr = l & 15, lk = l >> 4;

    {   // phase 2: x_new = x_old + agg @ Wo (MFMA); wave w -> N-tile w
        float4v acc = (float4v){0.f, 0.f, 0.f, 0.f};
        #pragma unroll
        for (int ks = 0; ks < 4; ++ks) {
            short8v af = *reinterpret_cast<const short8v*>(&a_s[lr][lk * 8 + ks * 32]);
            short8v bf = *reinterpret_cast<const short8v*>(&Woxl[((size_t)(w * 4 + ks) * 64 + l) * 8]);
            acc = __builtin_amdgcn_mfma_f32_16x16x32_bf16(af, bf, acc, 0, 0, 0);
        }
        #pragma unroll
        for (int r = 0; r < 4; ++r)
            xf_s[lk * 4 + r][w * 16 + lr] += acc[r];
    }
    __syncthreads();

    {   // phase 3: rms(x_new) -> a_s
        float4 v = *reinterpret_cast<const float4*>(&xf_s[ni][c4]);
        float ss = v.x * v.x + v.y * v.y + v.z * v.z + v.w * v.w;
        #pragma unroll
        for (int m = 1; m < 32; m <<= 1) ss += __shfl_xor(ss, m, 32);
        float r = rsqrtf(ss * (1.0f / 1152.0f) + 1e-6f);
        uint2 pk;
        pk.x = pack2bf(v.x * r, v.y * r);
        pk.y = pack2bf(v.z * r, v.w * r);
        *reinterpret_cast<uint2*>(&a_s[ni][c4]) = pk;
    }
    __syncthreads();

    {   // phase 4: FFN GEMM1 -> h_s; wave w -> N-tiles w*4..w*4+3
        float4v acc[4];
        #pragma unroll
        for (int nf = 0; nf < 4; ++nf) acc[nf] = (float4v){0.f, 0.f, 0.f, 0.f};
        #pragma unroll
        for (int ks = 0; ks < 4; ++ks) {
            short8v af = *reinterpret_cast<const short8v*>(&a_s[lr][lk * 8 + ks * 32]);
            #pragma unroll
            for (int nf = 0; nf < 4; ++nf) {
                int nt = w * 4 + nf;
                short8v bf = *reinterpret_cast<const short8v*>(&Wf1xl[((size_t)(nt * 4 + ks) * 64 + l) * 8]);
                acc[nf] = __builtin_amdgcn_mfma_f32_16x16x32_bf16(af, bf, acc[nf], 0, 0, 0);
            }
        }
        #pragma unroll
        for (int nf = 0; nf < 4; ++nf) {
            #pragma unroll
            for (int r = 0; r < 4; ++r) {
                float v = siluf(acc[nf][r]);
                float vn = __shfl_xor(v, 1, 64);
                if ((l & 1) == 0) {
                    int row = lk * 4 + r;
                    int col = (w * 4 + nf) * 16 + lr;
                    *reinterpret_cast<uint*>(&h_s[row][col]) = pack2bf(v, vn);
                }
            }
        }
    }
    __syncthreads();

    {   // phase 5: FFN GEMM2 -> delta into xf_s; wave w -> N-tile w
        float4v acc = (float4v){0.f, 0.f, 0.f, 0.f};
        #pragma unroll 4
        for (int ks = 0; ks < 16; ++ks) {
            short8v af = *reinterpret_cast<const short8v*>(&h_s[lr][lk * 8 + ks * 32]);
            short8v bf = *reinterpret_cast<const short8v*>(&Wf2xl[((size_t)(w * 16 + ks) * 64 + l) * 8]);
            acc = __builtin_amdgcn_mfma_f32_16x16x32_bf16(af, bf, acc, 0, 0, 0);
        }
        #pragma unroll
        for (int r = 0; r < 4; ++r)
            xf_s[lk * 4 + r][w * 16 + lr] += acc[r];
    }
    __syncthreads();

    {   // phase 6: final rms -> x + a_s + gemm3, or out
        float4 v = *reinterpret_cast<const float4*>(&xf_s[ni][c4]);
        float ss = v.x * v.x + v.y * v.y + v.z * v.z + v.w * v.w;
        #pragma unroll
        for (int m = 1; m < 32; m <<= 1) ss += __shfl_xor(ss, m, 32);
        float r = rsqrtf(ss * (1.0f / 1152.0f) + 1e-6f);

        if (!LAST) {
            *reinterpret_cast<float4*>(&x[(size_t)(n0 + ni) * 128 + c4]) = v;
            uint2 pk;
            pk.x = pack2bf(v.x * r, v.y * r);
            pk.y = pack2bf(v.z * r, v.w * r);
            *reinterpret_cast<uint2*>(&a_s[ni][c4]) = pk;
            __syncthreads();
            node_gemm3_8w(a_s, tid, n0, WvxN, Wa1sxN, Wa1dxN, VbO, Psb, Pdb);
        } else {
            size_t base = (size_t)(n0 + ni) * 1152 + c4;
            *reinterpret_cast<float4*>(&out[base]) = make_float4(v.x * r, v.y * r, v.z * r, v.w * r);
            const float4 z4 = make_float4(0.f, 0.f, 0.f, 0.f);
            #pragma unroll
            for (int k = 1; k < 9; ++k)
                *reinterpret_cast<float4*>(&out[base + (size_t)k * 128]) = z4;
        }
    }
}

extern "C" void kernel_launch(void* const* d_in, const int* in_sizes, int n_in,
                              void* d_out, int out_size, void* d_ws, size_t ws_size,
                              hipStream_t stream)
{
    const int*   atom_feats = (const int*)d_in[0];
    const int*   bond_feats = (const int*)d_in[1];
    const int*   edge_index = (const int*)d_in[2];
    const float* edge_dist  = (const float*)d_in[3];
    const float* atom_emb   = (const float*)d_in[4];
    const float* bond_emb   = (const float*)d_in[5];
    const float* W_rbf1     = (const float*)d_in[6];
    const float* b_rbf1     = (const float*)d_in[7];
    const float* W_rbf2     = (const float*)d_in[8];
    const float* b_rbf2     = (const float*)d_in[9];
    const float* Wa1        = (const float*)d_in[10];
    const float* Wa2        = (const float*)d_in[11];
    const float* Wv         = (const float*)d_in[12];
    const float* Wg         = (const float*)d_in[13];
    const float* Wo         = (const float*)d_in[14];
    const float* Wf1        = (const float*)d_in[15];
    const float* Wf2        = (const float*)d_in[16];
    float* out = (float*)d_out;

    float* ws   = (float*)d_ws;
    float* x    = ws;                           // NN*128
    uint* nexp  = (uint*)(x + NN * 128);        // NE*8 uint (bf16 num|ex)
    float* W2A  = (float*)(nexp + (size_t)NE * 8);
    float* W2G  = W2A  + 2 * 16384;
    float* bA   = W2G  + 2 * 1024;
    float* bG   = bA   + 2 * 128;
    float* TG   = bG   + 16;
    float* BGc  = TG   + 2 * (size_t)TROWS * 8;
    uint* Vb    = (uint*)(BGc + 2 * 512 * 8);   // NN*64
    uint* Psb   = Vb  + NN * 64;
    uint* Pdb   = Psb + NN * 64;
    uint* TAb   = Pdb + NN * 64;                // 2*TROWS*64
    uint* BAcb  = TAb + 2 * (size_t)TROWS * 64; // 2*512*64
    ushort* Wf1x  = (ushort*)(BAcb + 2 * 512 * 64);
    ushort* Wf2x  = Wf1x  + 2 * 65536;
    ushort* Wvx   = Wf2x  + 2 * 65536;
    ushort* Wa1sx = Wvx   + 2 * 16384;
    ushort* Wa1dx = Wa1sx + 2 * 16384;
    ushort* Wa2x  = Wa1dx + 2 * 16384;
    ushort* Wox   = Wa2x  + 2 * 2048;
    int* deg    = (int*)(Wox + 2 * 16384);
    int* off    = deg + NN;
    int* cursor = off + NN + 1;
    int* srcp   = cursor + NN;                  // NE
    int4* erec  = (int4*)(srcp + NE);           // NE int4

    k_prep<<<dim3(371, 2), 256, 0, stream>>>(W_rbf2, b_rbf2, Wa1, Wg, bond_emb,
        Wf1, Wf2, Wv, Wa2, Wo, W2A, W2G, bA, bG, BAcb, BGc,
        Wf1x, Wf2x, Wvx, Wa1sx, Wa1dx, Wa2x, Wox, deg);
    k_prep2<<<889 + (NE + 255) / 256, 256, 0, stream>>>(W_rbf1, b_rbf1, W2A, W2G, bA, bG,
        TAb, TG, atom_feats, atom_emb, x, deg, edge_index,
        Wvx, Wa1sx, Wa1dx, Vb, Psb, Pdb);

    k_scan<<<1, 1024, 0, stream>>>(deg, off, cursor);
    k_fill<<<(NE + 255) / 256, 256, 0, stream>>>(edge_index, bond_feats, edge_dist,
                                                 cursor, srcp, erec);

    for (int l = 0; l < 2; ++l) {
        k_attn<<<(NE + 63) / 64, 256, 0, stream>>>(erec,
            Psb, Pdb,
            TAb + (size_t)l * TROWS * 64, TG + (size_t)l * TROWS * 8,
            BAcb + (size_t)l * 512 * 64, BGc + (size_t)l * 512 * 8,
            Wa2x + (size_t)l * 2048, nexp);
        if (l == 0)
            k_layer_fused<0><<<NN / 16, 512, 0, stream>>>(x, off, srcp, nexp, Vb,
                Wox, Wf1x, Wf2x, out,
                Wvx + 16384, Wa1sx + 16384, Wa1dx + 16384, Vb, Psb, Pdb);
        else
            k_layer_fused<1><<<NN / 16, 512, 0, stream>>>(x, off, srcp, nexp, Vb,
                Wox + 16384, Wf1x + 65536, Wf2x + 65536, out,
                Wvx, Wa1sx, Wa1dx, Vb, Psb, Pdb);
    }
}